// Round 11
// baseline (2864.340 us; speedup 1.0000x reference)
//
#include <hip/hip_runtime.h>
#include <hip/hip_bf16.h>
#include <math.h>

// Problem constants (from setup_inputs)
#define BB 2
#define NSEQ 1024
#define DIM 1024
#define NH 16
#define DH 64
#define DEPTH 4
#define VOCAB 32000
#define XLM 256
#define MDB 4096
#define TOPK 32
#define KNN_LAYER 2
#define BNROWS (BB * NSEQ)   // 2048
#define LOGITS_CHUNK 6400    // 32000 = 5 * 6400
#define NKEYS 1280           // XLM + NSEQ
#define KSP_PS ((size_t)BB * NKEYS * DH)   // plane stride for K/V split planes

typedef __bf16 bf16x8v __attribute__((ext_vector_type(8)));
typedef float f32x4v __attribute__((ext_vector_type(4)));
typedef unsigned short u16x8v __attribute__((ext_vector_type(8)));

__device__ __forceinline__ float bfbits2f(unsigned short u) {
    union { float f; unsigned int i; } v; v.i = ((unsigned int)u) << 16; return v.f;
}
__device__ __forceinline__ unsigned short f2bfbits(float f) {
    union { __hip_bfloat16 b; unsigned short u; } v;
    v.b = __float2bfloat16(f);
    return v.u;
}
__device__ __forceinline__ float bf2f(__hip_bfloat16 h) { return __bfloat162float(h); }
__device__ __forceinline__ __hip_bfloat16 f2bf(float f) { return __float2bfloat16(f); }

__device__ __forceinline__ void gload16(const void* gp, void* lp) {
    __builtin_amdgcn_global_load_lds(
        (const __attribute__((address_space(1))) unsigned int*)gp,
        (__attribute__((address_space(3))) unsigned int*)lp, 16, 0, 0);
}

// ---------------------------------------------------------------------------
__global__ __launch_bounds__(256) void embed_kernel(const int* __restrict__ tok,
                                                    const float* __restrict__ emb,
                                                    float* __restrict__ x) {
    int r = blockIdx.x, t = threadIdx.x;
    int id = tok[r];
    const float* er = emb + (size_t)id * DIM;
    float* xr = x + (size_t)r * DIM;
#pragma unroll
    for (int i = 0; i < 4; i++) xr[t + 256 * i] = er[t + 256 * i];
}

// ---------------------------------------------------------------------------
// Row LayerNorm over DIM=1024, fp32 in, split-bf16 (hi/lo planes) out
__global__ __launch_bounds__(256) void ln_kernel(const float* __restrict__ x,
                                                 const float* __restrict__ w,
                                                 const float* __restrict__ b,
                                                 __hip_bfloat16* __restrict__ y,
                                                 size_t ypS) {
    __shared__ float red[256];
    int r = blockIdx.x, t = threadIdx.x;
    const float* xr = x + (size_t)r * DIM;
    float v[4];
#pragma unroll
    for (int i = 0; i < 4; i++) v[i] = xr[t + 256 * i];
    float s = v[0] + v[1] + v[2] + v[3];
    red[t] = s; __syncthreads();
    for (int st = 128; st; st >>= 1) { if (t < st) red[t] += red[t + st]; __syncthreads(); }
    float mean = red[0] * (1.0f / DIM);
    __syncthreads();
    float s2 = 0.f;
#pragma unroll
    for (int i = 0; i < 4; i++) { float d = v[i] - mean; s2 += d * d; }
    red[t] = s2; __syncthreads();
    for (int st = 128; st; st >>= 1) { if (t < st) red[t] += red[t + st]; __syncthreads(); }
    float rs = rsqrtf(red[0] * (1.0f / DIM) + 1e-5f);
    __hip_bfloat16* yr = y + (size_t)r * DIM;
#pragma unroll
    for (int i = 0; i < 4; i++) {
        int c = t + 256 * i;
        float val = (v[i] - mean) * rs * w[c] + b[c];
        __hip_bfloat16 hv = f2bf(val);
        yr[c] = hv;
        yr[c + ypS] = f2bf(val - bf2f(hv));
    }
}

// ---------------------------------------------------------------------------
// L2-normalize fp32 rows of length 64 (row stride configurable), in-place
__global__ void l2norm_kernel(float* __restrict__ p, int stride) {
    int r = blockIdx.x, t = threadIdx.x; // 64 threads
    float* pr = p + (size_t)r * stride;
    float v = pr[t];
    float s = v * v;
#pragma unroll
    for (int off = 32; off; off >>= 1) s += __shfl_xor(s, off, 64);
    float n = fmaxf(sqrtf(s), 1e-12f);
    pr[t] = v / n;
}

__global__ void dbnorm_kernel(const float* __restrict__ db, float* __restrict__ dbkn) {
    int r = blockIdx.x, t = threadIdx.x; // 64 threads
    float v = db[((size_t)r * 2 + 0) * DH + t];
    float s = v * v;
#pragma unroll
    for (int off = 32; off; off >>= 1) s += __shfl_xor(s, off, 64);
    float n = fmaxf(sqrtf(s), 1e-12f);
    dbkn[(size_t)r * DH + t] = v / n;
}

// ---------------------------------------------------------------------------
// fp32 -> split-bf16 planes (hi at y, lo at y+pS). n4 = n/4 float4 groups.
__global__ __launch_bounds__(256) void split_conv(const float* __restrict__ x,
                                                  unsigned short* __restrict__ y,
                                                  size_t pS, size_t n4) {
    size_t idx = (size_t)blockIdx.x * 256 + threadIdx.x;
    if (idx >= n4) return;
    float4 v = *(const float4*)&x[idx * 4];
    float vv[4] = {v.x, v.y, v.z, v.w};
    ushort4 h4, l4;
    unsigned short* hp = (unsigned short*)&h4;
    unsigned short* lp = (unsigned short*)&l4;
#pragma unroll
    for (int j = 0; j < 4; j++) {
        hp[j] = f2bfbits(vv[j]);
        lp[j] = f2bfbits(vv[j] - bfbits2f(hp[j]));
    }
    *(ushort4*)&y[idx * 4] = h4;
    *(ushort4*)&y[idx * 4 + pS] = l4;
}

// ---------------------------------------------------------------------------
// Per-layer K/V split-bf16 prep: K planes [b][key][dim]; V transposed planes
// [b][dim][key]. keys 0..255 from xlm, 256..1279 from fresh kv.
__global__ void kv_prep(const float* __restrict__ kvf, const float* __restrict__ xlm,
                        unsigned short* __restrict__ ksp, unsigned short* __restrict__ vtp) {
    int key = blockIdx.x, b = blockIdx.y, d = threadIdx.x; // 64 threads
    float kvv, vvv;
    if (key < XLM) {
        kvv = xlm[(((size_t)b * XLM + key) * 2 + 0) * DH + d];
        vvv = xlm[(((size_t)b * XLM + key) * 2 + 1) * DH + d];
    } else {
        const float* r = &kvf[(size_t)(b * NSEQ + key - XLM) * 128];
        kvv = r[d]; vvv = r[64 + d];
    }
    unsigned short kh = f2bfbits(kvv), kl = f2bfbits(kvv - bfbits2f(kh));
    unsigned short vh = f2bfbits(vvv), vl = f2bfbits(vvv - bfbits2f(vh));
    size_t ko = (size_t)b * NKEYS * DH + (size_t)key * DH + d;
    ksp[ko] = kh; ksp[ko + KSP_PS] = kl;
    size_t vo = (size_t)b * DH * NKEYS + (size_t)d * NKEYS + key;
    vtp[vo] = vh; vtp[vo + KSP_PS] = vl;
}

// ---------------------------------------------------------------------------
// Weight convert + transpose: W (K x N fp32, row stride ldw) ->
// WT (N x K split-bf16, hi plane + lo plane at +wpS). wlo=0: hi only.
__global__ __launch_bounds__(256) void wconv(const float* __restrict__ W,
                                             __hip_bfloat16* __restrict__ WT,
                                             size_t wpS, int K, int N, int ldw,
                                             int wlo) {
    __shared__ float tile[64][65];
    int k0 = blockIdx.x * 64, n0 = blockIdx.y * 64;
    int t = threadIdx.x;
    int r = t >> 4, c4 = (t & 15) * 4;
#pragma unroll
    for (int rr = 0; rr < 4; rr++) {
        int row = rr * 16 + r;
        float4 v = *(const float4*)&W[(size_t)(k0 + row) * ldw + n0 + c4];
        tile[row][c4] = v.x; tile[row][c4 + 1] = v.y; tile[row][c4 + 2] = v.z; tile[row][c4 + 3] = v.w;
    }
    __syncthreads();
#pragma unroll
    for (int rr = 0; rr < 4; rr++) {
        int nrow = rr * 16 + r;
        size_t base = (size_t)(n0 + nrow) * K + k0 + c4;
#pragma unroll
        for (int j = 0; j < 4; j++) {
            float val = tile[c4 + j][nrow];
            __hip_bfloat16 hv = f2bf(val);
            WT[base + j] = hv;
            if (wlo) WT[base + j + wpS] = f2bf(val - bf2f(hv));
        }
    }
}

// ---------------------------------------------------------------------------
// Split-bf16 MFMA GEMM: C(MxN) = A(MxK) @ BT(NxK)^T with A,B as hi/lo planes.
// TERMS: 3 = hi*hi + lo*hi + hi*lo (fp32-grade); 1 = hi*hi only (bf16-grade).
// OT: float / __hip_bfloat16 (split 2-plane) / unsigned short (single bf16).
// SIMDB: batch mode over bh (z dim).
template <typename OT, int ACT, int TERMS, int SIMDB>
__global__ __launch_bounds__(256) void gemm_split(const __hip_bfloat16* __restrict__ A, int lda, size_t apS,
                                                  const __hip_bfloat16* __restrict__ BT, int ldb, size_t bpS,
                                                  OT* __restrict__ C, int ldc, size_t cpS, int K,
                                                  const float* __restrict__ bias,
                                                  const float* __restrict__ res,
                                                  int bh0) {
    __shared__ __align__(16) __hip_bfloat16 sAh[128 * 32];
    __shared__ __align__(16) __hip_bfloat16 sBh[128 * 32];
    __shared__ __align__(16) __hip_bfloat16 sAl[TERMS >= 2 ? 128 * 32 : 1];
    __shared__ __align__(16) __hip_bfloat16 sBl[TERMS >= 3 ? 128 * 32 : 1];
    if constexpr (SIMDB) {
        int bh = bh0 + blockIdx.z;
        A += ((size_t)(bh >> 4) * NSEQ) * lda + (bh & 15) * DH;
        BT += (size_t)(bh >> 4) * MDB * ldb;
        C += (size_t)blockIdx.z * NSEQ * ldc;
    }
    int bn = blockIdx.x * 128;
    int bm = blockIdx.y * 128;
    int t = threadIdx.x;
    int lane = t & 63, wid = t >> 6;
    int wr = wid >> 1, wc = wid & 1;
    int lr = lane & 15, kc = lane >> 4;

    f32x4v acc[4][4];
#pragma unroll
    for (int m = 0; m < 4; m++)
#pragma unroll
        for (int n = 0; n < 4; n++) acc[m][n] = (f32x4v){0.f, 0.f, 0.f, 0.f};

    for (int k0 = 0; k0 < K; k0 += 32) {
        __syncthreads();
#pragma unroll
        for (int it = 0; it < 2; it++) {
            int e = wid * 128 + it * 64 + lane;
            int r = e >> 2;
            int cl = (e & 3) ^ ((r >> 1) & 3);
            size_t aoff = (size_t)(bm + r) * lda + k0 + cl * 8;
            size_t boff = (size_t)(bn + r) * ldb + k0 + cl * 8;
            int dst = (wid * 128 + it * 64) * 8;
            gload16(&A[aoff], &sAh[dst]);
            gload16(&BT[boff], &sBh[dst]);
            if constexpr (TERMS >= 2) gload16(&A[aoff + apS], &sAl[dst]);
            if constexpr (TERMS >= 3) gload16(&BT[boff + bpS], &sBl[dst]);
        }
        __syncthreads();

        bf16x8v ah[4], al[4], bh[4], bl[4];
#pragma unroll
        for (int m = 0; m < 4; m++) {
            int row = wr * 64 + m * 16 + lr;
            int off = row * 32 + ((kc ^ ((row >> 1) & 3)) << 3);
            ah[m] = *(const bf16x8v*)&sAh[off];
            if constexpr (TERMS >= 2) al[m] = *(const bf16x8v*)&sAl[off];
        }
#pragma unroll
        for (int n = 0; n < 4; n++) {
            int row = wc * 64 + n * 16 + lr;
            int off = row * 32 + ((kc ^ ((row >> 1) & 3)) << 3);
            bh[n] = *(const bf16x8v*)&sBh[off];
            if constexpr (TERMS >= 3) bl[n] = *(const bf16x8v*)&sBl[off];
        }
#pragma unroll
        for (int m = 0; m < 4; m++)
#pragma unroll
            for (int n = 0; n < 4; n++) {
                acc[m][n] = __builtin_amdgcn_mfma_f32_16x16x32_bf16(ah[m], bh[n], acc[m][n], 0, 0, 0);
                if constexpr (TERMS >= 2)
                    acc[m][n] = __builtin_amdgcn_mfma_f32_16x16x32_bf16(al[m], bh[n], acc[m][n], 0, 0, 0);
                if constexpr (TERMS >= 3)
                    acc[m][n] = __builtin_amdgcn_mfma_f32_16x16x32_bf16(ah[m], bl[n], acc[m][n], 0, 0, 0);
            }
    }

#pragma unroll
    for (int m = 0; m < 4; m++) {
#pragma unroll
        for (int n = 0; n < 4; n++) {
            int gcol = bn + wc * 64 + n * 16 + lr;
            float bv = bias ? bias[gcol] : 0.f;
#pragma unroll
            for (int j = 0; j < 4; j++) {
                int grow = bm + wr * 64 + m * 16 + kc * 4 + j;
                float v = acc[m][n][j] + bv;
                if (ACT == 1) v = 0.5f * v * (1.0f + erff(v * 0.70710678118654752f));
                if (res) v += res[(size_t)grow * ldc + gcol];
                size_t idx = (size_t)grow * ldc + gcol;
                if constexpr (__is_same(OT, float)) {
                    C[idx] = v;
                } else if constexpr (__is_same(OT, unsigned short)) {
                    C[idx] = f2bfbits(v);
                } else {
                    __hip_bfloat16 hv = f2bf(v);
                    C[idx] = hv;
                    C[idx + cpS] = f2bf(v - bf2f(hv));
                }
            }
        }
    }
}

// ---------------------------------------------------------------------------
// Split-bf16 MFMA flash attention over XL + causal local keys.
// K/V pre-split by kv_prep; staging is pure global_load_lds.
template <int KNNL>
__global__ __launch_bounds__(256) void flash_kernel(const float* __restrict__ q,
                                                    const unsigned short* __restrict__ ksp,
                                                    const unsigned short* __restrict__ vtp,
                                                    const float* __restrict__ knn_scale,
                                                    __hip_bfloat16* __restrict__ out,
                                                    size_t opS,
                                                    float* __restrict__ stats) {
    __shared__ __align__(16) unsigned short sKh[64 * 64];
    __shared__ __align__(16) unsigned short sKl[64 * 64];
    __shared__ __align__(16) unsigned short sVh[64 * 64];   // transposed [dim][key]
    __shared__ __align__(16) unsigned short sVl[64 * 64];
    __shared__ __align__(16) float sPf[4 * 16 * 64];        // per-wave P fp32

    int qt = blockIdx.x, h = blockIdx.y, b = blockIdx.z;
    int q0 = qt * 64;
    int t = threadIdx.x;
    int w = t >> 6;
    int lane = t & 63;
    int lr = lane & 15, kc = lane >> 4;
    int wbase = w * 1024;

    float scale = KNNL ? __expf(knn_scale[h]) : 0.125f;

    bf16x8v qh[2], ql[2];
    {
        const float* qbase = q + (size_t)(b * NSEQ + q0 + w * 16 + lr) * DIM + h * DH;
#pragma unroll
        for (int ks = 0; ks < 2; ks++) {
            const float* s = qbase + ks * 32 + kc * 8;
            float4 a = *(const float4*)s;
            float4 c2 = *(const float4*)(s + 4);
            float vv[8] = {a.x, a.y, a.z, a.w, c2.x, c2.y, c2.z, c2.w};
            u16x8v hi, lo;
#pragma unroll
            for (int j = 0; j < 8; j++) {
                hi[j] = f2bfbits(vv[j]);
                lo[j] = f2bfbits(vv[j] - bfbits2f(hi[j]));
            }
            qh[ks] = *(bf16x8v*)&hi;
            ql[ks] = *(bf16x8v*)&lo;
        }
    }

    float m[4], l[4];
    f32x4v o[4];
#pragma unroll
    for (int j = 0; j < 4; j++) { m[j] = -1e30f; l[j] = 0.f; }
#pragma unroll
    for (int f = 0; f < 4; f++) o[f] = (f32x4v){0.f, 0.f, 0.f, 0.f};

    int ntiles = 5 + qt;
    size_t kbase = (size_t)b * NKEYS * DH;
    size_t vbase = (size_t)b * DH * NKEYS;

    for (int T = 0; T < ntiles; T++) {
        __syncthreads();
        // ---- stage K + Vt planes via global_load_lds (512 16B-chunks each)
#pragma unroll
        for (int i2 = 0; i2 < 2; i2++) {
            int cbase = i2 * 256 + w * 64;
            int c = cbase + lane;
            int key = c >> 3, ch = (c & 7) ^ (key & 7);
            size_t ko = kbase + (size_t)(T * 64 + key) * DH + ch * 8;
            gload16(&ksp[ko], &sKh[cbase * 8]);
            gload16(&ksp[ko + KSP_PS], &sKl[cbase * 8]);
            int dim = c >> 3, k8 = (c & 7) ^ (dim & 7);
            size_t vo = vbase + (size_t)dim * NKEYS + T * 64 + k8 * 8;
            gload16(&vtp[vo], &sVh[cbase * 8]);
            gload16(&vtp[vo + KSP_PS], &sVl[cbase * 8]);
        }
        __syncthreads();

        f32x4v s4[4];
#pragma unroll
        for (int n = 0; n < 4; n++) s4[n] = (f32x4v){0.f, 0.f, 0.f, 0.f};
#pragma unroll
        for (int ks = 0; ks < 2; ks++) {
            bf16x8v qh_ = qh[ks], ql_ = ql[ks];
#pragma unroll
            for (int n = 0; n < 4; n++) {
                int row = n * 16 + lr;
                int off = row * 64 + (((ks * 4 + kc) ^ (lr & 7)) << 3);
                bf16x8v kh = *(const bf16x8v*)&sKh[off];
                bf16x8v kl = *(const bf16x8v*)&sKl[off];
                s4[n] = __builtin_amdgcn_mfma_f32_16x16x32_bf16(qh_, kh, s4[n], 0, 0, 0);
                s4[n] = __builtin_amdgcn_mfma_f32_16x16x32_bf16(ql_, kh, s4[n], 0, 0, 0);
                s4[n] = __builtin_amdgcn_mfma_f32_16x16x32_bf16(qh_, kl, s4[n], 0, 0, 0);
            }
        }

#pragma unroll
        for (int n = 0; n < 4; n++) {
            int key = T * 64 + n * 16 + lr;
#pragma unroll
            for (int j = 0; j < 4; j++) {
                int gq = q0 + w * 16 + kc * 4 + j;
                float sv = s4[n][j] * scale;
                s4[n][j] = (key <= XLM + gq) ? sv : -1e30f;
            }
        }

        float tm[4];
#pragma unroll
        for (int j = 0; j < 4; j++) {
            float v = fmaxf(fmaxf(s4[0][j], s4[1][j]), fmaxf(s4[2][j], s4[3][j]));
            v = fmaxf(v, __shfl_xor(v, 1, 64));
            v = fmaxf(v, __shfl_xor(v, 2, 64));
            v = fmaxf(v, __shfl_xor(v, 4, 64));
            v = fmaxf(v, __shfl_xor(v, 8, 64));
            tm[j] = v;
        }
        float alpha[4];
#pragma unroll
        for (int j = 0; j < 4; j++) {
            float mnew = fmaxf(m[j], tm[j]);
            alpha[j] = __expf(m[j] - mnew);
            m[j] = mnew;
        }
        float psum[4] = {0.f, 0.f, 0.f, 0.f};
#pragma unroll
        for (int n = 0; n < 4; n++)
#pragma unroll
            for (int j = 0; j < 4; j++) {
                float p = __expf(s4[n][j] - m[j]);
                s4[n][j] = p;
                psum[j] += p;
            }
#pragma unroll
        for (int j = 0; j < 4; j++) {
            float v = psum[j];
            v += __shfl_xor(v, 1, 64);
            v += __shfl_xor(v, 2, 64);
            v += __shfl_xor(v, 4, 64);
            v += __shfl_xor(v, 8, 64);
            l[j] = l[j] * alpha[j] + v;
        }
#pragma unroll
        for (int f = 0; f < 4; f++)
#pragma unroll
            for (int j = 0; j < 4; j++) o[f][j] *= alpha[j];

#pragma unroll
        for (int n = 0; n < 4; n++) {
            int chunkcol = 2 * n + (lr >> 3);
#pragma unroll
            for (int j = 0; j < 4; j++) {
                int row = kc * 4 + j;
                int off = wbase + row * 64 + (((chunkcol ^ (row & 7)) << 3) + (lr & 7));
                sPf[off] = s4[n][j];
            }
        }

#pragma unroll
        for (int ks = 0; ks < 2; ks++) {
            int poff = wbase + lr * 64 + (((ks * 4 + kc) ^ (lr & 7)) << 3);
            float4 a = *(const float4*)&sPf[poff];
            float4 c2 = *(const float4*)&sPf[poff + 4];
            float vv[8] = {a.x, a.y, a.z, a.w, c2.x, c2.y, c2.z, c2.w};
            u16x8v hib, lob;
#pragma unroll
            for (int j = 0; j < 8; j++) {
                hib[j] = f2bfbits(vv[j]);
                lob[j] = f2bfbits(vv[j] - bfbits2f(hib[j]));
            }
            bf16x8v ph = *(bf16x8v*)&hib;
            bf16x8v pl = *(bf16x8v*)&lob;
#pragma unroll
            for (int f = 0; f < 4; f++) {
                int row = f * 16 + lr;
                int off = row * 64 + (((ks * 4 + kc) ^ (lr & 7)) << 3);
                bf16x8v vh = *(const bf16x8v*)&sVh[off];
                bf16x8v vl = *(const bf16x8v*)&sVl[off];
                o[f] = __builtin_amdgcn_mfma_f32_16x16x32_bf16(ph, vh, o[f], 0, 0, 0);
                o[f] = __builtin_amdgcn_mfma_f32_16x16x32_bf16(pl, vh, o[f], 0, 0, 0);
                o[f] = __builtin_amdgcn_mfma_f32_16x16x32_bf16(ph, vl, o[f], 0, 0, 0);
            }
        }
    }

    float inv[4];
#pragma unroll
    for (int j = 0; j < 4; j++) inv[j] = 1.0f / l[j];
    unsigned short* outu = (unsigned short*)out;
#pragma unroll
    for (int f = 0; f < 4; f++)
#pragma unroll
        for (int j = 0; j < 4; j++) {
            int gq = q0 + w * 16 + kc * 4 + j;
            size_t oidx = (size_t)(b * NSEQ + gq) * DIM + h * DH + f * 16 + lr;
            float v = o[f][j] * inv[j];
            unsigned short hv = f2bfbits(v);
            outu[oidx] = hv;
            outu[oidx + opS] = f2bfbits(v - bfbits2f(hv));
        }
    if (KNNL && lr == 0) {
#pragma unroll
        for (int j = 0; j < 4; j++) {
            int gq = q0 + w * 16 + kc * 4 + j;
            size_t srow = (((size_t)b * NH + h) * NSEQ + gq) * 2;
            stats[srow] = m[j];
            stats[srow + 1] = l[j];
        }
    }
}

// ---------------------------------------------------------------------------
// Per-row top-32 over bf16 simdb + exact recompute + mem softmax + combine.
// 4 waves per block, ONE ROW PER WAVE (no idle waves, no barriers).
// Per-wave 8KB LDS slab, chunk-of-8 XOR swizzle: element (c,l) of the row
// (c=chunk 0..63, l=0..63) at u16 index c*64 + (l ^ ((c&7)<<3)).
__global__ __launch_bounds__(256) void knn_select(const unsigned short* __restrict__ simdb,
                                                  const float* __restrict__ db,
                                                  const float* __restrict__ qf,
                                                  const float* __restrict__ dbkn,
                                                  const float* __restrict__ knn_scale,
                                                  const float* __restrict__ stats,
                                                  __hip_bfloat16* __restrict__ out,
                                                  size_t opS,
                                                  int bh0) {
    __shared__ unsigned short sv[4 * 4096];

    int bh = bh0 + blockIdx.y;
    int b = bh >> 4, h = bh & 15;
    int t = threadIdx.x;
    int w = t >> 6, lane = t & 63;
    int i = blockIdx.x * 4 + w;
    unsigned short* svw = &sv[w * 4096];

    // stage this wave's row: 512 16B-chunks / 64 lanes = 8 iters
    const unsigned short* srow = &simdb[((size_t)blockIdx.y * NSEQ + i) * MDB];
#pragma unroll
    for (int it = 0; it < 8; it++) {
        int g = it * 64 + lane;
        int c = g >> 3, sub = g & 7;
        u16x8v d = *(const u16x8v*)&srow[(size_t)g * 8];
        *(u16x8v*)&svw[c * 64 + ((sub ^ (c & 7)) << 3)] = d;
    }

    // per-column candidates: lane owns column l, scans 64 chunks
    float lmax = -1e30f; int lidx = 0;
#pragma unroll
    for (int c = 0; c < 64; c++) {
        float v = bfbits2f(svw[c * 64 + (lane ^ ((c & 7) << 3))]);
        if (v > lmax) { lmax = v; lidx = c * 64 + lane; }
    }

    // 32 selection iterations, wave-synchronous
    int tidx = 0;
    for (int it = 0; it < TOPK; it++) {
        float v = lmax; int idx = lidx;
#pragma unroll
        for (int off = 32; off; off >>= 1) {
            float v2 = __shfl_xor(v, off, 64);
            int i2 = __shfl_xor(idx, off, 64);
            if (v2 > v || (v2 == v && i2 < idx)) { v = v2; idx = i2; }
        }
        if (lane == it) tidx = idx;
        int col = idx & 63, cc = idx >> 6;
        if (lane == 0) svw[cc * 64 + (col ^ ((cc & 7) << 3))] = 0xFF80; // bf16 -inf
        // rescan column col: lane reads element (c=lane, col)
        float rv = bfbits2f(svw[lane * 64 + (col ^ ((lane & 7) << 3))]);
        int ridx = lane * 64 + col;
#pragma unroll
        for (int off = 32; off; off >>= 1) {
            float v2 = __shfl_xor(rv, off, 64);
            int i2 = __shfl_xor(ridx, off, 64);
            if (v2 > rv || (v2 == rv && i2 < ridx)) { rv = v2; ridx = i2; }
        }
        if (lane == col) { lmax = rv; lidx = ridx; }
    }

    // exact recompute of selected sims (lane j < 32 recomputes sim of its idx)
    float srec = -1e30f;
    if (lane < TOPK) {
        const float* qrow = &qf[(size_t)(b * NSEQ + i) * DIM + h * DH];
        const float* krow = &dbkn[((size_t)b * MDB + tidx) * DH];
        float s = 0.f;
#pragma unroll
        for (int d4 = 0; d4 < 16; d4++) {
            float4 a = *(const float4*)&qrow[d4 * 4];
            float4 k2 = *(const float4*)&krow[d4 * 4];
            s += a.x * k2.x + a.y * k2.y + a.z * k2.z + a.w * k2.w;
        }
        srec = s;
    }

    float scl = __expf(knn_scale[h]);
    size_t srow_idx = (((size_t)b * NH + h) * NSEQ + i) * 2;
    float m_loc = stats[srow_idx], l_loc = stats[srow_idx + 1];
    float mm = srec;
#pragma unroll
    for (int off = 32; off; off >>= 1) mm = fmaxf(mm, __shfl_xor(mm, off, 64));
    float M = fmaxf(m_loc, mm * scl);
    float co = __expf(m_loc - M);
    float e = (lane < TOPK) ? __expf(srec * scl - M) : 0.f;
    float esum = e;
#pragma unroll
    for (int off = 32; off; off >>= 1) esum += __shfl_xor(esum, off, 64);
    float denom = l_loc * co + esum;

    // gather: lane = output dim; iterate 32 selected keys via shfl broadcast
    float acc = 0.f;
#pragma unroll
    for (int j = 0; j < TOPK; j++) {
        int idxj = __shfl(tidx, j, 64);
        float ej = __shfl(e, j, 64);
        acc += ej * db[(((size_t)b * MDB + idxj) * 2 + 1) * DH + lane];
    }

    size_t op = (size_t)(b * NSEQ + i) * DIM + h * DH + lane;
    float o_loc = bf2f(out[op]) + bf2f(out[op + opS]);
    float nv = (o_loc * l_loc * co + acc) / denom;
    __hip_bfloat16 hv = f2bf(nv);
    out[op] = hv;
    out[op + opS] = f2bf(nv - bf2f(hv));
}

// ---------------------------------------------------------------------------
extern "C" void kernel_launch(void* const* d_in, const int* in_sizes, int n_in,
                              void* d_out, int out_size, void* d_ws, size_t ws_size,
                              hipStream_t stream) {
    const int* tokens = (const int*)d_in[0];
    const float* emb = (const float*)d_in[1];
    const float* ln1_w = (const float*)d_in[2];
    const float* ln1_b = (const float*)d_in[3];
    const float* wq = (const float*)d_in[4];
    const float* wkv = (const float*)d_in[5];
    const float* wo = (const float*)d_in[6];
    const float* wo_b = (const float*)d_in[7];
    const float* knn_scale = (const float*)d_in[8];
    const float* ln2_w = (const float*)d_in[9];
    const float* ln2_b = (const float*)d_in[10];
    const float* ff_w1 = (const float*)d_in[11];
    const float* ff_b1 = (const float*)d_in[12];
    const float* ff_w2 = (const float*)d_in[13];
    const float* ff_b2 = (const float*)d_in[14];
    const float* lnf_w = (const float*)d_in[15];
    const float* lnf_b = (const float*)d_in[16];
    const float* w_logits = (const float*)d_in[17];
    const float* b_logits = (const float*)d_in[18];
    const float* xl_mems = (const float*)d_in[19];
    const float* db_kv = (const float*)d_in[20];

    // ---- workspace layout ----
    const size_t PS_H = (size_t)BNROWS * DIM;        // plane stride for h / attn-out
    char* p = (char*)d_ws;
    float* x = (float*)p;                p += PS_H * 4;                        // 8 MB
    __hip_bfloat16* hb = (__hip_bfloat16*)p;  p += PS_H * 2 * 2;               // 8 MB (2 planes)
    float* qf = (float*)p;               p += PS_H * 4;                        // 8 MB
    float* kvf = (float*)p;              p += (size_t)BNROWS * 128 * 4;        // 1 MB
    float* dbkn = (float*)p;             p += (size_t)BB * MDB * DH * 4;       // 2 MB
    float* stats = (float*)p;            p += (size_t)BB * NH * NSEQ * 2 * 4;  // 0.25 MB
    unsigned short* ksp = (unsigned short*)p; p += KSP_PS * 2 * 2;             // 0.66 MB
    unsigned short* vtp = (unsigned short*)p; p += KSP_PS * 2 * 2;             // 0.66 MB
    __hip_bfloat16* wT = (__hip_bfloat16*)p; p += (size_t)4096 * DIM * 2 * 2;  // 16 MB (2 planes)

    // qsplit/dbkn-split live in the wT region during the KNN phase (wT idle)
    unsigned short* qsplit = (unsigned short*)wT;                  // 2 planes x PS_H
    unsigned short* dbks = (unsigned short*)wT + 2 * PS_H;         // 2 planes x BB*MDB*DH
    const size_t PS_DB = (size_t)BB * MDB * DH;

    const size_t PS_MID = (size_t)BNROWS * 4 * DIM;  // 8M elems per plane
    __hip_bfloat16* midb = (__hip_bfloat16*)d_out;   // 32 MB of the 262 MB out buf
    float* logits = (float*)d_out;

    embed_kernel<<<BNROWS, 256, 0, stream>>>(tokens, emb, x);
    dbnorm_kernel<<<BB * MDB, 64, 0, stream>>>(db_kv, dbkn);

    for (int l = 0; l < DEPTH; l++) {
        const float* wq_l = wq + (size_t)l * DIM * DIM;
        const float* wkv_l = wkv + (size_t)l * DIM * 128;
        const float* wo_l = wo + (size_t)l * DIM * DIM;
        const float* xlm_l = xl_mems + (size_t)l * BB * XLM * 2 * DH;

        // h = LN1(x) -> split bf16
        ln_kernel<<<BNROWS, 256, 0, stream>>>(x, ln1_w + (size_t)l * DIM, ln1_b + (size_t)l * DIM, hb, PS_H);

        // q = h @ wq  (fp32 out)
        wconv<<<dim3(16, 16), 256, 0, stream>>>(wq_l, wT, (size_t)DIM * DIM, DIM, DIM, DIM, 1);
        gemm_split<float, 0, 3, 0><<<dim3(DIM / 128, BNROWS / 128), 256, 0, stream>>>(
            hb, DIM, PS_H, wT, DIM, (size_t)DIM * DIM, qf, DIM, 0, DIM, nullptr, nullptr, 0);
        // kv = h @ wkv (fp32 out)
        wconv<<<dim3(16, 2), 256, 0, stream>>>(wkv_l, wT, (size_t)128 * DIM, DIM, 128, 128, 1);
        gemm_split<float, 0, 3, 0><<<dim3(1, BNROWS / 128), 256, 0, stream>>>(
            hb, DIM, PS_H, wT, DIM, (size_t)128 * DIM, kvf, 128, 0, DIM, nullptr, nullptr, 0);

        if (l == KNN_LAYER) {
            l2norm_kernel<<<BNROWS * NH, 64, 0, stream>>>(qf, DH);
            l2norm_kernel<<<BNROWS, 64, 0, stream>>>(kvf, 128);
            kv_prep<<<dim3(NKEYS, BB), 64, 0, stream>>>(kvf, xlm_l, ksp, vtp);
            split_conv<<<(PS_H / 4 + 255) / 256, 256, 0, stream>>>(qf, qsplit, PS_H, PS_H / 4);
            split_conv<<<(PS_DB / 4 + 255) / 256, 256, 0, stream>>>(dbkn, dbks, PS_DB, PS_DB / 4);
            flash_kernel<1><<<dim3(NSEQ / 64, NH, BB), 256, 0, stream>>>(
                qf, ksp, vtp, knn_scale, hb, PS_H, stats);
            // CHUNK=4: 4 slices x 8 MB bf16 = 33 MB per gemm->select pair, so
            // the simdb slab stays L2/L3-resident between producer and consumer.
            const int CHUNK = 4;
            for (int bh0 = 0; bh0 < BB * NH; bh0 += CHUNK) {
                gemm_split<unsigned short, 0, 3, 1><<<dim3(MDB / 128, NSEQ / 128, CHUNK), 256, 0, stream>>>(
                    (const __hip_bfloat16*)qsplit, DIM, PS_H,
                    (const __hip_bfloat16*)dbks, DH, PS_DB,
                    (unsigned short*)d_out, MDB, 0, DH, nullptr, nullptr, bh0);
                knn_select<<<dim3(NSEQ / 4, CHUNK), 256, 0, stream>>>(
                    (const unsigned short*)d_out, db_kv, qf, dbkn, knn_scale, stats, hb, PS_H, bh0);
            }
        } else {
            kv_prep<<<dim3(NKEYS, BB), 64, 0, stream>>>(kvf, xlm_l, ksp, vtp);
            flash_kernel<0><<<dim3(NSEQ / 64, NH, BB), 256, 0, stream>>>(
                qf, ksp, vtp, knn_scale, hb, PS_H, stats);
        }

        // x = attn @ wo + wo_b + x
        wconv<<<dim3(16, 16), 256, 0, stream>>>(wo_l, wT, (size_t)DIM * DIM, DIM, DIM, DIM, 1);
        gemm_split<float, 0, 3, 0><<<dim3(DIM / 128, BNROWS / 128), 256, 0, stream>>>(
            hb, DIM, PS_H, wT, DIM, (size_t)DIM * DIM, x, DIM, 0, DIM,
            wo_b + (size_t)l * DIM, x, 0);

        // h = LN2(x)
        ln_kernel<<<BNROWS, 256, 0, stream>>>(x, ln2_w + (size_t)l * DIM, ln2_b + (size_t)l * DIM, hb, PS_H);
        // mid = gelu(h @ ff_w1 + b1) -> split bf16 (in d_out)
        wconv<<<dim3(16, 64), 256, 0, stream>>>(ff_w1 + (size_t)l * DIM * 4 * DIM, wT, (size_t)4096 * DIM, DIM, 4 * DIM, 4 * DIM, 1);
        gemm_split<__hip_bfloat16, 1, 3, 0><<<dim3(4 * DIM / 128, BNROWS / 128), 256, 0, stream>>>(
            hb, DIM, PS_H, wT, DIM, (size_t)4096 * DIM, midb, 4 * DIM, PS_MID, DIM,
            ff_b1 + (size_t)l * 4 * DIM, nullptr, 0);
        // x = mid @ ff_w2 + b2 + x
        wconv<<<dim3(64, 16), 256, 0, stream>>>(ff_w2 + (size_t)l * 4 * DIM * DIM, wT, (size_t)DIM * 4096, 4 * DIM, DIM, DIM, 1);
        gemm_split<float, 0, 3, 0><<<dim3(DIM / 128, BNROWS / 128), 256, 0, stream>>>(
            midb, 4 * DIM, PS_MID, wT, 4 * DIM, (size_t)DIM * 4096, x, DIM, 0, 4 * DIM,
            ff_b2 + (size_t)l * DIM, x, 0);
    }

    // final LN + logits (5 column chunks of 6400, hi-plane-only bf16 GEMM)
    ln_kernel<<<BNROWS, 256, 0, stream>>>(x, lnf_w, lnf_b, hb, PS_H);
    for (int c0 = 0; c0 < VOCAB; c0 += LOGITS_CHUNK) {
        wconv<<<dim3(16, LOGITS_CHUNK / 64), 256, 0, stream>>>(
            w_logits + c0, wT, 0, DIM, LOGITS_CHUNK, VOCAB, 0);
        gemm_split<float, 0, 1, 0><<<dim3(LOGITS_CHUNK / 128, BNROWS / 128), 256, 0, stream>>>(
            hb, DIM, PS_H, wT, DIM, 0, logits + c0, VOCAB, 0, DIM,
            b_logits + c0, nullptr, 0);
    }
}

// Round 12
// 2314.667 us; speedup vs baseline: 1.2375x; 1.2375x over previous
//
#include <hip/hip_runtime.h>
#include <hip/hip_bf16.h>
#include <math.h>

// Problem constants (from setup_inputs)
#define BB 2
#define NSEQ 1024
#define DIM 1024
#define NH 16
#define DH 64
#define DEPTH 4
#define VOCAB 32000
#define XLM 256
#define MDB 4096
#define TOPK 32
#define KNN_LAYER 2
#define BNROWS (BB * NSEQ)   // 2048
#define LOGITS_CHUNK 6400    // 32000 = 5 * 6400
#define NKEYS 1280           // XLM + NSEQ
#define KSP_PS ((size_t)BB * NKEYS * DH)   // plane stride for K/V split planes

typedef __bf16 bf16x8v __attribute__((ext_vector_type(8)));
typedef float f32x4v __attribute__((ext_vector_type(4)));
typedef unsigned short u16x8v __attribute__((ext_vector_type(8)));

__device__ __forceinline__ float bfbits2f(unsigned short u) {
    union { float f; unsigned int i; } v; v.i = ((unsigned int)u) << 16; return v.f;
}
__device__ __forceinline__ unsigned short f2bfbits(float f) {
    union { __hip_bfloat16 b; unsigned short u; } v;
    v.b = __float2bfloat16(f);
    return v.u;
}
__device__ __forceinline__ float bf2f(__hip_bfloat16 h) { return __bfloat162float(h); }
__device__ __forceinline__ __hip_bfloat16 f2bf(float f) { return __float2bfloat16(f); }

__device__ __forceinline__ void gload16(const void* gp, void* lp) {
    __builtin_amdgcn_global_load_lds(
        (const __attribute__((address_space(1))) unsigned int*)gp,
        (__attribute__((address_space(3))) unsigned int*)lp, 16, 0, 0);
}

// ---------------------------------------------------------------------------
__global__ __launch_bounds__(256) void embed_kernel(const int* __restrict__ tok,
                                                    const float* __restrict__ emb,
                                                    float* __restrict__ x) {
    int r = blockIdx.x, t = threadIdx.x;
    int id = tok[r];
    const float* er = emb + (size_t)id * DIM;
    float* xr = x + (size_t)r * DIM;
#pragma unroll
    for (int i = 0; i < 4; i++) xr[t + 256 * i] = er[t + 256 * i];
}

// ---------------------------------------------------------------------------
// Row LayerNorm over DIM=1024, fp32 in, split-bf16 (hi/lo planes) out
__global__ __launch_bounds__(256) void ln_kernel(const float* __restrict__ x,
                                                 const float* __restrict__ w,
                                                 const float* __restrict__ b,
                                                 __hip_bfloat16* __restrict__ y,
                                                 size_t ypS) {
    __shared__ float red[256];
    int r = blockIdx.x, t = threadIdx.x;
    const float* xr = x + (size_t)r * DIM;
    float v[4];
#pragma unroll
    for (int i = 0; i < 4; i++) v[i] = xr[t + 256 * i];
    float s = v[0] + v[1] + v[2] + v[3];
    red[t] = s; __syncthreads();
    for (int st = 128; st; st >>= 1) { if (t < st) red[t] += red[t + st]; __syncthreads(); }
    float mean = red[0] * (1.0f / DIM);
    __syncthreads();
    float s2 = 0.f;
#pragma unroll
    for (int i = 0; i < 4; i++) { float d = v[i] - mean; s2 += d * d; }
    red[t] = s2; __syncthreads();
    for (int st = 128; st; st >>= 1) { if (t < st) red[t] += red[t + st]; __syncthreads(); }
    float rs = rsqrtf(red[0] * (1.0f / DIM) + 1e-5f);
    __hip_bfloat16* yr = y + (size_t)r * DIM;
#pragma unroll
    for (int i = 0; i < 4; i++) {
        int c = t + 256 * i;
        float val = (v[i] - mean) * rs * w[c] + b[c];
        __hip_bfloat16 hv = f2bf(val);
        yr[c] = hv;
        yr[c + ypS] = f2bf(val - bf2f(hv));
    }
}

// ---------------------------------------------------------------------------
// L2-normalize fp32 rows of length 64 (row stride configurable), in-place
__global__ void l2norm_kernel(float* __restrict__ p, int stride) {
    int r = blockIdx.x, t = threadIdx.x; // 64 threads
    float* pr = p + (size_t)r * stride;
    float v = pr[t];
    float s = v * v;
#pragma unroll
    for (int off = 32; off; off >>= 1) s += __shfl_xor(s, off, 64);
    float n = fmaxf(sqrtf(s), 1e-12f);
    pr[t] = v / n;
}

__global__ void dbnorm_kernel(const float* __restrict__ db, float* __restrict__ dbkn) {
    int r = blockIdx.x, t = threadIdx.x; // 64 threads
    float v = db[((size_t)r * 2 + 0) * DH + t];
    float s = v * v;
#pragma unroll
    for (int off = 32; off; off >>= 1) s += __shfl_xor(s, off, 64);
    float n = fmaxf(sqrtf(s), 1e-12f);
    dbkn[(size_t)r * DH + t] = v / n;
}

// ---------------------------------------------------------------------------
// fp32 -> split-bf16 planes (hi at y, lo at y+pS). n4 = n/4 float4 groups.
__global__ __launch_bounds__(256) void split_conv(const float* __restrict__ x,
                                                  unsigned short* __restrict__ y,
                                                  size_t pS, size_t n4) {
    size_t idx = (size_t)blockIdx.x * 256 + threadIdx.x;
    if (idx >= n4) return;
    float4 v = *(const float4*)&x[idx * 4];
    float vv[4] = {v.x, v.y, v.z, v.w};
    ushort4 h4, l4;
    unsigned short* hp = (unsigned short*)&h4;
    unsigned short* lp = (unsigned short*)&l4;
#pragma unroll
    for (int j = 0; j < 4; j++) {
        hp[j] = f2bfbits(vv[j]);
        lp[j] = f2bfbits(vv[j] - bfbits2f(hp[j]));
    }
    *(ushort4*)&y[idx * 4] = h4;
    *(ushort4*)&y[idx * 4 + pS] = l4;
}

// ---------------------------------------------------------------------------
// Split-K partial combine: out = sum_z p[z*pS] [+bias] [+res]. n4 = M*N/4.
template <int NP>
__global__ __launch_bounds__(256) void combine_k(const float* __restrict__ pbuf, size_t pS,
                                                 float* __restrict__ out,
                                                 const float* __restrict__ bias,
                                                 const float* __restrict__ res,
                                                 int N, size_t n4) {
    size_t idx = (size_t)blockIdx.x * 256 + threadIdx.x;
    if (idx >= n4) return;
    f32x4v s = *(const f32x4v*)&pbuf[idx * 4];
#pragma unroll
    for (int z = 1; z < NP; z++) {
        f32x4v v = *(const f32x4v*)&pbuf[(size_t)z * pS + idx * 4];
        s += v;
    }
    if (bias) {
        int col = (int)((idx * 4) % (size_t)N);
        const f32x4v bv = *(const f32x4v*)&bias[col];
        s += bv;
    }
    if (res) {
        f32x4v r = *(const f32x4v*)&res[idx * 4];
        s += r;
    }
    *(f32x4v*)&out[idx * 4] = s;
}

// ---------------------------------------------------------------------------
// Per-layer K/V split-bf16 prep: K planes [b][key][dim]; V transposed planes
// [b][dim][key]. keys 0..255 from xlm, 256..1279 from fresh kv.
__global__ void kv_prep(const float* __restrict__ kvf, const float* __restrict__ xlm,
                        unsigned short* __restrict__ ksp, unsigned short* __restrict__ vtp) {
    int key = blockIdx.x, b = blockIdx.y, d = threadIdx.x; // 64 threads
    float kvv, vvv;
    if (key < XLM) {
        kvv = xlm[(((size_t)b * XLM + key) * 2 + 0) * DH + d];
        vvv = xlm[(((size_t)b * XLM + key) * 2 + 1) * DH + d];
    } else {
        const float* r = &kvf[(size_t)(b * NSEQ + key - XLM) * 128];
        kvv = r[d]; vvv = r[64 + d];
    }
    unsigned short kh = f2bfbits(kvv), kl = f2bfbits(kvv - bfbits2f(kh));
    unsigned short vh = f2bfbits(vvv), vl = f2bfbits(vvv - bfbits2f(vh));
    size_t ko = (size_t)b * NKEYS * DH + (size_t)key * DH + d;
    ksp[ko] = kh; ksp[ko + KSP_PS] = kl;
    size_t vo = (size_t)b * DH * NKEYS + (size_t)d * NKEYS + key;
    vtp[vo] = vh; vtp[vo + KSP_PS] = vl;
}

// ---------------------------------------------------------------------------
// Weight convert + transpose: W (K x N fp32, row stride ldw) ->
// WT (N x K split-bf16, hi plane + lo plane at +wpS). wlo=0: hi only.
__global__ __launch_bounds__(256) void wconv(const float* __restrict__ W,
                                             __hip_bfloat16* __restrict__ WT,
                                             size_t wpS, int K, int N, int ldw,
                                             int wlo) {
    __shared__ float tile[64][65];
    int k0 = blockIdx.x * 64, n0 = blockIdx.y * 64;
    int t = threadIdx.x;
    int r = t >> 4, c4 = (t & 15) * 4;
#pragma unroll
    for (int rr = 0; rr < 4; rr++) {
        int row = rr * 16 + r;
        float4 v = *(const float4*)&W[(size_t)(k0 + row) * ldw + n0 + c4];
        tile[row][c4] = v.x; tile[row][c4 + 1] = v.y; tile[row][c4 + 2] = v.z; tile[row][c4 + 3] = v.w;
    }
    __syncthreads();
#pragma unroll
    for (int rr = 0; rr < 4; rr++) {
        int nrow = rr * 16 + r;
        size_t base = (size_t)(n0 + nrow) * K + k0 + c4;
#pragma unroll
        for (int j = 0; j < 4; j++) {
            float val = tile[c4 + j][nrow];
            __hip_bfloat16 hv = f2bf(val);
            WT[base + j] = hv;
            if (wlo) WT[base + j + wpS] = f2bf(val - bf2f(hv));
        }
    }
}

// ---------------------------------------------------------------------------
// Split-bf16 MFMA GEMM: C(MxN) = A(MxK) @ BT(NxK)^T with A,B as hi/lo planes.
// TERMS: 3 = hi*hi + lo*hi + hi*lo (fp32-grade); 1 = hi*hi only (bf16-grade).
// OT: float / __hip_bfloat16 (split 2-plane) / unsigned short (single bf16).
// MODE: 0 = normal; 1 = simdb batch over bh (z dim);
//       2 = split-K (z = K-slice; K param is the slice length; partial
//           written to C + z*cpS; bias/res must be null).
template <typename OT, int ACT, int TERMS, int MODE>
__global__ __launch_bounds__(256) void gemm_split(const __hip_bfloat16* __restrict__ A, int lda, size_t apS,
                                                  const __hip_bfloat16* __restrict__ BT, int ldb, size_t bpS,
                                                  OT* __restrict__ C, int ldc, size_t cpS, int K,
                                                  const float* __restrict__ bias,
                                                  const float* __restrict__ res,
                                                  int bh0) {
    __shared__ __align__(16) __hip_bfloat16 sAh[128 * 32];
    __shared__ __align__(16) __hip_bfloat16 sBh[128 * 32];
    __shared__ __align__(16) __hip_bfloat16 sAl[TERMS >= 2 ? 128 * 32 : 1];
    __shared__ __align__(16) __hip_bfloat16 sBl[TERMS >= 3 ? 128 * 32 : 1];
    if constexpr (MODE == 1) {
        int bh = bh0 + blockIdx.z;
        A += ((size_t)(bh >> 4) * NSEQ) * lda + (bh & 15) * DH;
        BT += (size_t)(bh >> 4) * MDB * ldb;
        C += (size_t)blockIdx.z * NSEQ * ldc;
    }
    if constexpr (MODE == 2) {
        A += (size_t)blockIdx.z * K;
        BT += (size_t)blockIdx.z * K;
        C += (size_t)blockIdx.z * cpS;
    }
    int bn = blockIdx.x * 128;
    int bm = blockIdx.y * 128;
    int t = threadIdx.x;
    int lane = t & 63, wid = t >> 6;
    int wr = wid >> 1, wc = wid & 1;
    int lr = lane & 15, kc = lane >> 4;

    f32x4v acc[4][4];
#pragma unroll
    for (int m = 0; m < 4; m++)
#pragma unroll
        for (int n = 0; n < 4; n++) acc[m][n] = (f32x4v){0.f, 0.f, 0.f, 0.f};

    for (int k0 = 0; k0 < K; k0 += 32) {
        __syncthreads();
#pragma unroll
        for (int it = 0; it < 2; it++) {
            int e = wid * 128 + it * 64 + lane;
            int r = e >> 2;
            int cl = (e & 3) ^ ((r >> 1) & 3);
            size_t aoff = (size_t)(bm + r) * lda + k0 + cl * 8;
            size_t boff = (size_t)(bn + r) * ldb + k0 + cl * 8;
            int dst = (wid * 128 + it * 64) * 8;
            gload16(&A[aoff], &sAh[dst]);
            gload16(&BT[boff], &sBh[dst]);
            if constexpr (TERMS >= 2) gload16(&A[aoff + apS], &sAl[dst]);
            if constexpr (TERMS >= 3) gload16(&BT[boff + bpS], &sBl[dst]);
        }
        __syncthreads();

        bf16x8v ah[4], al[4], bh[4], bl[4];
#pragma unroll
        for (int m = 0; m < 4; m++) {
            int row = wr * 64 + m * 16 + lr;
            int off = row * 32 + ((kc ^ ((row >> 1) & 3)) << 3);
            ah[m] = *(const bf16x8v*)&sAh[off];
            if constexpr (TERMS >= 2) al[m] = *(const bf16x8v*)&sAl[off];
        }
#pragma unroll
        for (int n = 0; n < 4; n++) {
            int row = wc * 64 + n * 16 + lr;
            int off = row * 32 + ((kc ^ ((row >> 1) & 3)) << 3);
            bh[n] = *(const bf16x8v*)&sBh[off];
            if constexpr (TERMS >= 3) bl[n] = *(const bf16x8v*)&sBl[off];
        }
#pragma unroll
        for (int m = 0; m < 4; m++)
#pragma unroll
            for (int n = 0; n < 4; n++) {
                acc[m][n] = __builtin_amdgcn_mfma_f32_16x16x32_bf16(ah[m], bh[n], acc[m][n], 0, 0, 0);
                if constexpr (TERMS >= 2)
                    acc[m][n] = __builtin_amdgcn_mfma_f32_16x16x32_bf16(al[m], bh[n], acc[m][n], 0, 0, 0);
                if constexpr (TERMS >= 3)
                    acc[m][n] = __builtin_amdgcn_mfma_f32_16x16x32_bf16(ah[m], bl[n], acc[m][n], 0, 0, 0);
            }
    }

#pragma unroll
    for (int m = 0; m < 4; m++) {
#pragma unroll
        for (int n = 0; n < 4; n++) {
            int gcol = bn + wc * 64 + n * 16 + lr;
            float bv = bias ? bias[gcol] : 0.f;
#pragma unroll
            for (int j = 0; j < 4; j++) {
                int grow = bm + wr * 64 + m * 16 + kc * 4 + j;
                float v = acc[m][n][j] + bv;
                if (ACT == 1) v = 0.5f * v * (1.0f + erff(v * 0.70710678118654752f));
                if (res) v += res[(size_t)grow * ldc + gcol];
                size_t idx = (size_t)grow * ldc + gcol;
                if constexpr (__is_same(OT, float)) {
                    C[idx] = v;
                } else if constexpr (__is_same(OT, unsigned short)) {
                    C[idx] = f2bfbits(v);
                } else {
                    __hip_bfloat16 hv = f2bf(v);
                    C[idx] = hv;
                    C[idx + cpS] = f2bf(v - bf2f(hv));
                }
            }
        }
    }
}

// ---------------------------------------------------------------------------
// Split-bf16 MFMA flash attention over XL + causal local keys.
// K/V pre-split by kv_prep; staging is pure global_load_lds.
template <int KNNL>
__global__ __launch_bounds__(256) void flash_kernel(const float* __restrict__ q,
                                                    const unsigned short* __restrict__ ksp,
                                                    const unsigned short* __restrict__ vtp,
                                                    const float* __restrict__ knn_scale,
                                                    __hip_bfloat16* __restrict__ out,
                                                    size_t opS,
                                                    float* __restrict__ stats) {
    __shared__ __align__(16) unsigned short sKh[64 * 64];
    __shared__ __align__(16) unsigned short sKl[64 * 64];
    __shared__ __align__(16) unsigned short sVh[64 * 64];   // transposed [dim][key]
    __shared__ __align__(16) unsigned short sVl[64 * 64];
    __shared__ __align__(16) float sPf[4 * 16 * 64];        // per-wave P fp32

    int qt = blockIdx.x, h = blockIdx.y, b = blockIdx.z;
    int q0 = qt * 64;
    int t = threadIdx.x;
    int w = t >> 6;
    int lane = t & 63;
    int lr = lane & 15, kc = lane >> 4;
    int wbase = w * 1024;

    float scale = KNNL ? __expf(knn_scale[h]) : 0.125f;

    bf16x8v qh[2], ql[2];
    {
        const float* qbase = q + (size_t)(b * NSEQ + q0 + w * 16 + lr) * DIM + h * DH;
#pragma unroll
        for (int ks = 0; ks < 2; ks++) {
            const float* s = qbase + ks * 32 + kc * 8;
            float4 a = *(const float4*)s;
            float4 c2 = *(const float4*)(s + 4);
            float vv[8] = {a.x, a.y, a.z, a.w, c2.x, c2.y, c2.z, c2.w};
            u16x8v hi, lo;
#pragma unroll
            for (int j = 0; j < 8; j++) {
                hi[j] = f2bfbits(vv[j]);
                lo[j] = f2bfbits(vv[j] - bfbits2f(hi[j]));
            }
            qh[ks] = *(bf16x8v*)&hi;
            ql[ks] = *(bf16x8v*)&lo;
        }
    }

    float m[4], l[4];
    f32x4v o[4];
#pragma unroll
    for (int j = 0; j < 4; j++) { m[j] = -1e30f; l[j] = 0.f; }
#pragma unroll
    for (int f = 0; f < 4; f++) o[f] = (f32x4v){0.f, 0.f, 0.f, 0.f};

    int ntiles = 5 + qt;
    size_t kbase = (size_t)b * NKEYS * DH;
    size_t vbase = (size_t)b * DH * NKEYS;

    for (int T = 0; T < ntiles; T++) {
        __syncthreads();
        // ---- stage K + Vt planes via global_load_lds (512 16B-chunks each)
#pragma unroll
        for (int i2 = 0; i2 < 2; i2++) {
            int cbase = i2 * 256 + w * 64;
            int c = cbase + lane;
            int key = c >> 3, ch = (c & 7) ^ (key & 7);
            size_t ko = kbase + (size_t)(T * 64 + key) * DH + ch * 8;
            gload16(&ksp[ko], &sKh[cbase * 8]);
            gload16(&ksp[ko + KSP_PS], &sKl[cbase * 8]);
            int dim = c >> 3, k8 = (c & 7) ^ (dim & 7);
            size_t vo = vbase + (size_t)dim * NKEYS + T * 64 + k8 * 8;
            gload16(&vtp[vo], &sVh[cbase * 8]);
            gload16(&vtp[vo + KSP_PS], &sVl[cbase * 8]);
        }
        __syncthreads();

        f32x4v s4[4];
#pragma unroll
        for (int n = 0; n < 4; n++) s4[n] = (f32x4v){0.f, 0.f, 0.f, 0.f};
#pragma unroll
        for (int ks = 0; ks < 2; ks++) {
            bf16x8v qh_ = qh[ks], ql_ = ql[ks];
#pragma unroll
            for (int n = 0; n < 4; n++) {
                int row = n * 16 + lr;
                int off = row * 64 + (((ks * 4 + kc) ^ (lr & 7)) << 3);
                bf16x8v kh = *(const bf16x8v*)&sKh[off];
                bf16x8v kl = *(const bf16x8v*)&sKl[off];
                s4[n] = __builtin_amdgcn_mfma_f32_16x16x32_bf16(qh_, kh, s4[n], 0, 0, 0);
                s4[n] = __builtin_amdgcn_mfma_f32_16x16x32_bf16(ql_, kh, s4[n], 0, 0, 0);
                s4[n] = __builtin_amdgcn_mfma_f32_16x16x32_bf16(qh_, kl, s4[n], 0, 0, 0);
            }
        }

#pragma unroll
        for (int n = 0; n < 4; n++) {
            int key = T * 64 + n * 16 + lr;
#pragma unroll
            for (int j = 0; j < 4; j++) {
                int gq = q0 + w * 16 + kc * 4 + j;
                float sv = s4[n][j] * scale;
                s4[n][j] = (key <= XLM + gq) ? sv : -1e30f;
            }
        }

        float tm[4];
#pragma unroll
        for (int j = 0; j < 4; j++) {
            float v = fmaxf(fmaxf(s4[0][j], s4[1][j]), fmaxf(s4[2][j], s4[3][j]));
            v = fmaxf(v, __shfl_xor(v, 1, 64));
            v = fmaxf(v, __shfl_xor(v, 2, 64));
            v = fmaxf(v, __shfl_xor(v, 4, 64));
            v = fmaxf(v, __shfl_xor(v, 8, 64));
            tm[j] = v;
        }
        float alpha[4];
#pragma unroll
        for (int j = 0; j < 4; j++) {
            float mnew = fmaxf(m[j], tm[j]);
            alpha[j] = __expf(m[j] - mnew);
            m[j] = mnew;
        }
        float psum[4] = {0.f, 0.f, 0.f, 0.f};
#pragma unroll
        for (int n = 0; n < 4; n++)
#pragma unroll
            for (int j = 0; j < 4; j++) {
                float p = __expf(s4[n][j] - m[j]);
                s4[n][j] = p;
                psum[j] += p;
            }
#pragma unroll
        for (int j = 0; j < 4; j++) {
            float v = psum[j];
            v += __shfl_xor(v, 1, 64);
            v += __shfl_xor(v, 2, 64);
            v += __shfl_xor(v, 4, 64);
            v += __shfl_xor(v, 8, 64);
            l[j] = l[j] * alpha[j] + v;
        }
#pragma unroll
        for (int f = 0; f < 4; f++)
#pragma unroll
            for (int j = 0; j < 4; j++) o[f][j] *= alpha[j];

#pragma unroll
        for (int n = 0; n < 4; n++) {
            int chunkcol = 2 * n + (lr >> 3);
#pragma unroll
            for (int j = 0; j < 4; j++) {
                int row = kc * 4 + j;
                int off = wbase + row * 64 + (((chunkcol ^ (row & 7)) << 3) + (lr & 7));
                sPf[off] = s4[n][j];
            }
        }

#pragma unroll
        for (int ks = 0; ks < 2; ks++) {
            int poff = wbase + lr * 64 + (((ks * 4 + kc) ^ (lr & 7)) << 3);
            float4 a = *(const float4*)&sPf[poff];
            float4 c2 = *(const float4*)&sPf[poff + 4];
            float vv[8] = {a.x, a.y, a.z, a.w, c2.x, c2.y, c2.z, c2.w};
            u16x8v hib, lob;
#pragma unroll
            for (int j = 0; j < 8; j++) {
                hib[j] = f2bfbits(vv[j]);
                lob[j] = f2bfbits(vv[j] - bfbits2f(hib[j]));
            }
            bf16x8v ph = *(bf16x8v*)&hib;
            bf16x8v pl = *(bf16x8v*)&lob;
#pragma unroll
            for (int f = 0; f < 4; f++) {
                int row = f * 16 + lr;
                int off = row * 64 + (((ks * 4 + kc) ^ (lr & 7)) << 3);
                bf16x8v vh = *(const bf16x8v*)&sVh[off];
                bf16x8v vl = *(const bf16x8v*)&sVl[off];
                o[f] = __builtin_amdgcn_mfma_f32_16x16x32_bf16(ph, vh, o[f], 0, 0, 0);
                o[f] = __builtin_amdgcn_mfma_f32_16x16x32_bf16(pl, vh, o[f], 0, 0, 0);
                o[f] = __builtin_amdgcn_mfma_f32_16x16x32_bf16(ph, vl, o[f], 0, 0, 0);
            }
        }
    }

    float inv[4];
#pragma unroll
    for (int j = 0; j < 4; j++) inv[j] = 1.0f / l[j];
    unsigned short* outu = (unsigned short*)out;
#pragma unroll
    for (int f = 0; f < 4; f++)
#pragma unroll
        for (int j = 0; j < 4; j++) {
            int gq = q0 + w * 16 + kc * 4 + j;
            size_t oidx = (size_t)(b * NSEQ + gq) * DIM + h * DH + f * 16 + lr;
            float v = o[f][j] * inv[j];
            unsigned short hv = f2bfbits(v);
            outu[oidx] = hv;
            outu[oidx + opS] = f2bfbits(v - bfbits2f(hv));
        }
    if (KNNL && lr == 0) {
#pragma unroll
        for (int j = 0; j < 4; j++) {
            int gq = q0 + w * 16 + kc * 4 + j;
            size_t srow = (((size_t)b * NH + h) * NSEQ + gq) * 2;
            stats[srow] = m[j];
            stats[srow + 1] = l[j];
        }
    }
}

// ---------------------------------------------------------------------------
// Per-row top-32 over bf16 simdb + exact recompute + mem softmax + combine.
// 4 waves per block, ONE ROW PER WAVE (no idle waves, no barriers).
// Per-wave 8KB LDS slab, chunk-of-8 XOR swizzle: element (c,l) of the row
// (c=chunk 0..63, l=0..63) at u16 index c*64 + (l ^ ((c&7)<<3)).
__global__ __launch_bounds__(256) void knn_select(const unsigned short* __restrict__ simdb,
                                                  const float* __restrict__ db,
                                                  const float* __restrict__ qf,
                                                  const float* __restrict__ dbkn,
                                                  const float* __restrict__ knn_scale,
                                                  const float* __restrict__ stats,
                                                  __hip_bfloat16* __restrict__ out,
                                                  size_t opS,
                                                  int bh0) {
    __shared__ unsigned short sv[4 * 4096];

    int bh = bh0 + blockIdx.y;
    int b = bh >> 4, h = bh & 15;
    int t = threadIdx.x;
    int w = t >> 6, lane = t & 63;
    int i = blockIdx.x * 4 + w;
    unsigned short* svw = &sv[w * 4096];

    // stage this wave's row: 512 16B-chunks / 64 lanes = 8 iters
    const unsigned short* srow = &simdb[((size_t)blockIdx.y * NSEQ + i) * MDB];
#pragma unroll
    for (int it = 0; it < 8; it++) {
        int g = it * 64 + lane;
        int c = g >> 3, sub = g & 7;
        u16x8v d = *(const u16x8v*)&srow[(size_t)g * 8];
        *(u16x8v*)&svw[c * 64 + ((sub ^ (c & 7)) << 3)] = d;
    }

    // per-column candidates: lane owns column l, scans 64 chunks
    float lmax = -1e30f; int lidx = 0;
#pragma unroll
    for (int c = 0; c < 64; c++) {
        float v = bfbits2f(svw[c * 64 + (lane ^ ((c & 7) << 3))]);
        if (v > lmax) { lmax = v; lidx = c * 64 + lane; }
    }

    // 32 selection iterations, wave-synchronous
    int tidx = 0;
    for (int it = 0; it < TOPK; it++) {
        float v = lmax; int idx = lidx;
#pragma unroll
        for (int off = 32; off; off >>= 1) {
            float v2 = __shfl_xor(v, off, 64);
            int i2 = __shfl_xor(idx, off, 64);
            if (v2 > v || (v2 == v && i2 < idx)) { v = v2; idx = i2; }
        }
        if (lane == it) tidx = idx;
        int col = idx & 63, cc = idx >> 6;
        if (lane == 0) svw[cc * 64 + (col ^ ((cc & 7) << 3))] = 0xFF80; // bf16 -inf
        // rescan column col: lane reads element (c=lane, col)
        float rv = bfbits2f(svw[lane * 64 + (col ^ ((lane & 7) << 3))]);
        int ridx = lane * 64 + col;
#pragma unroll
        for (int off = 32; off; off >>= 1) {
            float v2 = __shfl_xor(rv, off, 64);
            int i2 = __shfl_xor(ridx, off, 64);
            if (v2 > rv || (v2 == rv && i2 < ridx)) { rv = v2; ridx = i2; }
        }
        if (lane == col) { lmax = rv; lidx = ridx; }
    }

    // exact recompute of selected sims (lane j < 32 recomputes sim of its idx)
    float srec = -1e30f;
    if (lane < TOPK) {
        const float* qrow = &qf[(size_t)(b * NSEQ + i) * DIM + h * DH];
        const float* krow = &dbkn[((size_t)b * MDB + tidx) * DH];
        float s = 0.f;
#pragma unroll
        for (int d4 = 0; d4 < 16; d4++) {
            float4 a = *(const float4*)&qrow[d4 * 4];
            float4 k2 = *(const float4*)&krow[d4 * 4];
            s += a.x * k2.x + a.y * k2.y + a.z * k2.z + a.w * k2.w;
        }
        srec = s;
    }

    float scl = __expf(knn_scale[h]);
    size_t srow_idx = (((size_t)b * NH + h) * NSEQ + i) * 2;
    float m_loc = stats[srow_idx], l_loc = stats[srow_idx + 1];
    float mm = srec;
#pragma unroll
    for (int off = 32; off; off >>= 1) mm = fmaxf(mm, __shfl_xor(mm, off, 64));
    float M = fmaxf(m_loc, mm * scl);
    float co = __expf(m_loc - M);
    float e = (lane < TOPK) ? __expf(srec * scl - M) : 0.f;
    float esum = e;
#pragma unroll
    for (int off = 32; off; off >>= 1) esum += __shfl_xor(esum, off, 64);
    float denom = l_loc * co + esum;

    // gather: lane = output dim; iterate 32 selected keys via shfl broadcast
    float acc = 0.f;
#pragma unroll
    for (int j = 0; j < TOPK; j++) {
        int idxj = __shfl(tidx, j, 64);
        float ej = __shfl(e, j, 64);
        acc += ej * db[(((size_t)b * MDB + idxj) * 2 + 1) * DH + lane];
    }

    size_t op = (size_t)(b * NSEQ + i) * DIM + h * DH + lane;
    float o_loc = bf2f(out[op]) + bf2f(out[op + opS]);
    float nv = (o_loc * l_loc * co + acc) / denom;
    __hip_bfloat16 hv = f2bf(nv);
    out[op] = hv;
    out[op + opS] = f2bf(nv - bf2f(hv));
}

// ---------------------------------------------------------------------------
extern "C" void kernel_launch(void* const* d_in, const int* in_sizes, int n_in,
                              void* d_out, int out_size, void* d_ws, size_t ws_size,
                              hipStream_t stream) {
    const int* tokens = (const int*)d_in[0];
    const float* emb = (const float*)d_in[1];
    const float* ln1_w = (const float*)d_in[2];
    const float* ln1_b = (const float*)d_in[3];
    const float* wq = (const float*)d_in[4];
    const float* wkv = (const float*)d_in[5];
    const float* wo = (const float*)d_in[6];
    const float* wo_b = (const float*)d_in[7];
    const float* knn_scale = (const float*)d_in[8];
    const float* ln2_w = (const float*)d_in[9];
    const float* ln2_b = (const float*)d_in[10];
    const float* ff_w1 = (const float*)d_in[11];
    const float* ff_b1 = (const float*)d_in[12];
    const float* ff_w2 = (const float*)d_in[13];
    const float* ff_b2 = (const float*)d_in[14];
    const float* lnf_w = (const float*)d_in[15];
    const float* lnf_b = (const float*)d_in[16];
    const float* w_logits = (const float*)d_in[17];
    const float* b_logits = (const float*)d_in[18];
    const float* xl_mems = (const float*)d_in[19];
    const float* db_kv = (const float*)d_in[20];

    // ---- workspace layout ----
    const size_t PS_H = (size_t)BNROWS * DIM;        // plane stride for h / attn-out
    char* p = (char*)d_ws;
    float* x = (float*)p;                p += PS_H * 4;                        // 8 MB
    __hip_bfloat16* hb = (__hip_bfloat16*)p;  p += PS_H * 2 * 2;               // 8 MB (2 planes)
    float* qf = (float*)p;               p += PS_H * 4;                        // 8 MB
    float* kvf = (float*)p;              p += (size_t)BNROWS * 128 * 4;        // 1 MB
    float* dbkn = (float*)p;             p += (size_t)BB * MDB * DH * 4;       // 2 MB
    float* stats = (float*)p;            p += (size_t)BB * NH * NSEQ * 2 * 4;  // 0.25 MB
    unsigned short* ksp = (unsigned short*)p; p += KSP_PS * 2 * 2;             // 0.66 MB
    unsigned short* vtp = (unsigned short*)p; p += KSP_PS * 2 * 2;             // 0.66 MB
    __hip_bfloat16* wT = (__hip_bfloat16*)p; p += (size_t)4096 * DIM * 2 * 2;  // 16 MB (2 planes)

    // qsplit/dbkn-split live in the wT region during the KNN phase (wT idle)
    unsigned short* qsplit = (unsigned short*)wT;                  // 2 planes x PS_H
    unsigned short* dbks = (unsigned short*)wT + 2 * PS_H;         // 2 planes x BB*MDB*DH
    const size_t PS_DB = (size_t)BB * MDB * DH;

    const size_t PS_MID = (size_t)BNROWS * 4 * DIM;  // 8M elems per plane
    __hip_bfloat16* midb = (__hip_bfloat16*)d_out;   // 32 MB of the 262 MB out buf
    float* logits = (float*)d_out;
    // split-K partial buffers: d_out + 64 MB (past midb/simdb regions; every
    // partial is consumed by its combine before any other use of the region)
    float* part = (float*)((char*)d_out + ((size_t)64 << 20));

    embed_kernel<<<BNROWS, 256, 0, stream>>>(tokens, emb, x);
    dbnorm_kernel<<<BB * MDB, 64, 0, stream>>>(db_kv, dbkn);

    for (int l = 0; l < DEPTH; l++) {
        const float* wq_l = wq + (size_t)l * DIM * DIM;
        const float* wkv_l = wkv + (size_t)l * DIM * 128;
        const float* wo_l = wo + (size_t)l * DIM * DIM;
        const float* xlm_l = xl_mems + (size_t)l * BB * XLM * 2 * DH;

        // h = LN1(x) -> split bf16
        ln_kernel<<<BNROWS, 256, 0, stream>>>(x, ln1_w + (size_t)l * DIM, ln1_b + (size_t)l * DIM, hb, PS_H);

        // q = h @ wq  (split-K=2, fp32 partials -> combine)
        wconv<<<dim3(16, 16), 256, 0, stream>>>(wq_l, wT, (size_t)DIM * DIM, DIM, DIM, DIM, 1);
        gemm_split<float, 0, 3, 2><<<dim3(DIM / 128, BNROWS / 128, 2), 256, 0, stream>>>(
            hb, DIM, PS_H, wT, DIM, (size_t)DIM * DIM, part, DIM, PS_H, 512, nullptr, nullptr, 0);
        combine_k<2><<<(PS_H / 4 + 255) / 256, 256, 0, stream>>>(
            part, PS_H, qf, nullptr, nullptr, DIM, PS_H / 4);
        // kv = h @ wkv (split-K=8)
        wconv<<<dim3(16, 2), 256, 0, stream>>>(wkv_l, wT, (size_t)128 * DIM, DIM, 128, 128, 1);
        gemm_split<float, 0, 3, 2><<<dim3(1, BNROWS / 128, 8), 256, 0, stream>>>(
            hb, DIM, PS_H, wT, DIM, (size_t)128 * DIM, part, 128, (size_t)BNROWS * 128, 128, nullptr, nullptr, 0);
        combine_k<8><<<((size_t)BNROWS * 128 / 4 + 255) / 256, 256, 0, stream>>>(
            part, (size_t)BNROWS * 128, kvf, nullptr, nullptr, 128, (size_t)BNROWS * 128 / 4);

        if (l == KNN_LAYER) {
            l2norm_kernel<<<BNROWS * NH, 64, 0, stream>>>(qf, DH);
            l2norm_kernel<<<BNROWS, 64, 0, stream>>>(kvf, 128);
            kv_prep<<<dim3(NKEYS, BB), 64, 0, stream>>>(kvf, xlm_l, ksp, vtp);
            split_conv<<<(PS_H / 4 + 255) / 256, 256, 0, stream>>>(qf, qsplit, PS_H, PS_H / 4);
            split_conv<<<(PS_DB / 4 + 255) / 256, 256, 0, stream>>>(dbkn, dbks, PS_DB, PS_DB / 4);
            flash_kernel<1><<<dim3(NSEQ / 64, NH, BB), 256, 0, stream>>>(
                qf, ksp, vtp, knn_scale, hb, PS_H, stats);
            // CHUNK=8: 8 slices x 8 MB bf16 = 67 MB per gemm->select pair
            // (L3-resident), 4 pairs total.
            const int CHUNK = 8;
            for (int bh0 = 0; bh0 < BB * NH; bh0 += CHUNK) {
                gemm_split<unsigned short, 0, 3, 1><<<dim3(MDB / 128, NSEQ / 128, CHUNK), 256, 0, stream>>>(
                    (const __hip_bfloat16*)qsplit, DIM, PS_H,
                    (const __hip_bfloat16*)dbks, DH, PS_DB,
                    (unsigned short*)d_out, MDB, 0, DH, nullptr, nullptr, bh0);
                knn_select<<<dim3(NSEQ / 4, CHUNK), 256, 0, stream>>>(
                    (const unsigned short*)d_out, db_kv, qf, dbkn, knn_scale, stats, hb, PS_H, bh0);
            }
        } else {
            kv_prep<<<dim3(NKEYS, BB), 64, 0, stream>>>(kvf, xlm_l, ksp, vtp);
            flash_kernel<0><<<dim3(NSEQ / 64, NH, BB), 256, 0, stream>>>(
                qf, ksp, vtp, knn_scale, hb, PS_H, stats);
        }

        // x = attn @ wo + wo_b + x  (split-K=2)
        wconv<<<dim3(16, 16), 256, 0, stream>>>(wo_l, wT, (size_t)DIM * DIM, DIM, DIM, DIM, 1);
        gemm_split<float, 0, 3, 2><<<dim3(DIM / 128, BNROWS / 128, 2), 256, 0, stream>>>(
            hb, DIM, PS_H, wT, DIM, (size_t)DIM * DIM, part, DIM, PS_H, 512, nullptr, nullptr, 0);
        combine_k<2><<<(PS_H / 4 + 255) / 256, 256, 0, stream>>>(
            part, PS_H, x, wo_b + (size_t)l * DIM, x, DIM, PS_H / 4);

        // h = LN2(x)
        ln_kernel<<<BNROWS, 256, 0, stream>>>(x, ln2_w + (size_t)l * DIM, ln2_b + (size_t)l * DIM, hb, PS_H);
        // mid = gelu(h @ ff_w1 + b1) -> split bf16 (in d_out)
        wconv<<<dim3(16, 64), 256, 0, stream>>>(ff_w1 + (size_t)l * DIM * 4 * DIM, wT, (size_t)4096 * DIM, DIM, 4 * DIM, 4 * DIM, 1);
        gemm_split<__hip_bfloat16, 1, 3, 0><<<dim3(4 * DIM / 128, BNROWS / 128), 256, 0, stream>>>(
            hb, DIM, PS_H, wT, DIM, (size_t)4096 * DIM, midb, 4 * DIM, PS_MID, DIM,
            ff_b1 + (size_t)l * 4 * DIM, nullptr, 0);
        // x = mid @ ff_w2 + b2 + x  (split-K=2 over K=4096)
        wconv<<<dim3(64, 16), 256, 0, stream>>>(ff_w2 + (size_t)l * 4 * DIM * DIM, wT, (size_t)DIM * 4096, 4 * DIM, DIM, DIM, 1);
        gemm_split<float, 0, 3, 2><<<dim3(DIM / 128, BNROWS / 128, 2), 256, 0, stream>>>(
            midb, 4 * DIM, PS_MID, wT, 4 * DIM, (size_t)DIM * 4096, part, DIM, PS_H, 2048, nullptr, nullptr, 0);
        combine_k<2><<<(PS_H / 4 + 255) / 256, 256, 0, stream>>>(
            part, PS_H, x, ff_b2 + (size_t)l * DIM, x, DIM, PS_H / 4);
    }

    // final LN + logits (5 column chunks of 6400, hi-plane-only bf16 GEMM)
    ln_kernel<<<BNROWS, 256, 0, stream>>>(x, lnf_w, lnf_b, hb, PS_H);
    for (int c0 = 0; c0 < VOCAB; c0 += LOGITS_CHUNK) {
        wconv<<<dim3(16, LOGITS_CHUNK / 64), 256, 0, stream>>>(
            w_logits + c0, wT, 0, DIM, LOGITS_CHUNK, VOCAB, 0);
        gemm_split<float, 0, 1, 0><<<dim3(LOGITS_CHUNK / 128, BNROWS / 128), 256, 0, stream>>>(
            hb, DIM, PS_H, wT, DIM, 0, logits + c0, VOCAB, 0, DIM,
            b_logits + c0, nullptr, 0);
    }
}

// Round 13
// 2275.591 us; speedup vs baseline: 1.2587x; 1.0172x over previous
//
#include <hip/hip_runtime.h>
#include <hip/hip_bf16.h>
#include <math.h>

// Problem constants (from setup_inputs)
#define BB 2
#define NSEQ 1024
#define DIM 1024
#define NH 16
#define DH 64
#define DEPTH 4
#define VOCAB 32000
#define XLM 256
#define MDB 4096
#define TOPK 32
#define KNN_LAYER 2
#define BNROWS (BB * NSEQ)   // 2048
#define LOGITS_CHUNK 6400    // 32000 = 5 * 6400
#define NKEYS 1280           // XLM + NSEQ
#define KSP_PS ((size_t)BB * NKEYS * DH)   // plane stride for K/V split planes

typedef __bf16 bf16x8v __attribute__((ext_vector_type(8)));
typedef float f32x4v __attribute__((ext_vector_type(4)));
typedef unsigned short u16x8v __attribute__((ext_vector_type(8)));

__device__ __forceinline__ float bfbits2f(unsigned short u) {
    union { float f; unsigned int i; } v; v.i = ((unsigned int)u) << 16; return v.f;
}
__device__ __forceinline__ unsigned short f2bfbits(float f) {
    union { __hip_bfloat16 b; unsigned short u; } v;
    v.b = __float2bfloat16(f);
    return v.u;
}
__device__ __forceinline__ float bf2f(__hip_bfloat16 h) { return __bfloat162float(h); }
__device__ __forceinline__ __hip_bfloat16 f2bf(float f) { return __float2bfloat16(f); }

__device__ __forceinline__ void gload16(const void* gp, void* lp) {
    __builtin_amdgcn_global_load_lds(
        (const __attribute__((address_space(1))) unsigned int*)gp,
        (__attribute__((address_space(3))) unsigned int*)lp, 16, 0, 0);
}

// ---------------------------------------------------------------------------
__global__ __launch_bounds__(256) void embed_kernel(const int* __restrict__ tok,
                                                    const float* __restrict__ emb,
                                                    float* __restrict__ x) {
    int r = blockIdx.x, t = threadIdx.x;
    int id = tok[r];
    const float* er = emb + (size_t)id * DIM;
    float* xr = x + (size_t)r * DIM;
#pragma unroll
    for (int i = 0; i < 4; i++) xr[t + 256 * i] = er[t + 256 * i];
}

// ---------------------------------------------------------------------------
// Row LayerNorm over DIM=1024, fp32 in, split-bf16 (hi/lo planes) out
__global__ __launch_bounds__(256) void ln_kernel(const float* __restrict__ x,
                                                 const float* __restrict__ w,
                                                 const float* __restrict__ b,
                                                 __hip_bfloat16* __restrict__ y,
                                                 size_t ypS) {
    __shared__ float red[256];
    int r = blockIdx.x, t = threadIdx.x;
    const float* xr = x + (size_t)r * DIM;
    float v[4];
#pragma unroll
    for (int i = 0; i < 4; i++) v[i] = xr[t + 256 * i];
    float s = v[0] + v[1] + v[2] + v[3];
    red[t] = s; __syncthreads();
    for (int st = 128; st; st >>= 1) { if (t < st) red[t] += red[t + st]; __syncthreads(); }
    float mean = red[0] * (1.0f / DIM);
    __syncthreads();
    float s2 = 0.f;
#pragma unroll
    for (int i = 0; i < 4; i++) { float d = v[i] - mean; s2 += d * d; }
    red[t] = s2; __syncthreads();
    for (int st = 128; st; st >>= 1) { if (t < st) red[t] += red[t + st]; __syncthreads(); }
    float rs = rsqrtf(red[0] * (1.0f / DIM) + 1e-5f);
    __hip_bfloat16* yr = y + (size_t)r * DIM;
#pragma unroll
    for (int i = 0; i < 4; i++) {
        int c = t + 256 * i;
        float val = (v[i] - mean) * rs * w[c] + b[c];
        __hip_bfloat16 hv = f2bf(val);
        yr[c] = hv;
        yr[c + ypS] = f2bf(val - bf2f(hv));
    }
}

// ---------------------------------------------------------------------------
// Fused split-K combine + residual + LayerNorm:
// x[r,:] += sum_z part[z] + bias;  y = LN(x[r,:]) as split-bf16 planes.
template <int NP>
__global__ __launch_bounds__(256) void combine_ln(const float* __restrict__ pbuf, size_t pS,
                                                  const float* __restrict__ bias,
                                                  float* __restrict__ x,
                                                  const float* __restrict__ w,
                                                  const float* __restrict__ b,
                                                  __hip_bfloat16* __restrict__ y,
                                                  size_t ypS) {
    __shared__ float red[256];
    int r = blockIdx.x, t = threadIdx.x;
    float v[4];
#pragma unroll
    for (int i = 0; i < 4; i++) {
        int c = t + 256 * i;
        size_t idx = (size_t)r * DIM + c;
        float s = bias[c] + x[idx];
#pragma unroll
        for (int z = 0; z < NP; z++) s += pbuf[(size_t)z * pS + idx];
        v[i] = s;
        x[idx] = s;
    }
    float s = v[0] + v[1] + v[2] + v[3];
    red[t] = s; __syncthreads();
    for (int st = 128; st; st >>= 1) { if (t < st) red[t] += red[t + st]; __syncthreads(); }
    float mean = red[0] * (1.0f / DIM);
    __syncthreads();
    float s2 = 0.f;
#pragma unroll
    for (int i = 0; i < 4; i++) { float d = v[i] - mean; s2 += d * d; }
    red[t] = s2; __syncthreads();
    for (int st = 128; st; st >>= 1) { if (t < st) red[t] += red[t + st]; __syncthreads(); }
    float rs = rsqrtf(red[0] * (1.0f / DIM) + 1e-5f);
    __hip_bfloat16* yr = y + (size_t)r * DIM;
#pragma unroll
    for (int i = 0; i < 4; i++) {
        int c = t + 256 * i;
        float val = (v[i] - mean) * rs * w[c] + b[c];
        __hip_bfloat16 hv = f2bf(val);
        yr[c] = hv;
        yr[c + ypS] = f2bf(val - bf2f(hv));
    }
}

// ---------------------------------------------------------------------------
// L2-normalize fp32 rows of length 64 (row stride configurable), in-place
__global__ void l2norm_kernel(float* __restrict__ p, int stride) {
    int r = blockIdx.x, t = threadIdx.x; // 64 threads
    float* pr = p + (size_t)r * stride;
    float v = pr[t];
    float s = v * v;
#pragma unroll
    for (int off = 32; off; off >>= 1) s += __shfl_xor(s, off, 64);
    float n = fmaxf(sqrtf(s), 1e-12f);
    pr[t] = v / n;
}

__global__ void dbnorm_kernel(const float* __restrict__ db, float* __restrict__ dbkn) {
    int r = blockIdx.x, t = threadIdx.x; // 64 threads
    float v = db[((size_t)r * 2 + 0) * DH + t];
    float s = v * v;
#pragma unroll
    for (int off = 32; off; off >>= 1) s += __shfl_xor(s, off, 64);
    float n = fmaxf(sqrtf(s), 1e-12f);
    dbkn[(size_t)r * DH + t] = v / n;
}

// ---------------------------------------------------------------------------
// fp32 -> split-bf16 planes (hi at y, lo at y+pS). n4 = n/4 float4 groups.
__global__ __launch_bounds__(256) void split_conv(const float* __restrict__ x,
                                                  unsigned short* __restrict__ y,
                                                  size_t pS, size_t n4) {
    size_t idx = (size_t)blockIdx.x * 256 + threadIdx.x;
    if (idx >= n4) return;
    float4 v = *(const float4*)&x[idx * 4];
    float vv[4] = {v.x, v.y, v.z, v.w};
    ushort4 h4, l4;
    unsigned short* hp = (unsigned short*)&h4;
    unsigned short* lp = (unsigned short*)&l4;
#pragma unroll
    for (int j = 0; j < 4; j++) {
        hp[j] = f2bfbits(vv[j]);
        lp[j] = f2bfbits(vv[j] - bfbits2f(hp[j]));
    }
    *(ushort4*)&y[idx * 4] = h4;
    *(ushort4*)&y[idx * 4 + pS] = l4;
}

// ---------------------------------------------------------------------------
// Split-K partial combine: out = sum_z p[z*pS] [+bias] [+res]. n4 = M*N/4.
template <int NP>
__global__ __launch_bounds__(256) void combine_k(const float* __restrict__ pbuf, size_t pS,
                                                 float* __restrict__ out,
                                                 const float* __restrict__ bias,
                                                 const float* __restrict__ res,
                                                 int N, size_t n4) {
    size_t idx = (size_t)blockIdx.x * 256 + threadIdx.x;
    if (idx >= n4) return;
    f32x4v s = *(const f32x4v*)&pbuf[idx * 4];
#pragma unroll
    for (int z = 1; z < NP; z++) {
        f32x4v v = *(const f32x4v*)&pbuf[(size_t)z * pS + idx * 4];
        s += v;
    }
    if (bias) {
        int col = (int)((idx * 4) % (size_t)N);
        const f32x4v bv = *(const f32x4v*)&bias[col];
        s += bv;
    }
    if (res) {
        f32x4v r = *(const f32x4v*)&res[idx * 4];
        s += r;
    }
    *(f32x4v*)&out[idx * 4] = s;
}

// ---------------------------------------------------------------------------
// Split-K combine + bias + exact GELU + split-bf16 plane write (for ff1).
template <int NP>
__global__ __launch_bounds__(256) void combine_gelu_split(const float* __restrict__ pbuf, size_t pS,
                                                          const float* __restrict__ bias, int N,
                                                          unsigned short* __restrict__ y, size_t ypS,
                                                          size_t n4) {
    size_t idx = (size_t)blockIdx.x * 256 + threadIdx.x;
    if (idx >= n4) return;
    f32x4v s = *(const f32x4v*)&pbuf[idx * 4];
#pragma unroll
    for (int z = 1; z < NP; z++) {
        f32x4v v = *(const f32x4v*)&pbuf[(size_t)z * pS + idx * 4];
        s += v;
    }
    int col = (int)((idx * 4) % (size_t)N);
    const f32x4v bv = *(const f32x4v*)&bias[col];
    s += bv;
    ushort4 h4, l4;
    unsigned short* hp = (unsigned short*)&h4;
    unsigned short* lp = (unsigned short*)&l4;
#pragma unroll
    for (int j = 0; j < 4; j++) {
        float v = s[j];
        v = 0.5f * v * (1.0f + erff(v * 0.70710678118654752f));
        hp[j] = f2bfbits(v);
        lp[j] = f2bfbits(v - bfbits2f(hp[j]));
    }
    *(ushort4*)&y[idx * 4] = h4;
    *(ushort4*)&y[idx * 4 + ypS] = l4;
}

// ---------------------------------------------------------------------------
// Per-layer K/V split-bf16 prep: K planes [b][key][dim]; V transposed planes
// [b][dim][key]. keys 0..255 from xlm, 256..1279 from fresh kv.
__global__ void kv_prep(const float* __restrict__ kvf, const float* __restrict__ xlm,
                        unsigned short* __restrict__ ksp, unsigned short* __restrict__ vtp) {
    int key = blockIdx.x, b = blockIdx.y, d = threadIdx.x; // 64 threads
    float kvv, vvv;
    if (key < XLM) {
        kvv = xlm[(((size_t)b * XLM + key) * 2 + 0) * DH + d];
        vvv = xlm[(((size_t)b * XLM + key) * 2 + 1) * DH + d];
    } else {
        const float* r = &kvf[(size_t)(b * NSEQ + key - XLM) * 128];
        kvv = r[d]; vvv = r[64 + d];
    }
    unsigned short kh = f2bfbits(kvv), kl = f2bfbits(kvv - bfbits2f(kh));
    unsigned short vh = f2bfbits(vvv), vl = f2bfbits(vvv - bfbits2f(vh));
    size_t ko = (size_t)b * NKEYS * DH + (size_t)key * DH + d;
    ksp[ko] = kh; ksp[ko + KSP_PS] = kl;
    size_t vo = (size_t)b * DH * NKEYS + (size_t)d * NKEYS + key;
    vtp[vo] = vh; vtp[vo + KSP_PS] = vl;
}

// ---------------------------------------------------------------------------
// Weight convert + transpose: W (K x N fp32, row stride ldw) ->
// WT (N x K split-bf16, hi plane + lo plane at +wpS). wlo=0: hi only.
__global__ __launch_bounds__(256) void wconv(const float* __restrict__ W,
                                             __hip_bfloat16* __restrict__ WT,
                                             size_t wpS, int K, int N, int ldw,
                                             int wlo) {
    __shared__ float tile[64][65];
    int k0 = blockIdx.x * 64, n0 = blockIdx.y * 64;
    int t = threadIdx.x;
    int r = t >> 4, c4 = (t & 15) * 4;
#pragma unroll
    for (int rr = 0; rr < 4; rr++) {
        int row = rr * 16 + r;
        float4 v = *(const float4*)&W[(size_t)(k0 + row) * ldw + n0 + c4];
        tile[row][c4] = v.x; tile[row][c4 + 1] = v.y; tile[row][c4 + 2] = v.z; tile[row][c4 + 3] = v.w;
    }
    __syncthreads();
#pragma unroll
    for (int rr = 0; rr < 4; rr++) {
        int nrow = rr * 16 + r;
        size_t base = (size_t)(n0 + nrow) * K + k0 + c4;
#pragma unroll
        for (int j = 0; j < 4; j++) {
            float val = tile[c4 + j][nrow];
            __hip_bfloat16 hv = f2bf(val);
            WT[base + j] = hv;
            if (wlo) WT[base + j + wpS] = f2bf(val - bf2f(hv));
        }
    }
}

// ---------------------------------------------------------------------------
// Split-bf16 MFMA GEMM: C(MxN) = A(MxK) @ BT(NxK)^T with A,B as hi/lo planes.
// TERMS: 3 = hi*hi + lo*hi + hi*lo (fp32-grade); 1 = hi*hi only (bf16-grade).
// OT: float / __hip_bfloat16 (split 2-plane) / unsigned short (single bf16).
// MODE: 0 = normal; 1 = simdb batch over bh (z dim);
//       2 = split-K (z = K-slice; K param is the slice length; partial
//           written to C + z*cpS; bias/res must be null).
template <typename OT, int ACT, int TERMS, int MODE>
__global__ __launch_bounds__(256) void gemm_split(const __hip_bfloat16* __restrict__ A, int lda, size_t apS,
                                                  const __hip_bfloat16* __restrict__ BT, int ldb, size_t bpS,
                                                  OT* __restrict__ C, int ldc, size_t cpS, int K,
                                                  const float* __restrict__ bias,
                                                  const float* __restrict__ res,
                                                  int bh0) {
    __shared__ __align__(16) __hip_bfloat16 sAh[128 * 32];
    __shared__ __align__(16) __hip_bfloat16 sBh[128 * 32];
    __shared__ __align__(16) __hip_bfloat16 sAl[TERMS >= 2 ? 128 * 32 : 1];
    __shared__ __align__(16) __hip_bfloat16 sBl[TERMS >= 3 ? 128 * 32 : 1];
    if constexpr (MODE == 1) {
        int bh = bh0 + blockIdx.z;
        A += ((size_t)(bh >> 4) * NSEQ) * lda + (bh & 15) * DH;
        BT += (size_t)(bh >> 4) * MDB * ldb;
        C += (size_t)blockIdx.z * NSEQ * ldc;
    }
    if constexpr (MODE == 2) {
        A += (size_t)blockIdx.z * K;
        BT += (size_t)blockIdx.z * K;
        C += (size_t)blockIdx.z * cpS;
    }
    int bn = blockIdx.x * 128;
    int bm = blockIdx.y * 128;
    int t = threadIdx.x;
    int lane = t & 63, wid = t >> 6;
    int wr = wid >> 1, wc = wid & 1;
    int lr = lane & 15, kc = lane >> 4;

    f32x4v acc[4][4];
#pragma unroll
    for (int m = 0; m < 4; m++)
#pragma unroll
        for (int n = 0; n < 4; n++) acc[m][n] = (f32x4v){0.f, 0.f, 0.f, 0.f};

    for (int k0 = 0; k0 < K; k0 += 32) {
        __syncthreads();
#pragma unroll
        for (int it = 0; it < 2; it++) {
            int e = wid * 128 + it * 64 + lane;
            int r = e >> 2;
            int cl = (e & 3) ^ ((r >> 1) & 3);
            size_t aoff = (size_t)(bm + r) * lda + k0 + cl * 8;
            size_t boff = (size_t)(bn + r) * ldb + k0 + cl * 8;
            int dst = (wid * 128 + it * 64) * 8;
            gload16(&A[aoff], &sAh[dst]);
            gload16(&BT[boff], &sBh[dst]);
            if constexpr (TERMS >= 2) gload16(&A[aoff + apS], &sAl[dst]);
            if constexpr (TERMS >= 3) gload16(&BT[boff + bpS], &sBl[dst]);
        }
        __syncthreads();

        bf16x8v ah[4], al[4], bh[4], bl[4];
#pragma unroll
        for (int m = 0; m < 4; m++) {
            int row = wr * 64 + m * 16 + lr;
            int off = row * 32 + ((kc ^ ((row >> 1) & 3)) << 3);
            ah[m] = *(const bf16x8v*)&sAh[off];
            if constexpr (TERMS >= 2) al[m] = *(const bf16x8v*)&sAl[off];
        }
#pragma unroll
        for (int n = 0; n < 4; n++) {
            int row = wc * 64 + n * 16 + lr;
            int off = row * 32 + ((kc ^ ((row >> 1) & 3)) << 3);
            bh[n] = *(const bf16x8v*)&sBh[off];
            if constexpr (TERMS >= 3) bl[n] = *(const bf16x8v*)&sBl[off];
        }
#pragma unroll
        for (int m = 0; m < 4; m++)
#pragma unroll
            for (int n = 0; n < 4; n++) {
                acc[m][n] = __builtin_amdgcn_mfma_f32_16x16x32_bf16(ah[m], bh[n], acc[m][n], 0, 0, 0);
                if constexpr (TERMS >= 2)
                    acc[m][n] = __builtin_amdgcn_mfma_f32_16x16x32_bf16(al[m], bh[n], acc[m][n], 0, 0, 0);
                if constexpr (TERMS >= 3)
                    acc[m][n] = __builtin_amdgcn_mfma_f32_16x16x32_bf16(ah[m], bl[n], acc[m][n], 0, 0, 0);
            }
    }

#pragma unroll
    for (int m = 0; m < 4; m++) {
#pragma unroll
        for (int n = 0; n < 4; n++) {
            int gcol = bn + wc * 64 + n * 16 + lr;
            float bv = bias ? bias[gcol] : 0.f;
#pragma unroll
            for (int j = 0; j < 4; j++) {
                int grow = bm + wr * 64 + m * 16 + kc * 4 + j;
                float v = acc[m][n][j] + bv;
                if (ACT == 1) v = 0.5f * v * (1.0f + erff(v * 0.70710678118654752f));
                if (res) v += res[(size_t)grow * ldc + gcol];
                size_t idx = (size_t)grow * ldc + gcol;
                if constexpr (__is_same(OT, float)) {
                    C[idx] = v;
                } else if constexpr (__is_same(OT, unsigned short)) {
                    C[idx] = f2bfbits(v);
                } else {
                    __hip_bfloat16 hv = f2bf(v);
                    C[idx] = hv;
                    C[idx + cpS] = f2bf(v - bf2f(hv));
                }
            }
        }
    }
}

// ---------------------------------------------------------------------------
// Split-bf16 MFMA flash attention over XL + causal local keys.
// K/V pre-split by kv_prep; staging is pure global_load_lds.
template <int KNNL>
__global__ __launch_bounds__(256) void flash_kernel(const float* __restrict__ q,
                                                    const unsigned short* __restrict__ ksp,
                                                    const unsigned short* __restrict__ vtp,
                                                    const float* __restrict__ knn_scale,
                                                    __hip_bfloat16* __restrict__ out,
                                                    size_t opS,
                                                    float* __restrict__ stats) {
    __shared__ __align__(16) unsigned short sKh[64 * 64];
    __shared__ __align__(16) unsigned short sKl[64 * 64];
    __shared__ __align__(16) unsigned short sVh[64 * 64];   // transposed [dim][key]
    __shared__ __align__(16) unsigned short sVl[64 * 64];
    __shared__ __align__(16) float sPf[4 * 16 * 64];        // per-wave P fp32

    int qt = blockIdx.x, h = blockIdx.y, b = blockIdx.z;
    int q0 = qt * 64;
    int t = threadIdx.x;
    int w = t >> 6;
    int lane = t & 63;
    int lr = lane & 15, kc = lane >> 4;
    int wbase = w * 1024;

    float scale = KNNL ? __expf(knn_scale[h]) : 0.125f;

    bf16x8v qh[2], ql[2];
    {
        const float* qbase = q + (size_t)(b * NSEQ + q0 + w * 16 + lr) * DIM + h * DH;
#pragma unroll
        for (int ks = 0; ks < 2; ks++) {
            const float* s = qbase + ks * 32 + kc * 8;
            float4 a = *(const float4*)s;
            float4 c2 = *(const float4*)(s + 4);
            float vv[8] = {a.x, a.y, a.z, a.w, c2.x, c2.y, c2.z, c2.w};
            u16x8v hi, lo;
#pragma unroll
            for (int j = 0; j < 8; j++) {
                hi[j] = f2bfbits(vv[j]);
                lo[j] = f2bfbits(vv[j] - bfbits2f(hi[j]));
            }
            qh[ks] = *(bf16x8v*)&hi;
            ql[ks] = *(bf16x8v*)&lo;
        }
    }

    float m[4], l[4];
    f32x4v o[4];
#pragma unroll
    for (int j = 0; j < 4; j++) { m[j] = -1e30f; l[j] = 0.f; }
#pragma unroll
    for (int f = 0; f < 4; f++) o[f] = (f32x4v){0.f, 0.f, 0.f, 0.f};

    int ntiles = 5 + qt;
    size_t kbase = (size_t)b * NKEYS * DH;
    size_t vbase = (size_t)b * DH * NKEYS;

    for (int T = 0; T < ntiles; T++) {
        __syncthreads();
        // ---- stage K + Vt planes via global_load_lds (512 16B-chunks each)
#pragma unroll
        for (int i2 = 0; i2 < 2; i2++) {
            int cbase = i2 * 256 + w * 64;
            int c = cbase + lane;
            int key = c >> 3, ch = (c & 7) ^ (key & 7);
            size_t ko = kbase + (size_t)(T * 64 + key) * DH + ch * 8;
            gload16(&ksp[ko], &sKh[cbase * 8]);
            gload16(&ksp[ko + KSP_PS], &sKl[cbase * 8]);
            int dim = c >> 3, k8 = (c & 7) ^ (dim & 7);
            size_t vo = vbase + (size_t)dim * NKEYS + T * 64 + k8 * 8;
            gload16(&vtp[vo], &sVh[cbase * 8]);
            gload16(&vtp[vo + KSP_PS], &sVl[cbase * 8]);
        }
        __syncthreads();

        f32x4v s4[4];
#pragma unroll
        for (int n = 0; n < 4; n++) s4[n] = (f32x4v){0.f, 0.f, 0.f, 0.f};
#pragma unroll
        for (int ks = 0; ks < 2; ks++) {
            bf16x8v qh_ = qh[ks], ql_ = ql[ks];
#pragma unroll
            for (int n = 0; n < 4; n++) {
                int row = n * 16 + lr;
                int off = row * 64 + (((ks * 4 + kc) ^ (lr & 7)) << 3);
                bf16x8v kh = *(const bf16x8v*)&sKh[off];
                bf16x8v kl = *(const bf16x8v*)&sKl[off];
                s4[n] = __builtin_amdgcn_mfma_f32_16x16x32_bf16(qh_, kh, s4[n], 0, 0, 0);
                s4[n] = __builtin_amdgcn_mfma_f32_16x16x32_bf16(ql_, kh, s4[n], 0, 0, 0);
                s4[n] = __builtin_amdgcn_mfma_f32_16x16x32_bf16(qh_, kl, s4[n], 0, 0, 0);
            }
        }

#pragma unroll
        for (int n = 0; n < 4; n++) {
            int key = T * 64 + n * 16 + lr;
#pragma unroll
            for (int j = 0; j < 4; j++) {
                int gq = q0 + w * 16 + kc * 4 + j;
                float sv = s4[n][j] * scale;
                s4[n][j] = (key <= XLM + gq) ? sv : -1e30f;
            }
        }

        float tm[4];
#pragma unroll
        for (int j = 0; j < 4; j++) {
            float v = fmaxf(fmaxf(s4[0][j], s4[1][j]), fmaxf(s4[2][j], s4[3][j]));
            v = fmaxf(v, __shfl_xor(v, 1, 64));
            v = fmaxf(v, __shfl_xor(v, 2, 64));
            v = fmaxf(v, __shfl_xor(v, 4, 64));
            v = fmaxf(v, __shfl_xor(v, 8, 64));
            tm[j] = v;
        }
        float alpha[4];
#pragma unroll
        for (int j = 0; j < 4; j++) {
            float mnew = fmaxf(m[j], tm[j]);
            alpha[j] = __expf(m[j] - mnew);
            m[j] = mnew;
        }
        float psum[4] = {0.f, 0.f, 0.f, 0.f};
#pragma unroll
        for (int n = 0; n < 4; n++)
#pragma unroll
            for (int j = 0; j < 4; j++) {
                float p = __expf(s4[n][j] - m[j]);
                s4[n][j] = p;
                psum[j] += p;
            }
#pragma unroll
        for (int j = 0; j < 4; j++) {
            float v = psum[j];
            v += __shfl_xor(v, 1, 64);
            v += __shfl_xor(v, 2, 64);
            v += __shfl_xor(v, 4, 64);
            v += __shfl_xor(v, 8, 64);
            l[j] = l[j] * alpha[j] + v;
        }
#pragma unroll
        for (int f = 0; f < 4; f++)
#pragma unroll
            for (int j = 0; j < 4; j++) o[f][j] *= alpha[j];

#pragma unroll
        for (int n = 0; n < 4; n++) {
            int chunkcol = 2 * n + (lr >> 3);
#pragma unroll
            for (int j = 0; j < 4; j++) {
                int row = kc * 4 + j;
                int off = wbase + row * 64 + (((chunkcol ^ (row & 7)) << 3) + (lr & 7));
                sPf[off] = s4[n][j];
            }
        }

#pragma unroll
        for (int ks = 0; ks < 2; ks++) {
            int poff = wbase + lr * 64 + (((ks * 4 + kc) ^ (lr & 7)) << 3);
            float4 a = *(const float4*)&sPf[poff];
            float4 c2 = *(const float4*)&sPf[poff + 4];
            float vv[8] = {a.x, a.y, a.z, a.w, c2.x, c2.y, c2.z, c2.w};
            u16x8v hib, lob;
#pragma unroll
            for (int j = 0; j < 8; j++) {
                hib[j] = f2bfbits(vv[j]);
                lob[j] = f2bfbits(vv[j] - bfbits2f(hib[j]));
            }
            bf16x8v ph = *(bf16x8v*)&hib;
            bf16x8v pl = *(bf16x8v*)&lob;
#pragma unroll
            for (int f = 0; f < 4; f++) {
                int row = f * 16 + lr;
                int off = row * 64 + (((ks * 4 + kc) ^ (lr & 7)) << 3);
                bf16x8v vh = *(const bf16x8v*)&sVh[off];
                bf16x8v vl = *(const bf16x8v*)&sVl[off];
                o[f] = __builtin_amdgcn_mfma_f32_16x16x32_bf16(ph, vh, o[f], 0, 0, 0);
                o[f] = __builtin_amdgcn_mfma_f32_16x16x32_bf16(pl, vh, o[f], 0, 0, 0);
                o[f] = __builtin_amdgcn_mfma_f32_16x16x32_bf16(ph, vl, o[f], 0, 0, 0);
            }
        }
    }

    float inv[4];
#pragma unroll
    for (int j = 0; j < 4; j++) inv[j] = 1.0f / l[j];
    unsigned short* outu = (unsigned short*)out;
#pragma unroll
    for (int f = 0; f < 4; f++)
#pragma unroll
        for (int j = 0; j < 4; j++) {
            int gq = q0 + w * 16 + kc * 4 + j;
            size_t oidx = (size_t)(b * NSEQ + gq) * DIM + h * DH + f * 16 + lr;
            float v = o[f][j] * inv[j];
            unsigned short hv = f2bfbits(v);
            outu[oidx] = hv;
            outu[oidx + opS] = f2bfbits(v - bfbits2f(hv));
        }
    if (KNNL && lr == 0) {
#pragma unroll
        for (int j = 0; j < 4; j++) {
            int gq = q0 + w * 16 + kc * 4 + j;
            size_t srow = (((size_t)b * NH + h) * NSEQ + gq) * 2;
            stats[srow] = m[j];
            stats[srow + 1] = l[j];
        }
    }
}

// ---------------------------------------------------------------------------
// Per-row top-32 over bf16 simdb + exact recompute + mem softmax + combine.
// 4 waves per block, ONE ROW PER WAVE (no idle waves, no barriers).
__global__ __launch_bounds__(256) void knn_select(const unsigned short* __restrict__ simdb,
                                                  const float* __restrict__ db,
                                                  const float* __restrict__ qf,
                                                  const float* __restrict__ dbkn,
                                                  const float* __restrict__ knn_scale,
                                                  const float* __restrict__ stats,
                                                  __hip_bfloat16* __restrict__ out,
                                                  size_t opS,
                                                  int bh0) {
    __shared__ unsigned short sv[4 * 4096];

    int bh = bh0 + blockIdx.y;
    int b = bh >> 4, h = bh & 15;
    int t = threadIdx.x;
    int w = t >> 6, lane = t & 63;
    int i = blockIdx.x * 4 + w;
    unsigned short* svw = &sv[w * 4096];

    // stage this wave's row: 512 16B-chunks / 64 lanes = 8 iters
    const unsigned short* srow = &simdb[((size_t)blockIdx.y * NSEQ + i) * MDB];
#pragma unroll
    for (int it = 0; it < 8; it++) {
        int g = it * 64 + lane;
        int c = g >> 3, sub = g & 7;
        u16x8v d = *(const u16x8v*)&srow[(size_t)g * 8];
        *(u16x8v*)&svw[c * 64 + ((sub ^ (c & 7)) << 3)] = d;
    }

    // per-column candidates: lane owns column l, scans 64 chunks
    float lmax = -1e30f; int lidx = 0;
#pragma unroll
    for (int c = 0; c < 64; c++) {
        float v = bfbits2f(svw[c * 64 + (lane ^ ((c & 7) << 3))]);
        if (v > lmax) { lmax = v; lidx = c * 64 + lane; }
    }

    // 32 selection iterations, wave-synchronous
    int tidx = 0;
    for (int it = 0; it < TOPK; it++) {
        float v = lmax; int idx = lidx;
#pragma unroll
        for (int off = 32; off; off >>= 1) {
            float v2 = __shfl_xor(v, off, 64);
            int i2 = __shfl_xor(idx, off, 64);
            if (v2 > v || (v2 == v && i2 < idx)) { v = v2; idx = i2; }
        }
        if (lane == it) tidx = idx;
        int col = idx & 63, cc = idx >> 6;
        if (lane == 0) svw[cc * 64 + (col ^ ((cc & 7) << 3))] = 0xFF80; // bf16 -inf
        // rescan column col: lane reads element (c=lane, col)
        float rv = bfbits2f(svw[lane * 64 + (col ^ ((lane & 7) << 3))]);
        int ridx = lane * 64 + col;
#pragma unroll
        for (int off = 32; off; off >>= 1) {
            float v2 = __shfl_xor(rv, off, 64);
            int i2 = __shfl_xor(ridx, off, 64);
            if (v2 > rv || (v2 == rv && i2 < ridx)) { rv = v2; ridx = i2; }
        }
        if (lane == col) { lmax = rv; lidx = ridx; }
    }

    // exact recompute of selected sims (lane j < 32 recomputes sim of its idx)
    float srec = -1e30f;
    if (lane < TOPK) {
        const float* qrow = &qf[(size_t)(b * NSEQ + i) * DIM + h * DH];
        const float* krow = &dbkn[((size_t)b * MDB + tidx) * DH];
        float s = 0.f;
#pragma unroll
        for (int d4 = 0; d4 < 16; d4++) {
            float4 a = *(const float4*)&qrow[d4 * 4];
            float4 k2 = *(const float4*)&krow[d4 * 4];
            s += a.x * k2.x + a.y * k2.y + a.z * k2.z + a.w * k2.w;
        }
        srec = s;
    }

    float scl = __expf(knn_scale[h]);
    size_t srow_idx = (((size_t)b * NH + h) * NSEQ + i) * 2;
    float m_loc = stats[srow_idx], l_loc = stats[srow_idx + 1];
    float mm = srec;
#pragma unroll
    for (int off = 32; off; off >>= 1) mm = fmaxf(mm, __shfl_xor(mm, off, 64));
    float M = fmaxf(m_loc, mm * scl);
    float co = __expf(m_loc - M);
    float e = (lane < TOPK) ? __expf(srec * scl - M) : 0.f;
    float esum = e;
#pragma unroll
    for (int off = 32; off; off >>= 1) esum += __shfl_xor(esum, off, 64);
    float denom = l_loc * co + esum;

    // gather: lane = output dim; iterate 32 selected keys via shfl broadcast
    float acc = 0.f;
#pragma unroll
    for (int j = 0; j < TOPK; j++) {
        int idxj = __shfl(tidx, j, 64);
        float ej = __shfl(e, j, 64);
        acc += ej * db[(((size_t)b * MDB + idxj) * 2 + 1) * DH + lane];
    }

    size_t op = (size_t)(b * NSEQ + i) * DIM + h * DH + lane;
    float o_loc = bf2f(out[op]) + bf2f(out[op + opS]);
    float nv = (o_loc * l_loc * co + acc) / denom;
    __hip_bfloat16 hv = f2bf(nv);
    out[op] = hv;
    out[op + opS] = f2bf(nv - bf2f(hv));
}

// ---------------------------------------------------------------------------
extern "C" void kernel_launch(void* const* d_in, const int* in_sizes, int n_in,
                              void* d_out, int out_size, void* d_ws, size_t ws_size,
                              hipStream_t stream) {
    const int* tokens = (const int*)d_in[0];
    const float* emb = (const float*)d_in[1];
    const float* ln1_w = (const float*)d_in[2];
    const float* ln1_b = (const float*)d_in[3];
    const float* wq = (const float*)d_in[4];
    const float* wkv = (const float*)d_in[5];
    const float* wo = (const float*)d_in[6];
    const float* wo_b = (const float*)d_in[7];
    const float* knn_scale = (const float*)d_in[8];
    const float* ln2_w = (const float*)d_in[9];
    const float* ln2_b = (const float*)d_in[10];
    const float* ff_w1 = (const float*)d_in[11];
    const float* ff_b1 = (const float*)d_in[12];
    const float* ff_w2 = (const float*)d_in[13];
    const float* ff_b2 = (const float*)d_in[14];
    const float* lnf_w = (const float*)d_in[15];
    const float* lnf_b = (const float*)d_in[16];
    const float* w_logits = (const float*)d_in[17];
    const float* b_logits = (const float*)d_in[18];
    const float* xl_mems = (const float*)d_in[19];
    const float* db_kv = (const float*)d_in[20];

    // ---- workspace layout ----
    const size_t PS_H = (size_t)BNROWS * DIM;        // plane stride for h / attn-out
    char* p = (char*)d_ws;
    float* x = (float*)p;                p += PS_H * 4;                        // 8 MB
    __hip_bfloat16* hb = (__hip_bfloat16*)p;  p += PS_H * 2 * 2;               // 8 MB (2 planes)
    float* qf = (float*)p;               p += PS_H * 4;                        // 8 MB
    float* kvf = (float*)p;              p += (size_t)BNROWS * 128 * 4;        // 1 MB
    float* dbkn = (float*)p;             p += (size_t)BB * MDB * DH * 4;       // 2 MB
    float* stats = (float*)p;            p += (size_t)BB * NH * NSEQ * 2 * 4;  // 0.25 MB
    unsigned short* ksp = (unsigned short*)p; p += KSP_PS * 2 * 2;             // 0.66 MB
    unsigned short* vtp = (unsigned short*)p; p += KSP_PS * 2 * 2;             // 0.66 MB
    __hip_bfloat16* wT = (__hip_bfloat16*)p; p += (size_t)4096 * DIM * 2 * 2;  // 16 MB (2 planes)

    // qsplit/dbkn-split live in the wT region during the KNN phase (wT idle)
    unsigned short* qsplit = (unsigned short*)wT;                  // 2 planes x PS_H
    unsigned short* dbks = (unsigned short*)wT + 2 * PS_H;         // 2 planes x BB*MDB*DH
    const size_t PS_DB = (size_t)BB * MDB * DH;

    const size_t PS_MID = (size_t)BNROWS * 4 * DIM;  // 8M elems per plane
    __hip_bfloat16* midb = (__hip_bfloat16*)d_out;   // 32 MB of the 262 MB out buf
    float* logits = (float*)d_out;
    // split-K partial buffers: d_out + 96 MB (clear of simdb 0..67MB and midb)
    float* part = (float*)((char*)d_out + ((size_t)96 << 20));

    embed_kernel<<<BNROWS, 256, 0, stream>>>(tokens, emb, x);
    dbnorm_kernel<<<BB * MDB, 64, 0, stream>>>(db_kv, dbkn);
    // first LN (later LNs are fused into combine_ln)
    ln_kernel<<<BNROWS, 256, 0, stream>>>(x, ln1_w, ln1_b, hb, PS_H);

    for (int l = 0; l < DEPTH; l++) {
        const float* wq_l = wq + (size_t)l * DIM * DIM;
        const float* wkv_l = wkv + (size_t)l * DIM * 128;
        const float* wo_l = wo + (size_t)l * DIM * DIM;
        const float* xlm_l = xl_mems + (size_t)l * BB * XLM * 2 * DH;

        // q = h @ wq  (split-K=4 -> combine)
        wconv<<<dim3(16, 16), 256, 0, stream>>>(wq_l, wT, (size_t)DIM * DIM, DIM, DIM, DIM, 1);
        gemm_split<float, 0, 3, 2><<<dim3(DIM / 128, BNROWS / 128, 4), 256, 0, stream>>>(
            hb, DIM, PS_H, wT, DIM, (size_t)DIM * DIM, part, DIM, PS_H, 256, nullptr, nullptr, 0);
        combine_k<4><<<(PS_H / 4 + 255) / 256, 256, 0, stream>>>(
            part, PS_H, qf, nullptr, nullptr, DIM, PS_H / 4);
        // kv = h @ wkv (split-K=16)
        wconv<<<dim3(16, 2), 256, 0, stream>>>(wkv_l, wT, (size_t)128 * DIM, DIM, 128, 128, 1);
        gemm_split<float, 0, 3, 2><<<dim3(1, BNROWS / 128, 16), 256, 0, stream>>>(
            hb, DIM, PS_H, wT, DIM, (size_t)128 * DIM, part, 128, (size_t)BNROWS * 128, 64, nullptr, nullptr, 0);
        combine_k<16><<<((size_t)BNROWS * 128 / 4 + 255) / 256, 256, 0, stream>>>(
            part, (size_t)BNROWS * 128, kvf, nullptr, nullptr, 128, (size_t)BNROWS * 128 / 4);

        if (l == KNN_LAYER) {
            l2norm_kernel<<<BNROWS * NH, 64, 0, stream>>>(qf, DH);
            l2norm_kernel<<<BNROWS, 64, 0, stream>>>(kvf, 128);
            kv_prep<<<dim3(NKEYS, BB), 64, 0, stream>>>(kvf, xlm_l, ksp, vtp);
            split_conv<<<(PS_H / 4 + 255) / 256, 256, 0, stream>>>(qf, qsplit, PS_H, PS_H / 4);
            split_conv<<<(PS_DB / 4 + 255) / 256, 256, 0, stream>>>(dbkn, dbks, PS_DB, PS_DB / 4);
            flash_kernel<1><<<dim3(NSEQ / 64, NH, BB), 256, 0, stream>>>(
                qf, ksp, vtp, knn_scale, hb, PS_H, stats);
            const int CHUNK = 8;  // 8 x 8 MB bf16 = 67 MB per gemm->select pair
            for (int bh0 = 0; bh0 < BB * NH; bh0 += CHUNK) {
                gemm_split<unsigned short, 0, 3, 1><<<dim3(MDB / 128, NSEQ / 128, CHUNK), 256, 0, stream>>>(
                    (const __hip_bfloat16*)qsplit, DIM, PS_H,
                    (const __hip_bfloat16*)dbks, DH, PS_DB,
                    (unsigned short*)d_out, MDB, 0, DH, nullptr, nullptr, bh0);
                knn_select<<<dim3(NSEQ / 4, CHUNK), 256, 0, stream>>>(
                    (const unsigned short*)d_out, db_kv, qf, dbkn, knn_scale, stats, hb, PS_H, bh0);
            }
        } else {
            kv_prep<<<dim3(NKEYS, BB), 64, 0, stream>>>(kvf, xlm_l, ksp, vtp);
            flash_kernel<0><<<dim3(NSEQ / 64, NH, BB), 256, 0, stream>>>(
                qf, ksp, vtp, knn_scale, hb, PS_H, stats);
        }

        // x = attn @ wo + wo_b + x; h = LN2(x)   (split-K=4 + fused combine+LN)
        wconv<<<dim3(16, 16), 256, 0, stream>>>(wo_l, wT, (size_t)DIM * DIM, DIM, DIM, DIM, 1);
        gemm_split<float, 0, 3, 2><<<dim3(DIM / 128, BNROWS / 128, 4), 256, 0, stream>>>(
            hb, DIM, PS_H, wT, DIM, (size_t)DIM * DIM, part, DIM, PS_H, 256, nullptr, nullptr, 0);
        combine_ln<4><<<BNROWS, 256, 0, stream>>>(
            part, PS_H, wo_b + (size_t)l * DIM, x,
            ln2_w + (size_t)l * DIM, ln2_b + (size_t)l * DIM, hb, PS_H);

        // mid = gelu(h @ ff_w1 + b1)  (split-K=2 + fused combine+gelu+split)
        wconv<<<dim3(16, 64), 256, 0, stream>>>(ff_w1 + (size_t)l * DIM * 4 * DIM, wT, (size_t)4096 * DIM, DIM, 4 * DIM, 4 * DIM, 1);
        gemm_split<float, 0, 3, 2><<<dim3(4 * DIM / 128, BNROWS / 128, 2), 256, 0, stream>>>(
            hb, DIM, PS_H, wT, DIM, (size_t)4096 * DIM, part, 4 * DIM, PS_MID, 512, nullptr, nullptr, 0);
        combine_gelu_split<2><<<(PS_MID / 4 + 255) / 256, 256, 0, stream>>>(
            part, PS_MID, ff_b1 + (size_t)l * 4 * DIM, 4 * DIM,
            (unsigned short*)midb, PS_MID, PS_MID / 4);

        // x = mid @ ff_w2 + b2 + x; h = LN_next(x)  (split-K=4 + fused)
        wconv<<<dim3(64, 16), 256, 0, stream>>>(ff_w2 + (size_t)l * 4 * DIM * DIM, wT, (size_t)DIM * 4096, 4 * DIM, DIM, DIM, 1);
        gemm_split<float, 0, 3, 2><<<dim3(DIM / 128, BNROWS / 128, 4), 256, 0, stream>>>(
            midb, 4 * DIM, PS_MID, wT, 4 * DIM, (size_t)DIM * 4096, part, DIM, PS_H, 1024, nullptr, nullptr, 0);
        const float* nw = (l < DEPTH - 1) ? ln1_w + (size_t)(l + 1) * DIM : lnf_w;
        const float* nb = (l < DEPTH - 1) ? ln1_b + (size_t)(l + 1) * DIM : lnf_b;
        combine_ln<4><<<BNROWS, 256, 0, stream>>>(
            part, PS_H, ff_b2 + (size_t)l * DIM, x, nw, nb, hb, PS_H);
    }

    // logits (hb already holds LNf output; 5 column chunks, hi-plane bf16)
    for (int c0 = 0; c0 < VOCAB; c0 += LOGITS_CHUNK) {
        wconv<<<dim3(16, LOGITS_CHUNK / 64), 256, 0, stream>>>(
            w_logits + c0, wT, 0, DIM, LOGITS_CHUNK, VOCAB, 0);
        gemm_split<float, 0, 1, 0><<<dim3(LOGITS_CHUNK / 128, BNROWS / 128), 256, 0, stream>>>(
            hb, DIM, PS_H, wT, DIM, 0, logits + c0, VOCAB, 0, DIM,
            b_logits + c0, nullptr, 0);
    }
}

// Round 14
// 2252.295 us; speedup vs baseline: 1.2717x; 1.0103x over previous
//
#include <hip/hip_runtime.h>
#include <hip/hip_bf16.h>
#include <math.h>

// Problem constants (from setup_inputs)
#define BB 2
#define NSEQ 1024
#define DIM 1024
#define NH 16
#define DH 64
#define DEPTH 4
#define VOCAB 32000
#define XLM 256
#define MDB 4096
#define TOPK 32
#define KNN_LAYER 2
#define BNROWS (BB * NSEQ)   // 2048
#define LOGITS_CHUNK 6400    // 32000 = 5 * 6400
#define NKEYS 1280           // XLM + NSEQ
#define KSP_PS ((size_t)BB * NKEYS * DH)   // plane stride for K/V split planes

typedef __bf16 bf16x8v __attribute__((ext_vector_type(8)));
typedef float f32x4v __attribute__((ext_vector_type(4)));
typedef unsigned short u16x8v __attribute__((ext_vector_type(8)));

__device__ __forceinline__ float bfbits2f(unsigned short u) {
    union { float f; unsigned int i; } v; v.i = ((unsigned int)u) << 16; return v.f;
}
__device__ __forceinline__ unsigned short f2bfbits(float f) {
    union { __hip_bfloat16 b; unsigned short u; } v;
    v.b = __float2bfloat16(f);
    return v.u;
}
__device__ __forceinline__ float bf2f(__hip_bfloat16 h) { return __bfloat162float(h); }
__device__ __forceinline__ __hip_bfloat16 f2bf(float f) { return __float2bfloat16(f); }

__device__ __forceinline__ void gload16(const void* gp, void* lp) {
    __builtin_amdgcn_global_load_lds(
        (const __attribute__((address_space(1))) unsigned int*)gp,
        (__attribute__((address_space(3))) unsigned int*)lp, 16, 0, 0);
}

// ---------------------------------------------------------------------------
__global__ __launch_bounds__(256) void embed_kernel(const int* __restrict__ tok,
                                                    const float* __restrict__ emb,
                                                    float* __restrict__ x) {
    int r = blockIdx.x, t = threadIdx.x;
    int id = tok[r];
    const float* er = emb + (size_t)id * DIM;
    float* xr = x + (size_t)r * DIM;
#pragma unroll
    for (int i = 0; i < 4; i++) xr[t + 256 * i] = er[t + 256 * i];
}

// ---------------------------------------------------------------------------
// Row LayerNorm over DIM=1024, fp32 in, split-bf16 (hi/lo planes) out
__global__ __launch_bounds__(256) void ln_kernel(const float* __restrict__ x,
                                                 const float* __restrict__ w,
                                                 const float* __restrict__ b,
                                                 __hip_bfloat16* __restrict__ y,
                                                 size_t ypS) {
    __shared__ float red[256];
    int r = blockIdx.x, t = threadIdx.x;
    const float* xr = x + (size_t)r * DIM;
    float v[4];
#pragma unroll
    for (int i = 0; i < 4; i++) v[i] = xr[t + 256 * i];
    float s = v[0] + v[1] + v[2] + v[3];
    red[t] = s; __syncthreads();
    for (int st = 128; st; st >>= 1) { if (t < st) red[t] += red[t + st]; __syncthreads(); }
    float mean = red[0] * (1.0f / DIM);
    __syncthreads();
    float s2 = 0.f;
#pragma unroll
    for (int i = 0; i < 4; i++) { float d = v[i] - mean; s2 += d * d; }
    red[t] = s2; __syncthreads();
    for (int st = 128; st; st >>= 1) { if (t < st) red[t] += red[t + st]; __syncthreads(); }
    float rs = rsqrtf(red[0] * (1.0f / DIM) + 1e-5f);
    __hip_bfloat16* yr = y + (size_t)r * DIM;
#pragma unroll
    for (int i = 0; i < 4; i++) {
        int c = t + 256 * i;
        float val = (v[i] - mean) * rs * w[c] + b[c];
        __hip_bfloat16 hv = f2bf(val);
        yr[c] = hv;
        yr[c + ypS] = f2bf(val - bf2f(hv));
    }
}

// ---------------------------------------------------------------------------
// Fused split-K combine + residual + LayerNorm:
// x[r,:] += sum_z part[z] + bias;  y = LN(x[r,:]) as split-bf16 planes.
template <int NP>
__global__ __launch_bounds__(256) void combine_ln(const float* __restrict__ pbuf, size_t pS,
                                                  const float* __restrict__ bias,
                                                  float* __restrict__ x,
                                                  const float* __restrict__ w,
                                                  const float* __restrict__ b,
                                                  __hip_bfloat16* __restrict__ y,
                                                  size_t ypS) {
    __shared__ float red[256];
    int r = blockIdx.x, t = threadIdx.x;
    float v[4];
#pragma unroll
    for (int i = 0; i < 4; i++) {
        int c = t + 256 * i;
        size_t idx = (size_t)r * DIM + c;
        float s = bias[c] + x[idx];
#pragma unroll
        for (int z = 0; z < NP; z++) s += pbuf[(size_t)z * pS + idx];
        v[i] = s;
        x[idx] = s;
    }
    float s = v[0] + v[1] + v[2] + v[3];
    red[t] = s; __syncthreads();
    for (int st = 128; st; st >>= 1) { if (t < st) red[t] += red[t + st]; __syncthreads(); }
    float mean = red[0] * (1.0f / DIM);
    __syncthreads();
    float s2 = 0.f;
#pragma unroll
    for (int i = 0; i < 4; i++) { float d = v[i] - mean; s2 += d * d; }
    red[t] = s2; __syncthreads();
    for (int st = 128; st; st >>= 1) { if (t < st) red[t] += red[t + st]; __syncthreads(); }
    float rs = rsqrtf(red[0] * (1.0f / DIM) + 1e-5f);
    __hip_bfloat16* yr = y + (size_t)r * DIM;
#pragma unroll
    for (int i = 0; i < 4; i++) {
        int c = t + 256 * i;
        float val = (v[i] - mean) * rs * w[c] + b[c];
        __hip_bfloat16 hv = f2bf(val);
        yr[c] = hv;
        yr[c + ypS] = f2bf(val - bf2f(hv));
    }
}

// ---------------------------------------------------------------------------
// Fused q l2norm + split-plane write: row r (64 elems at qf+r*64) is
// normalized in place and emitted as hi/lo bf16 planes (flat layout).
__global__ void l2split_q(float* __restrict__ qf, unsigned short* __restrict__ qs,
                          size_t pS) {
    int r = blockIdx.x, t = threadIdx.x; // 64 threads
    size_t idx = (size_t)r * DH + t;
    float v = qf[idx];
    float s = v * v;
#pragma unroll
    for (int off = 32; off; off >>= 1) s += __shfl_xor(s, off, 64);
    float n = fmaxf(sqrtf(s), 1e-12f);
    v /= n;
    qf[idx] = v;
    unsigned short hv = f2bfbits(v);
    qs[idx] = hv;
    qs[idx + pS] = f2bfbits(v - bfbits2f(hv));
}

__global__ void dbnorm_kernel(const float* __restrict__ db, float* __restrict__ dbkn) {
    int r = blockIdx.x, t = threadIdx.x; // 64 threads
    float v = db[((size_t)r * 2 + 0) * DH + t];
    float s = v * v;
#pragma unroll
    for (int off = 32; off; off >>= 1) s += __shfl_xor(s, off, 64);
    float n = fmaxf(sqrtf(s), 1e-12f);
    dbkn[(size_t)r * DH + t] = v / n;
}

// ---------------------------------------------------------------------------
// fp32 -> split-bf16 planes (hi at y, lo at y+pS). n4 = n/4 float4 groups.
__global__ __launch_bounds__(256) void split_conv(const float* __restrict__ x,
                                                  unsigned short* __restrict__ y,
                                                  size_t pS, size_t n4) {
    size_t idx = (size_t)blockIdx.x * 256 + threadIdx.x;
    if (idx >= n4) return;
    float4 v = *(const float4*)&x[idx * 4];
    float vv[4] = {v.x, v.y, v.z, v.w};
    ushort4 h4, l4;
    unsigned short* hp = (unsigned short*)&h4;
    unsigned short* lp = (unsigned short*)&l4;
#pragma unroll
    for (int j = 0; j < 4; j++) {
        hp[j] = f2bfbits(vv[j]);
        lp[j] = f2bfbits(vv[j] - bfbits2f(hp[j]));
    }
    *(ushort4*)&y[idx * 4] = h4;
    *(ushort4*)&y[idx * 4 + pS] = l4;
}

// ---------------------------------------------------------------------------
// Split-K partial combine: out = sum_z p[z*pS] [+bias] [+res]. n4 = M*N/4.
template <int NP>
__global__ __launch_bounds__(256) void combine_k(const float* __restrict__ pbuf, size_t pS,
                                                 float* __restrict__ out,
                                                 const float* __restrict__ bias,
                                                 const float* __restrict__ res,
                                                 int N, size_t n4) {
    size_t idx = (size_t)blockIdx.x * 256 + threadIdx.x;
    if (idx >= n4) return;
    f32x4v s = *(const f32x4v*)&pbuf[idx * 4];
#pragma unroll
    for (int z = 1; z < NP; z++) {
        f32x4v v = *(const f32x4v*)&pbuf[(size_t)z * pS + idx * 4];
        s += v;
    }
    if (bias) {
        int col = (int)((idx * 4) % (size_t)N);
        const f32x4v bv = *(const f32x4v*)&bias[col];
        s += bv;
    }
    if (res) {
        f32x4v r = *(const f32x4v*)&res[idx * 4];
        s += r;
    }
    *(f32x4v*)&out[idx * 4] = s;
}

// ---------------------------------------------------------------------------
// Split-K combine + bias + exact GELU + split-bf16 plane write (for ff1).
template <int NP>
__global__ __launch_bounds__(256) void combine_gelu_split(const float* __restrict__ pbuf, size_t pS,
                                                          const float* __restrict__ bias, int N,
                                                          unsigned short* __restrict__ y, size_t ypS,
                                                          size_t n4) {
    size_t idx = (size_t)blockIdx.x * 256 + threadIdx.x;
    if (idx >= n4) return;
    f32x4v s = *(const f32x4v*)&pbuf[idx * 4];
#pragma unroll
    for (int z = 1; z < NP; z++) {
        f32x4v v = *(const f32x4v*)&pbuf[(size_t)z * pS + idx * 4];
        s += v;
    }
    int col = (int)((idx * 4) % (size_t)N);
    const f32x4v bv = *(const f32x4v*)&bias[col];
    s += bv;
    ushort4 h4, l4;
    unsigned short* hp = (unsigned short*)&h4;
    unsigned short* lp = (unsigned short*)&l4;
#pragma unroll
    for (int j = 0; j < 4; j++) {
        float v = s[j];
        v = 0.5f * v * (1.0f + erff(v * 0.70710678118654752f));
        hp[j] = f2bfbits(v);
        lp[j] = f2bfbits(v - bfbits2f(hp[j]));
    }
    *(ushort4*)&y[idx * 4] = h4;
    *(ushort4*)&y[idx * 4 + ypS] = l4;
}

// ---------------------------------------------------------------------------
// Per-layer K/V split-bf16 prep (NORM: l2-normalize fresh keys on the fly):
// K planes [b][key][dim]; V transposed planes [b][dim][key].
template <int NORM>
__global__ void kv_prep(const float* __restrict__ kvf, const float* __restrict__ xlm,
                        unsigned short* __restrict__ ksp, unsigned short* __restrict__ vtp) {
    int key = blockIdx.x, b = blockIdx.y, d = threadIdx.x; // 64 threads
    float kvv, vvv;
    if (key < XLM) {
        kvv = xlm[(((size_t)b * XLM + key) * 2 + 0) * DH + d];
        vvv = xlm[(((size_t)b * XLM + key) * 2 + 1) * DH + d];
    } else {
        const float* r = &kvf[(size_t)(b * NSEQ + key - XLM) * 128];
        kvv = r[d]; vvv = r[64 + d];
        if (NORM) {
            float s = kvv * kvv;
#pragma unroll
            for (int off = 32; off; off >>= 1) s += __shfl_xor(s, off, 64);
            kvv /= fmaxf(sqrtf(s), 1e-12f);
        }
    }
    unsigned short kh = f2bfbits(kvv), kl = f2bfbits(kvv - bfbits2f(kh));
    unsigned short vh = f2bfbits(vvv), vl = f2bfbits(vvv - bfbits2f(vh));
    size_t ko = (size_t)b * NKEYS * DH + (size_t)key * DH + d;
    ksp[ko] = kh; ksp[ko + KSP_PS] = kl;
    size_t vo = (size_t)b * DH * NKEYS + (size_t)d * NKEYS + key;
    vtp[vo] = vh; vtp[vo + KSP_PS] = vl;
}

// ---------------------------------------------------------------------------
// Weight convert + transpose: W (K x N fp32, row stride ldw) ->
// WT (N x K split-bf16, hi plane + lo plane at +wpS). wlo=0: hi only.
__global__ __launch_bounds__(256) void wconv(const float* __restrict__ W,
                                             __hip_bfloat16* __restrict__ WT,
                                             size_t wpS, int K, int N, int ldw,
                                             int wlo) {
    __shared__ float tile[64][65];
    int k0 = blockIdx.x * 64, n0 = blockIdx.y * 64;
    int t = threadIdx.x;
    int r = t >> 4, c4 = (t & 15) * 4;
#pragma unroll
    for (int rr = 0; rr < 4; rr++) {
        int row = rr * 16 + r;
        float4 v = *(const float4*)&W[(size_t)(k0 + row) * ldw + n0 + c4];
        tile[row][c4] = v.x; tile[row][c4 + 1] = v.y; tile[row][c4 + 2] = v.z; tile[row][c4 + 3] = v.w;
    }
    __syncthreads();
#pragma unroll
    for (int rr = 0; rr < 4; rr++) {
        int nrow = rr * 16 + r;
        size_t base = (size_t)(n0 + nrow) * K + k0 + c4;
#pragma unroll
        for (int j = 0; j < 4; j++) {
            float val = tile[c4 + j][nrow];
            __hip_bfloat16 hv = f2bf(val);
            WT[base + j] = hv;
            if (wlo) WT[base + j + wpS] = f2bf(val - bf2f(hv));
        }
    }
}

// ---------------------------------------------------------------------------
// Split-bf16 MFMA GEMM: C(MxN) = A(MxK) @ BT(NxK)^T with A,B as hi/lo planes.
// TERMS: 3 = hi*hi + lo*hi + hi*lo (fp32-grade); 1 = hi*hi only (bf16-grade).
// OT: float / __hip_bfloat16 (split 2-plane) / unsigned short (single bf16).
// MODE: 0 = normal; 1 = simdb batch over bh (z dim);
//       2 = split-K (z = K-slice; K param is the slice length; partial
//           written to C + z*cpS; bias/res must be null).
template <typename OT, int ACT, int TERMS, int MODE>
__global__ __launch_bounds__(256) void gemm_split(const __hip_bfloat16* __restrict__ A, int lda, size_t apS,
                                                  const __hip_bfloat16* __restrict__ BT, int ldb, size_t bpS,
                                                  OT* __restrict__ C, int ldc, size_t cpS, int K,
                                                  const float* __restrict__ bias,
                                                  const float* __restrict__ res,
                                                  int bh0) {
    __shared__ __align__(16) __hip_bfloat16 sAh[128 * 32];
    __shared__ __align__(16) __hip_bfloat16 sBh[128 * 32];
    __shared__ __align__(16) __hip_bfloat16 sAl[TERMS >= 2 ? 128 * 32 : 1];
    __shared__ __align__(16) __hip_bfloat16 sBl[TERMS >= 3 ? 128 * 32 : 1];
    if constexpr (MODE == 1) {
        int bh = bh0 + blockIdx.z;
        A += ((size_t)(bh >> 4) * NSEQ) * lda + (bh & 15) * DH;
        BT += (size_t)(bh >> 4) * MDB * ldb;
        C += (size_t)blockIdx.z * NSEQ * ldc;
    }
    if constexpr (MODE == 2) {
        A += (size_t)blockIdx.z * K;
        BT += (size_t)blockIdx.z * K;
        C += (size_t)blockIdx.z * cpS;
    }
    int bn = blockIdx.x * 128;
    int bm = blockIdx.y * 128;
    int t = threadIdx.x;
    int lane = t & 63, wid = t >> 6;
    int wr = wid >> 1, wc = wid & 1;
    int lr = lane & 15, kc = lane >> 4;

    f32x4v acc[4][4];
#pragma unroll
    for (int m = 0; m < 4; m++)
#pragma unroll
        for (int n = 0; n < 4; n++) acc[m][n] = (f32x4v){0.f, 0.f, 0.f, 0.f};

    for (int k0 = 0; k0 < K; k0 += 32) {
        __syncthreads();
#pragma unroll
        for (int it = 0; it < 2; it++) {
            int e = wid * 128 + it * 64 + lane;
            int r = e >> 2;
            int cl = (e & 3) ^ ((r >> 1) & 3);
            size_t aoff = (size_t)(bm + r) * lda + k0 + cl * 8;
            size_t boff = (size_t)(bn + r) * ldb + k0 + cl * 8;
            int dst = (wid * 128 + it * 64) * 8;
            gload16(&A[aoff], &sAh[dst]);
            gload16(&BT[boff], &sBh[dst]);
            if constexpr (TERMS >= 2) gload16(&A[aoff + apS], &sAl[dst]);
            if constexpr (TERMS >= 3) gload16(&BT[boff + bpS], &sBl[dst]);
        }
        __syncthreads();

        bf16x8v ah[4], al[4], bh[4], bl[4];
#pragma unroll
        for (int m = 0; m < 4; m++) {
            int row = wr * 64 + m * 16 + lr;
            int off = row * 32 + ((kc ^ ((row >> 1) & 3)) << 3);
            ah[m] = *(const bf16x8v*)&sAh[off];
            if constexpr (TERMS >= 2) al[m] = *(const bf16x8v*)&sAl[off];
        }
#pragma unroll
        for (int n = 0; n < 4; n++) {
            int row = wc * 64 + n * 16 + lr;
            int off = row * 32 + ((kc ^ ((row >> 1) & 3)) << 3);
            bh[n] = *(const bf16x8v*)&sBh[off];
            if constexpr (TERMS >= 3) bl[n] = *(const bf16x8v*)&sBl[off];
        }
#pragma unroll
        for (int m = 0; m < 4; m++)
#pragma unroll
            for (int n = 0; n < 4; n++) {
                acc[m][n] = __builtin_amdgcn_mfma_f32_16x16x32_bf16(ah[m], bh[n], acc[m][n], 0, 0, 0);
                if constexpr (TERMS >= 2)
                    acc[m][n] = __builtin_amdgcn_mfma_f32_16x16x32_bf16(al[m], bh[n], acc[m][n], 0, 0, 0);
                if constexpr (TERMS >= 3)
                    acc[m][n] = __builtin_amdgcn_mfma_f32_16x16x32_bf16(ah[m], bl[n], acc[m][n], 0, 0, 0);
            }
    }

#pragma unroll
    for (int m = 0; m < 4; m++) {
#pragma unroll
        for (int n = 0; n < 4; n++) {
            int gcol = bn + wc * 64 + n * 16 + lr;
            float bv = bias ? bias[gcol] : 0.f;
#pragma unroll
            for (int j = 0; j < 4; j++) {
                int grow = bm + wr * 64 + m * 16 + kc * 4 + j;
                float v = acc[m][n][j] + bv;
                if (ACT == 1) v = 0.5f * v * (1.0f + erff(v * 0.70710678118654752f));
                if (res) v += res[(size_t)grow * ldc + gcol];
                size_t idx = (size_t)grow * ldc + gcol;
                if constexpr (__is_same(OT, float)) {
                    C[idx] = v;
                } else if constexpr (__is_same(OT, unsigned short)) {
                    C[idx] = f2bfbits(v);
                } else {
                    __hip_bfloat16 hv = f2bf(v);
                    C[idx] = hv;
                    C[idx + cpS] = f2bf(v - bf2f(hv));
                }
            }
        }
    }
}

// ---------------------------------------------------------------------------
// Split-bf16 MFMA flash attention over XL + causal local keys.
// K/V pre-split by kv_prep; staging is pure global_load_lds.
template <int KNNL>
__global__ __launch_bounds__(256) void flash_kernel(const float* __restrict__ q,
                                                    const unsigned short* __restrict__ ksp,
                                                    const unsigned short* __restrict__ vtp,
                                                    const float* __restrict__ knn_scale,
                                                    __hip_bfloat16* __restrict__ out,
                                                    size_t opS,
                                                    float* __restrict__ stats) {
    __shared__ __align__(16) unsigned short sKh[64 * 64];
    __shared__ __align__(16) unsigned short sKl[64 * 64];
    __shared__ __align__(16) unsigned short sVh[64 * 64];   // transposed [dim][key]
    __shared__ __align__(16) unsigned short sVl[64 * 64];
    __shared__ __align__(16) float sPf[4 * 16 * 64];        // per-wave P fp32

    int qt = blockIdx.x, h = blockIdx.y, b = blockIdx.z;
    int q0 = qt * 64;
    int t = threadIdx.x;
    int w = t >> 6;
    int lane = t & 63;
    int lr = lane & 15, kc = lane >> 4;
    int wbase = w * 1024;

    float scale = KNNL ? __expf(knn_scale[h]) : 0.125f;

    bf16x8v qh[2], ql[2];
    {
        const float* qbase = q + (size_t)(b * NSEQ + q0 + w * 16 + lr) * DIM + h * DH;
#pragma unroll
        for (int ks = 0; ks < 2; ks++) {
            const float* s = qbase + ks * 32 + kc * 8;
            float4 a = *(const float4*)s;
            float4 c2 = *(const float4*)(s + 4);
            float vv[8] = {a.x, a.y, a.z, a.w, c2.x, c2.y, c2.z, c2.w};
            u16x8v hi, lo;
#pragma unroll
            for (int j = 0; j < 8; j++) {
                hi[j] = f2bfbits(vv[j]);
                lo[j] = f2bfbits(vv[j] - bfbits2f(hi[j]));
            }
            qh[ks] = *(bf16x8v*)&hi;
            ql[ks] = *(bf16x8v*)&lo;
        }
    }

    float m[4], l[4];
    f32x4v o[4];
#pragma unroll
    for (int j = 0; j < 4; j++) { m[j] = -1e30f; l[j] = 0.f; }
#pragma unroll
    for (int f = 0; f < 4; f++) o[f] = (f32x4v){0.f, 0.f, 0.f, 0.f};

    int ntiles = 5 + qt;
    size_t kbase = (size_t)b * NKEYS * DH;
    size_t vbase = (size_t)b * DH * NKEYS;

    for (int T = 0; T < ntiles; T++) {
        __syncthreads();
        // ---- stage K + Vt planes via global_load_lds (512 16B-chunks each)
#pragma unroll
        for (int i2 = 0; i2 < 2; i2++) {
            int cbase = i2 * 256 + w * 64;
            int c = cbase + lane;
            int key = c >> 3, ch = (c & 7) ^ (key & 7);
            size_t ko = kbase + (size_t)(T * 64 + key) * DH + ch * 8;
            gload16(&ksp[ko], &sKh[cbase * 8]);
            gload16(&ksp[ko + KSP_PS], &sKl[cbase * 8]);
            int dim = c >> 3, k8 = (c & 7) ^ (dim & 7);
            size_t vo = vbase + (size_t)dim * NKEYS + T * 64 + k8 * 8;
            gload16(&vtp[vo], &sVh[cbase * 8]);
            gload16(&vtp[vo + KSP_PS], &sVl[cbase * 8]);
        }
        __syncthreads();

        f32x4v s4[4];
#pragma unroll
        for (int n = 0; n < 4; n++) s4[n] = (f32x4v){0.f, 0.f, 0.f, 0.f};
#pragma unroll
        for (int ks = 0; ks < 2; ks++) {
            bf16x8v qh_ = qh[ks], ql_ = ql[ks];
#pragma unroll
            for (int n = 0; n < 4; n++) {
                int row = n * 16 + lr;
                int off = row * 64 + (((ks * 4 + kc) ^ (lr & 7)) << 3);
                bf16x8v kh = *(const bf16x8v*)&sKh[off];
                bf16x8v kl = *(const bf16x8v*)&sKl[off];
                s4[n] = __builtin_amdgcn_mfma_f32_16x16x32_bf16(qh_, kh, s4[n], 0, 0, 0);
                s4[n] = __builtin_amdgcn_mfma_f32_16x16x32_bf16(ql_, kh, s4[n], 0, 0, 0);
                s4[n] = __builtin_amdgcn_mfma_f32_16x16x32_bf16(qh_, kl, s4[n], 0, 0, 0);
            }
        }

#pragma unroll
        for (int n = 0; n < 4; n++) {
            int key = T * 64 + n * 16 + lr;
#pragma unroll
            for (int j = 0; j < 4; j++) {
                int gq = q0 + w * 16 + kc * 4 + j;
                float sv = s4[n][j] * scale;
                s4[n][j] = (key <= XLM + gq) ? sv : -1e30f;
            }
        }

        float tm[4];
#pragma unroll
        for (int j = 0; j < 4; j++) {
            float v = fmaxf(fmaxf(s4[0][j], s4[1][j]), fmaxf(s4[2][j], s4[3][j]));
            v = fmaxf(v, __shfl_xor(v, 1, 64));
            v = fmaxf(v, __shfl_xor(v, 2, 64));
            v = fmaxf(v, __shfl_xor(v, 4, 64));
            v = fmaxf(v, __shfl_xor(v, 8, 64));
            tm[j] = v;
        }
        float alpha[4];
#pragma unroll
        for (int j = 0; j < 4; j++) {
            float mnew = fmaxf(m[j], tm[j]);
            alpha[j] = __expf(m[j] - mnew);
            m[j] = mnew;
        }
        float psum[4] = {0.f, 0.f, 0.f, 0.f};
#pragma unroll
        for (int n = 0; n < 4; n++)
#pragma unroll
            for (int j = 0; j < 4; j++) {
                float p = __expf(s4[n][j] - m[j]);
                s4[n][j] = p;
                psum[j] += p;
            }
#pragma unroll
        for (int j = 0; j < 4; j++) {
            float v = psum[j];
            v += __shfl_xor(v, 1, 64);
            v += __shfl_xor(v, 2, 64);
            v += __shfl_xor(v, 4, 64);
            v += __shfl_xor(v, 8, 64);
            l[j] = l[j] * alpha[j] + v;
        }
#pragma unroll
        for (int f = 0; f < 4; f++)
#pragma unroll
            for (int j = 0; j < 4; j++) o[f][j] *= alpha[j];

#pragma unroll
        for (int n = 0; n < 4; n++) {
            int chunkcol = 2 * n + (lr >> 3);
#pragma unroll
            for (int j = 0; j < 4; j++) {
                int row = kc * 4 + j;
                int off = wbase + row * 64 + (((chunkcol ^ (row & 7)) << 3) + (lr & 7));
                sPf[off] = s4[n][j];
            }
        }

#pragma unroll
        for (int ks = 0; ks < 2; ks++) {
            int poff = wbase + lr * 64 + (((ks * 4 + kc) ^ (lr & 7)) << 3);
            float4 a = *(const float4*)&sPf[poff];
            float4 c2 = *(const float4*)&sPf[poff + 4];
            float vv[8] = {a.x, a.y, a.z, a.w, c2.x, c2.y, c2.z, c2.w};
            u16x8v hib, lob;
#pragma unroll
            for (int j = 0; j < 8; j++) {
                hib[j] = f2bfbits(vv[j]);
                lob[j] = f2bfbits(vv[j] - bfbits2f(hib[j]));
            }
            bf16x8v ph = *(bf16x8v*)&hib;
            bf16x8v pl = *(bf16x8v*)&lob;
#pragma unroll
            for (int f = 0; f < 4; f++) {
                int row = f * 16 + lr;
                int off = row * 64 + (((ks * 4 + kc) ^ (lr & 7)) << 3);
                bf16x8v vh = *(const bf16x8v*)&sVh[off];
                bf16x8v vl = *(const bf16x8v*)&sVl[off];
                o[f] = __builtin_amdgcn_mfma_f32_16x16x32_bf16(ph, vh, o[f], 0, 0, 0);
                o[f] = __builtin_amdgcn_mfma_f32_16x16x32_bf16(pl, vh, o[f], 0, 0, 0);
                o[f] = __builtin_amdgcn_mfma_f32_16x16x32_bf16(ph, vl, o[f], 0, 0, 0);
            }
        }
    }

    float inv[4];
#pragma unroll
    for (int j = 0; j < 4; j++) inv[j] = 1.0f / l[j];
    unsigned short* outu = (unsigned short*)out;
#pragma unroll
    for (int f = 0; f < 4; f++)
#pragma unroll
        for (int j = 0; j < 4; j++) {
            int gq = q0 + w * 16 + kc * 4 + j;
            size_t oidx = (size_t)(b * NSEQ + gq) * DIM + h * DH + f * 16 + lr;
            float v = o[f][j] * inv[j];
            unsigned short hv = f2bfbits(v);
            outu[oidx] = hv;
            outu[oidx + opS] = f2bfbits(v - bfbits2f(hv));
        }
    if (KNNL && lr == 0) {
#pragma unroll
        for (int j = 0; j < 4; j++) {
            int gq = q0 + w * 16 + kc * 4 + j;
            size_t srow = (((size_t)b * NH + h) * NSEQ + gq) * 2;
            stats[srow] = m[j];
            stats[srow + 1] = l[j];
        }
    }
}

// ---------------------------------------------------------------------------
// Per-row top-32 over bf16 simdb + exact recompute + mem softmax + combine.
// 4 waves per block, ONE ROW PER WAVE (no idle waves, no barriers).
__global__ __launch_bounds__(256) void knn_select(const unsigned short* __restrict__ simdb,
                                                  const float* __restrict__ db,
                                                  const float* __restrict__ qf,
                                                  const float* __restrict__ dbkn,
                                                  const float* __restrict__ knn_scale,
                                                  const float* __restrict__ stats,
                                                  __hip_bfloat16* __restrict__ out,
                                                  size_t opS,
                                                  int bh0) {
    __shared__ unsigned short sv[4 * 4096];

    int bh = bh0 + blockIdx.y;
    int b = bh >> 4, h = bh & 15;
    int t = threadIdx.x;
    int w = t >> 6, lane = t & 63;
    int i = blockIdx.x * 4 + w;
    unsigned short* svw = &sv[w * 4096];

    // stage this wave's row: 512 16B-chunks / 64 lanes = 8 iters
    const unsigned short* srow = &simdb[((size_t)blockIdx.y * NSEQ + i) * MDB];
#pragma unroll
    for (int it = 0; it < 8; it++) {
        int g = it * 64 + lane;
        int c = g >> 3, sub = g & 7;
        u16x8v d = *(const u16x8v*)&srow[(size_t)g * 8];
        *(u16x8v*)&svw[c * 64 + ((sub ^ (c & 7)) << 3)] = d;
    }

    // per-column candidates: lane owns column l, scans 64 chunks
    float lmax = -1e30f; int lidx = 0;
#pragma unroll
    for (int c = 0; c < 64; c++) {
        float v = bfbits2f(svw[c * 64 + (lane ^ ((c & 7) << 3))]);
        if (v > lmax) { lmax = v; lidx = c * 64 + lane; }
    }

    // 32 selection iterations, wave-synchronous
    int tidx = 0;
    for (int it = 0; it < TOPK; it++) {
        float v = lmax; int idx = lidx;
#pragma unroll
        for (int off = 32; off; off >>= 1) {
            float v2 = __shfl_xor(v, off, 64);
            int i2 = __shfl_xor(idx, off, 64);
            if (v2 > v || (v2 == v && i2 < idx)) { v = v2; idx = i2; }
        }
        if (lane == it) tidx = idx;
        int col = idx & 63, cc = idx >> 6;
        if (lane == 0) svw[cc * 64 + (col ^ ((cc & 7) << 3))] = 0xFF80; // bf16 -inf
        // rescan column col: lane reads element (c=lane, col)
        float rv = bfbits2f(svw[lane * 64 + (col ^ ((lane & 7) << 3))]);
        int ridx = lane * 64 + col;
#pragma unroll
        for (int off = 32; off; off >>= 1) {
            float v2 = __shfl_xor(rv, off, 64);
            int i2 = __shfl_xor(ridx, off, 64);
            if (v2 > rv || (v2 == rv && i2 < ridx)) { rv = v2; ridx = i2; }
        }
        if (lane == col) { lmax = rv; lidx = ridx; }
    }

    // exact recompute of selected sims (lane j < 32 recomputes sim of its idx)
    float srec = -1e30f;
    if (lane < TOPK) {
        const float* qrow = &qf[(size_t)(b * NSEQ + i) * DIM + h * DH];
        const float* krow = &dbkn[((size_t)b * MDB + tidx) * DH];
        float s = 0.f;
#pragma unroll
        for (int d4 = 0; d4 < 16; d4++) {
            float4 a = *(const float4*)&qrow[d4 * 4];
            float4 k2 = *(const float4*)&krow[d4 * 4];
            s += a.x * k2.x + a.y * k2.y + a.z * k2.z + a.w * k2.w;
        }
        srec = s;
    }

    float scl = __expf(knn_scale[h]);
    size_t srow_idx = (((size_t)b * NH + h) * NSEQ + i) * 2;
    float m_loc = stats[srow_idx], l_loc = stats[srow_idx + 1];
    float mm = srec;
#pragma unroll
    for (int off = 32; off; off >>= 1) mm = fmaxf(mm, __shfl_xor(mm, off, 64));
    float M = fmaxf(m_loc, mm * scl);
    float co = __expf(m_loc - M);
    float e = (lane < TOPK) ? __expf(srec * scl - M) : 0.f;
    float esum = e;
#pragma unroll
    for (int off = 32; off; off >>= 1) esum += __shfl_xor(esum, off, 64);
    float denom = l_loc * co + esum;

    // gather: lane = output dim; iterate 32 selected keys via shfl broadcast
    float acc = 0.f;
#pragma unroll
    for (int j = 0; j < TOPK; j++) {
        int idxj = __shfl(tidx, j, 64);
        float ej = __shfl(e, j, 64);
        acc += ej * db[(((size_t)b * MDB + idxj) * 2 + 1) * DH + lane];
    }

    size_t op = (size_t)(b * NSEQ + i) * DIM + h * DH + lane;
    float o_loc = bf2f(out[op]) + bf2f(out[op + opS]);
    float nv = (o_loc * l_loc * co + acc) / denom;
    __hip_bfloat16 hv = f2bf(nv);
    out[op] = hv;
    out[op + opS] = f2bf(nv - bf2f(hv));
}

// ---------------------------------------------------------------------------
extern "C" void kernel_launch(void* const* d_in, const int* in_sizes, int n_in,
                              void* d_out, int out_size, void* d_ws, size_t ws_size,
                              hipStream_t stream) {
    const int* tokens = (const int*)d_in[0];
    const float* emb = (const float*)d_in[1];
    const float* ln1_w = (const float*)d_in[2];
    const float* ln1_b = (const float*)d_in[3];
    const float* wq = (const float*)d_in[4];
    const float* wkv = (const float*)d_in[5];
    const float* wo = (const float*)d_in[6];
    const float* wo_b = (const float*)d_in[7];
    const float* knn_scale = (const float*)d_in[8];
    const float* ln2_w = (const float*)d_in[9];
    const float* ln2_b = (const float*)d_in[10];
    const float* ff_w1 = (const float*)d_in[11];
    const float* ff_b1 = (const float*)d_in[12];
    const float* ff_w2 = (const float*)d_in[13];
    const float* ff_b2 = (const float*)d_in[14];
    const float* lnf_w = (const float*)d_in[15];
    const float* lnf_b = (const float*)d_in[16];
    const float* w_logits = (const float*)d_in[17];
    const float* b_logits = (const float*)d_in[18];
    const float* xl_mems = (const float*)d_in[19];
    const float* db_kv = (const float*)d_in[20];

    // ---- workspace layout ----
    const size_t PS_H = (size_t)BNROWS * DIM;        // plane stride for h / attn-out
    char* p = (char*)d_ws;
    float* x = (float*)p;                p += PS_H * 4;                        // 8 MB
    __hip_bfloat16* hb = (__hip_bfloat16*)p;  p += PS_H * 2 * 2;               // 8 MB (2 planes)
    float* qf = (float*)p;               p += PS_H * 4;                        // 8 MB
    float* kvf = (float*)p;              p += (size_t)BNROWS * 128 * 4;        // 1 MB
    float* dbkn = (float*)p;             p += (size_t)BB * MDB * DH * 4;       // 2 MB
    float* stats = (float*)p;            p += (size_t)BB * NH * NSEQ * 2 * 4;  // 0.25 MB
    unsigned short* ksp = (unsigned short*)p; p += KSP_PS * 2 * 2;             // 0.66 MB
    unsigned short* vtp = (unsigned short*)p; p += KSP_PS * 2 * 2;             // 0.66 MB
    __hip_bfloat16* wT = (__hip_bfloat16*)p; p += (size_t)4096 * DIM * 2 * 2;  // 16 MB (2 planes)

    // qsplit/dbkn-split live in the wT region during the KNN phase (wT idle)
    unsigned short* qsplit = (unsigned short*)wT;                  // 2 planes x PS_H
    unsigned short* dbks = (unsigned short*)wT + 2 * PS_H;         // 2 planes x BB*MDB*DH
    const size_t PS_DB = (size_t)BB * MDB * DH;

    const size_t PS_MID = (size_t)BNROWS * 4 * DIM;  // 8M elems per plane
    __hip_bfloat16* midb = (__hip_bfloat16*)d_out;   // 32 MB of the 262 MB out buf
    float* logits = (float*)d_out;
    // split-K partial buffers: d_out + 96 MB (clear of simdb 0..67MB and midb)
    float* part = (float*)((char*)d_out + ((size_t)96 << 20));

    embed_kernel<<<BNROWS, 256, 0, stream>>>(tokens, emb, x);
    dbnorm_kernel<<<BB * MDB, 64, 0, stream>>>(db_kv, dbkn);
    // first LN (later LNs are fused into combine_ln)
    ln_kernel<<<BNROWS, 256, 0, stream>>>(x, ln1_w, ln1_b, hb, PS_H);

    for (int l = 0; l < DEPTH; l++) {
        const float* wq_l = wq + (size_t)l * DIM * DIM;
        const float* wkv_l = wkv + (size_t)l * DIM * 128;
        const float* wo_l = wo + (size_t)l * DIM * DIM;
        const float* xlm_l = xl_mems + (size_t)l * BB * XLM * 2 * DH;

        // q = h @ wq  (split-K=4 -> combine)
        wconv<<<dim3(16, 16), 256, 0, stream>>>(wq_l, wT, (size_t)DIM * DIM, DIM, DIM, DIM, 1);
        gemm_split<float, 0, 3, 2><<<dim3(DIM / 128, BNROWS / 128, 4), 256, 0, stream>>>(
            hb, DIM, PS_H, wT, DIM, (size_t)DIM * DIM, part, DIM, PS_H, 256, nullptr, nullptr, 0);
        combine_k<4><<<(PS_H / 4 + 255) / 256, 256, 0, stream>>>(
            part, PS_H, qf, nullptr, nullptr, DIM, PS_H / 4);
        // kv = h @ wkv (split-K=16)
        wconv<<<dim3(16, 2), 256, 0, stream>>>(wkv_l, wT, (size_t)128 * DIM, DIM, 128, 128, 1);
        gemm_split<float, 0, 3, 2><<<dim3(1, BNROWS / 128, 16), 256, 0, stream>>>(
            hb, DIM, PS_H, wT, DIM, (size_t)128 * DIM, part, 128, (size_t)BNROWS * 128, 64, nullptr, nullptr, 0);
        combine_k<16><<<((size_t)BNROWS * 128 / 4 + 255) / 256, 256, 0, stream>>>(
            part, (size_t)BNROWS * 128, kvf, nullptr, nullptr, 128, (size_t)BNROWS * 128 / 4);

        if (l == KNN_LAYER) {
            // fused q l2norm + split planes; fresh-k normalized inside kv_prep
            l2split_q<<<BNROWS * NH, 64, 0, stream>>>(qf, qsplit, PS_H);
            kv_prep<1><<<dim3(NKEYS, BB), 64, 0, stream>>>(kvf, xlm_l, ksp, vtp);
            split_conv<<<(PS_DB / 4 + 255) / 256, 256, 0, stream>>>(dbkn, dbks, PS_DB, PS_DB / 4);
            flash_kernel<1><<<dim3(NSEQ / 64, NH, BB), 256, 0, stream>>>(
                qf, ksp, vtp, knn_scale, hb, PS_H, stats);
            const int CHUNK = 8;  // 8 x 8 MB bf16 = 67 MB per gemm->select pair
            for (int bh0 = 0; bh0 < BB * NH; bh0 += CHUNK) {
                // TERMS=1: selection-grade sims (exact recompute in knn_select)
                gemm_split<unsigned short, 0, 1, 1><<<dim3(MDB / 128, NSEQ / 128, CHUNK), 256, 0, stream>>>(
                    (const __hip_bfloat16*)qsplit, DIM, PS_H,
                    (const __hip_bfloat16*)dbks, DH, PS_DB,
                    (unsigned short*)d_out, MDB, 0, DH, nullptr, nullptr, bh0);
                knn_select<<<dim3(NSEQ / 4, CHUNK), 256, 0, stream>>>(
                    (const unsigned short*)d_out, db_kv, qf, dbkn, knn_scale, stats, hb, PS_H, bh0);
            }
        } else {
            kv_prep<0><<<dim3(NKEYS, BB), 64, 0, stream>>>(kvf, xlm_l, ksp, vtp);
            flash_kernel<0><<<dim3(NSEQ / 64, NH, BB), 256, 0, stream>>>(
                qf, ksp, vtp, knn_scale, hb, PS_H, stats);
        }

        // x = attn @ wo + wo_b + x; h = LN2(x)   (split-K=4 + fused combine+LN)
        wconv<<<dim3(16, 16), 256, 0, stream>>>(wo_l, wT, (size_t)DIM * DIM, DIM, DIM, DIM, 1);
        gemm_split<float, 0, 3, 2><<<dim3(DIM / 128, BNROWS / 128, 4), 256, 0, stream>>>(
            hb, DIM, PS_H, wT, DIM, (size_t)DIM * DIM, part, DIM, PS_H, 256, nullptr, nullptr, 0);
        combine_ln<4><<<BNROWS, 256, 0, stream>>>(
            part, PS_H, wo_b + (size_t)l * DIM, x,
            ln2_w + (size_t)l * DIM, ln2_b + (size_t)l * DIM, hb, PS_H);

        // mid = gelu(h @ ff_w1 + b1)  (split-K=2 + fused combine+gelu+split)
        wconv<<<dim3(16, 64), 256, 0, stream>>>(ff_w1 + (size_t)l * DIM * 4 * DIM, wT, (size_t)4096 * DIM, DIM, 4 * DIM, 4 * DIM, 1);
        gemm_split<float, 0, 3, 2><<<dim3(4 * DIM / 128, BNROWS / 128, 2), 256, 0, stream>>>(
            hb, DIM, PS_H, wT, DIM, (size_t)4096 * DIM, part, 4 * DIM, PS_MID, 512, nullptr, nullptr, 0);
        combine_gelu_split<2><<<(PS_MID / 4 + 255) / 256, 256, 0, stream>>>(
            part, PS_MID, ff_b1 + (size_t)l * 4 * DIM, 4 * DIM,
            (unsigned short*)midb, PS_MID, PS_MID / 4);

        // x = mid @ ff_w2 + b2 + x; h = LN_next(x)  (split-K=4 + fused)
        wconv<<<dim3(64, 16), 256, 0, stream>>>(ff_w2 + (size_t)l * 4 * DIM * DIM, wT, (size_t)DIM * 4096, 4 * DIM, DIM, DIM, 1);
        gemm_split<float, 0, 3, 2><<<dim3(DIM / 128, BNROWS / 128, 4), 256, 0, stream>>>(
            midb, 4 * DIM, PS_MID, wT, 4 * DIM, (size_t)DIM * 4096, part, DIM, PS_H, 1024, nullptr, nullptr, 0);
        const float* nw = (l < DEPTH - 1) ? ln1_w + (size_t)(l + 1) * DIM : lnf_w;
        const float* nb = (l < DEPTH - 1) ? ln1_b + (size_t)(l + 1) * DIM : lnf_b;
        combine_ln<4><<<BNROWS, 256, 0, stream>>>(
            part, PS_H, ff_b2 + (size_t)l * DIM, x, nw, nb, hb, PS_H);
    }

    // logits (hb already holds LNf output; 5 column chunks, hi-plane bf16)
    for (int c0 = 0; c0 < VOCAB; c0 += LOGITS_CHUNK) {
        wconv<<<dim3(16, LOGITS_CHUNK / 64), 256, 0, stream>>>(
            w_logits + c0, wT, 0, DIM, LOGITS_CHUNK, VOCAB, 0);
        gemm_split<float, 0, 1, 0><<<dim3(LOGITS_CHUNK / 128, BNROWS / 128), 256, 0, stream>>>(
            hb, DIM, PS_H, wT, DIM, 0, logits + c0, VOCAB, 0, DIM,
            b_logits + c0, nullptr, 0);
    }
}

// Round 15
// 2228.738 us; speedup vs baseline: 1.2852x; 1.0106x over previous
//
#include <hip/hip_runtime.h>
#include <hip/hip_bf16.h>
#include <math.h>

// Problem constants (from setup_inputs)
#define BB 2
#define NSEQ 1024
#define DIM 1024
#define NH 16
#define DH 64
#define DEPTH 4
#define VOCAB 32000
#define XLM 256
#define MDB 4096
#define TOPK 32
#define KNN_LAYER 2
#define BNROWS (BB * NSEQ)   // 2048
#define LOGITS_CHUNK 6400    // 32000 = 5 * 6400
#define NKEYS 1280           // XLM + NSEQ
#define NQKV 1152            // 1024 (q) + 128 (kv) merged projection width
#define KSP_PS ((size_t)BB * NKEYS * DH)   // plane stride for K/V split planes

typedef __bf16 bf16x8v __attribute__((ext_vector_type(8)));
typedef float f32x4v __attribute__((ext_vector_type(4)));
typedef unsigned short u16x8v __attribute__((ext_vector_type(8)));

__device__ __forceinline__ float bfbits2f(unsigned short u) {
    union { float f; unsigned int i; } v; v.i = ((unsigned int)u) << 16; return v.f;
}
__device__ __forceinline__ unsigned short f2bfbits(float f) {
    union { __hip_bfloat16 b; unsigned short u; } v;
    v.b = __float2bfloat16(f);
    return v.u;
}
__device__ __forceinline__ float bf2f(__hip_bfloat16 h) { return __bfloat162float(h); }
__device__ __forceinline__ __hip_bfloat16 f2bf(float f) { return __float2bfloat16(f); }

__device__ __forceinline__ void gload16(const void* gp, void* lp) {
    __builtin_amdgcn_global_load_lds(
        (const __attribute__((address_space(1))) unsigned int*)gp,
        (__attribute__((address_space(3))) unsigned int*)lp, 16, 0, 0);
}

// ---------------------------------------------------------------------------
__global__ __launch_bounds__(256) void embed_kernel(const int* __restrict__ tok,
                                                    const float* __restrict__ emb,
                                                    float* __restrict__ x) {
    int r = blockIdx.x, t = threadIdx.x;
    int id = tok[r];
    const float* er = emb + (size_t)id * DIM;
    float* xr = x + (size_t)r * DIM;
#pragma unroll
    for (int i = 0; i < 4; i++) xr[t + 256 * i] = er[t + 256 * i];
}

// ---------------------------------------------------------------------------
// Row LayerNorm over DIM=1024, fp32 in, split-bf16 (hi/lo planes) out
__global__ __launch_bounds__(256) void ln_kernel(const float* __restrict__ x,
                                                 const float* __restrict__ w,
                                                 const float* __restrict__ b,
                                                 __hip_bfloat16* __restrict__ y,
                                                 size_t ypS) {
    __shared__ float red[256];
    int r = blockIdx.x, t = threadIdx.x;
    const float* xr = x + (size_t)r * DIM;
    float v[4];
#pragma unroll
    for (int i = 0; i < 4; i++) v[i] = xr[t + 256 * i];
    float s = v[0] + v[1] + v[2] + v[3];
    red[t] = s; __syncthreads();
    for (int st = 128; st; st >>= 1) { if (t < st) red[t] += red[t + st]; __syncthreads(); }
    float mean = red[0] * (1.0f / DIM);
    __syncthreads();
    float s2 = 0.f;
#pragma unroll
    for (int i = 0; i < 4; i++) { float d = v[i] - mean; s2 += d * d; }
    red[t] = s2; __syncthreads();
    for (int st = 128; st; st >>= 1) { if (t < st) red[t] += red[t + st]; __syncthreads(); }
    float rs = rsqrtf(red[0] * (1.0f / DIM) + 1e-5f);
    __hip_bfloat16* yr = y + (size_t)r * DIM;
#pragma unroll
    for (int i = 0; i < 4; i++) {
        int c = t + 256 * i;
        float val = (v[i] - mean) * rs * w[c] + b[c];
        __hip_bfloat16 hv = f2bf(val);
        yr[c] = hv;
        yr[c + ypS] = f2bf(val - bf2f(hv));
    }
}

// ---------------------------------------------------------------------------
// Fused split-K combine + residual + LayerNorm:
// x[r,:] += sum_z part[z] + bias;  y = LN(x[r,:]) as split-bf16 planes.
template <int NP>
__global__ __launch_bounds__(256) void combine_ln(const float* __restrict__ pbuf, size_t pS,
                                                  const float* __restrict__ bias,
                                                  float* __restrict__ x,
                                                  const float* __restrict__ w,
                                                  const float* __restrict__ b,
                                                  __hip_bfloat16* __restrict__ y,
                                                  size_t ypS) {
    __shared__ float red[256];
    int r = blockIdx.x, t = threadIdx.x;
    float v[4];
#pragma unroll
    for (int i = 0; i < 4; i++) {
        int c = t + 256 * i;
        size_t idx = (size_t)r * DIM + c;
        float s = bias[c] + x[idx];
#pragma unroll
        for (int z = 0; z < NP; z++) s += pbuf[(size_t)z * pS + idx];
        v[i] = s;
        x[idx] = s;
    }
    float s = v[0] + v[1] + v[2] + v[3];
    red[t] = s; __syncthreads();
    for (int st = 128; st; st >>= 1) { if (t < st) red[t] += red[t + st]; __syncthreads(); }
    float mean = red[0] * (1.0f / DIM);
    __syncthreads();
    float s2 = 0.f;
#pragma unroll
    for (int i = 0; i < 4; i++) { float d = v[i] - mean; s2 += d * d; }
    red[t] = s2; __syncthreads();
    for (int st = 128; st; st >>= 1) { if (t < st) red[t] += red[t + st]; __syncthreads(); }
    float rs = rsqrtf(red[0] * (1.0f / DIM) + 1e-5f);
    __hip_bfloat16* yr = y + (size_t)r * DIM;
#pragma unroll
    for (int i = 0; i < 4; i++) {
        int c = t + 256 * i;
        float val = (v[i] - mean) * rs * w[c] + b[c];
        __hip_bfloat16 hv = f2bf(val);
        yr[c] = hv;
        yr[c + ypS] = f2bf(val - bf2f(hv));
    }
}

// ---------------------------------------------------------------------------
// Fused q l2norm + split-plane write: row r (64 elems at qf+r*64) is
// normalized in place and emitted as hi/lo bf16 planes (flat layout).
__global__ void l2split_q(float* __restrict__ qf, unsigned short* __restrict__ qs,
                          size_t pS) {
    int r = blockIdx.x, t = threadIdx.x; // 64 threads
    size_t idx = (size_t)r * DH + t;
    float v = qf[idx];
    float s = v * v;
#pragma unroll
    for (int off = 32; off; off >>= 1) s += __shfl_xor(s, off, 64);
    float n = fmaxf(sqrtf(s), 1e-12f);
    v /= n;
    qf[idx] = v;
    unsigned short hv = f2bfbits(v);
    qs[idx] = hv;
    qs[idx + pS] = f2bfbits(v - bfbits2f(hv));
}

__global__ void dbnorm_kernel(const float* __restrict__ db, float* __restrict__ dbkn) {
    int r = blockIdx.x, t = threadIdx.x; // 64 threads
    float v = db[((size_t)r * 2 + 0) * DH + t];
    float s = v * v;
#pragma unroll
    for (int off = 32; off; off >>= 1) s += __shfl_xor(s, off, 64);
    float n = fmaxf(sqrtf(s), 1e-12f);
    dbkn[(size_t)r * DH + t] = v / n;
}

// ---------------------------------------------------------------------------
// fp32 -> split-bf16 planes (hi at y, lo at y+pS). n4 = n/4 float4 groups.
__global__ __launch_bounds__(256) void split_conv(const float* __restrict__ x,
                                                  unsigned short* __restrict__ y,
                                                  size_t pS, size_t n4) {
    size_t idx = (size_t)blockIdx.x * 256 + threadIdx.x;
    if (idx >= n4) return;
    float4 v = *(const float4*)&x[idx * 4];
    float vv[4] = {v.x, v.y, v.z, v.w};
    ushort4 h4, l4;
    unsigned short* hp = (unsigned short*)&h4;
    unsigned short* lp = (unsigned short*)&l4;
#pragma unroll
    for (int j = 0; j < 4; j++) {
        hp[j] = f2bfbits(vv[j]);
        lp[j] = f2bfbits(vv[j] - bfbits2f(hp[j]));
    }
    *(ushort4*)&y[idx * 4] = h4;
    *(ushort4*)&y[idx * 4 + pS] = l4;
}

// ---------------------------------------------------------------------------
// Split-K partial combine: out = sum_z p[z*pS] [+bias] [+res]. n4 = M*N/4.
template <int NP>
__global__ __launch_bounds__(256) void combine_k(const float* __restrict__ pbuf, size_t pS,
                                                 float* __restrict__ out,
                                                 const float* __restrict__ bias,
                                                 const float* __restrict__ res,
                                                 int N, size_t n4) {
    size_t idx = (size_t)blockIdx.x * 256 + threadIdx.x;
    if (idx >= n4) return;
    f32x4v s = *(const f32x4v*)&pbuf[idx * 4];
#pragma unroll
    for (int z = 1; z < NP; z++) {
        f32x4v v = *(const f32x4v*)&pbuf[(size_t)z * pS + idx * 4];
        s += v;
    }
    if (bias) {
        int col = (int)((idx * 4) % (size_t)N);
        const f32x4v bv = *(const f32x4v*)&bias[col];
        s += bv;
    }
    if (res) {
        f32x4v r = *(const f32x4v*)&res[idx * 4];
        s += r;
    }
    *(f32x4v*)&out[idx * 4] = s;
}

// ---------------------------------------------------------------------------
// Split-K combine for the merged q|kv projection: part rows are 1152 wide
// (cols 0..1023 -> qf, 1024..1151 -> kvf).
template <int NP>
__global__ __launch_bounds__(256) void combine_qkv(const float* __restrict__ pbuf, size_t pS,
                                                   float* __restrict__ qf,
                                                   float* __restrict__ kvf,
                                                   size_t n4) {
    size_t idx = (size_t)blockIdx.x * 256 + threadIdx.x;
    if (idx >= n4) return;
    f32x4v s = *(const f32x4v*)&pbuf[idx * 4];
#pragma unroll
    for (int z = 1; z < NP; z++) {
        f32x4v v = *(const f32x4v*)&pbuf[(size_t)z * pS + idx * 4];
        s += v;
    }
    size_t e = idx * 4;
    size_t row = e / NQKV;
    int col = (int)(e - row * NQKV);
    if (col < DIM) *(f32x4v*)&qf[row * DIM + col] = s;
    else *(f32x4v*)&kvf[row * 128 + (col - DIM)] = s;
}

// ---------------------------------------------------------------------------
// Split-K combine + bias + exact GELU + split-bf16 plane write (for ff1).
template <int NP>
__global__ __launch_bounds__(256) void combine_gelu_split(const float* __restrict__ pbuf, size_t pS,
                                                          const float* __restrict__ bias, int N,
                                                          unsigned short* __restrict__ y, size_t ypS,
                                                          size_t n4) {
    size_t idx = (size_t)blockIdx.x * 256 + threadIdx.x;
    if (idx >= n4) return;
    f32x4v s = *(const f32x4v*)&pbuf[idx * 4];
#pragma unroll
    for (int z = 1; z < NP; z++) {
        f32x4v v = *(const f32x4v*)&pbuf[(size_t)z * pS + idx * 4];
        s += v;
    }
    int col = (int)((idx * 4) % (size_t)N);
    const f32x4v bv = *(const f32x4v*)&bias[col];
    s += bv;
    ushort4 h4, l4;
    unsigned short* hp = (unsigned short*)&h4;
    unsigned short* lp = (unsigned short*)&l4;
#pragma unroll
    for (int j = 0; j < 4; j++) {
        float v = s[j];
        v = 0.5f * v * (1.0f + erff(v * 0.70710678118654752f));
        hp[j] = f2bfbits(v);
        lp[j] = f2bfbits(v - bfbits2f(hp[j]));
    }
    *(ushort4*)&y[idx * 4] = h4;
    *(ushort4*)&y[idx * 4 + ypS] = l4;
}

// ---------------------------------------------------------------------------
// Per-layer K/V split-bf16 prep (NORM: l2-normalize fresh keys on the fly):
// K planes [b][key][dim]; V transposed planes [b][dim][key].
template <int NORM>
__global__ void kv_prep(const float* __restrict__ kvf, const float* __restrict__ xlm,
                        unsigned short* __restrict__ ksp, unsigned short* __restrict__ vtp) {
    int key = blockIdx.x, b = blockIdx.y, d = threadIdx.x; // 64 threads
    float kvv, vvv;
    if (key < XLM) {
        kvv = xlm[(((size_t)b * XLM + key) * 2 + 0) * DH + d];
        vvv = xlm[(((size_t)b * XLM + key) * 2 + 1) * DH + d];
    } else {
        const float* r = &kvf[(size_t)(b * NSEQ + key - XLM) * 128];
        kvv = r[d]; vvv = r[64 + d];
        if (NORM) {
            float s = kvv * kvv;
#pragma unroll
            for (int off = 32; off; off >>= 1) s += __shfl_xor(s, off, 64);
            kvv /= fmaxf(sqrtf(s), 1e-12f);
        }
    }
    unsigned short kh = f2bfbits(kvv), kl = f2bfbits(kvv - bfbits2f(kh));
    unsigned short vh = f2bfbits(vvv), vl = f2bfbits(vvv - bfbits2f(vh));
    size_t ko = (size_t)b * NKEYS * DH + (size_t)key * DH + d;
    ksp[ko] = kh; ksp[ko + KSP_PS] = kl;
    size_t vo = (size_t)b * DH * NKEYS + (size_t)d * NKEYS + key;
    vtp[vo] = vh; vtp[vo + KSP_PS] = vl;
}

// ---------------------------------------------------------------------------
// Weight convert + transpose: W (K x N fp32, row stride ldw) ->
// WT (N x K split-bf16, hi plane + lo plane at +wpS). wlo=0: hi only.
__global__ __launch_bounds__(256) void wconv(const float* __restrict__ W,
                                             __hip_bfloat16* __restrict__ WT,
                                             size_t wpS, int K, int N, int ldw,
                                             int wlo) {
    __shared__ float tile[64][65];
    int k0 = blockIdx.x * 64, n0 = blockIdx.y * 64;
    int t = threadIdx.x;
    int r = t >> 4, c4 = (t & 15) * 4;
#pragma unroll
    for (int rr = 0; rr < 4; rr++) {
        int row = rr * 16 + r;
        float4 v = *(const float4*)&W[(size_t)(k0 + row) * ldw + n0 + c4];
        tile[row][c4] = v.x; tile[row][c4 + 1] = v.y; tile[row][c4 + 2] = v.z; tile[row][c4 + 3] = v.w;
    }
    __syncthreads();
#pragma unroll
    for (int rr = 0; rr < 4; rr++) {
        int nrow = rr * 16 + r;
        size_t base = (size_t)(n0 + nrow) * K + k0 + c4;
#pragma unroll
        for (int j = 0; j < 4; j++) {
            float val = tile[c4 + j][nrow];
            __hip_bfloat16 hv = f2bf(val);
            WT[base + j] = hv;
            if (wlo) WT[base + j + wpS] = f2bf(val - bf2f(hv));
        }
    }
}

// ---------------------------------------------------------------------------
// Split-bf16 MFMA GEMM: C(MxN) = A(MxK) @ BT(NxK)^T with A,B as hi/lo planes.
// TERMS: 3 = hi*hi + lo*hi + hi*lo (fp32-grade); 1 = hi*hi only (bf16-grade).
// OT: float / __hip_bfloat16 (split 2-plane) / unsigned short (single bf16).
// MODE: 0 = normal; 1 = simdb batch over bh (z dim);
//       2 = split-K (z = K-slice; K param is the slice length; partial
//           written to C + z*cpS; bias/res must be null).
template <typename OT, int ACT, int TERMS, int MODE>
__global__ __launch_bounds__(256) void gemm_split(const __hip_bfloat16* __restrict__ A, int lda, size_t apS,
                                                  const __hip_bfloat16* __restrict__ BT, int ldb, size_t bpS,
                                                  OT* __restrict__ C, int ldc, size_t cpS, int K,
                                                  const float* __restrict__ bias,
                                                  const float* __restrict__ res,
                                                  int bh0) {
    __shared__ __align__(16) __hip_bfloat16 sAh[128 * 32];
    __shared__ __align__(16) __hip_bfloat16 sBh[128 * 32];
    __shared__ __align__(16) __hip_bfloat16 sAl[TERMS >= 2 ? 128 * 32 : 1];
    __shared__ __align__(16) __hip_bfloat16 sBl[TERMS >= 3 ? 128 * 32 : 1];
    if constexpr (MODE == 1) {
        int bh = bh0 + blockIdx.z;
        A += ((size_t)(bh >> 4) * NSEQ) * lda + (bh & 15) * DH;
        BT += (size_t)(bh >> 4) * MDB * ldb;
        C += (size_t)blockIdx.z * NSEQ * ldc;
    }
    if constexpr (MODE == 2) {
        A += (size_t)blockIdx.z * K;
        BT += (size_t)blockIdx.z * K;
        C += (size_t)blockIdx.z * cpS;
    }
    int bn = blockIdx.x * 128;
    int bm = blockIdx.y * 128;
    int t = threadIdx.x;
    int lane = t & 63, wid = t >> 6;
    int wr = wid >> 1, wc = wid & 1;
    int lr = lane & 15, kc = lane >> 4;

    f32x4v acc[4][4];
#pragma unroll
    for (int m = 0; m < 4; m++)
#pragma unroll
        for (int n = 0; n < 4; n++) acc[m][n] = (f32x4v){0.f, 0.f, 0.f, 0.f};

    for (int k0 = 0; k0 < K; k0 += 32) {
        __syncthreads();
#pragma unroll
        for (int it = 0; it < 2; it++) {
            int e = wid * 128 + it * 64 + lane;
            int r = e >> 2;
            int cl = (e & 3) ^ ((r >> 1) & 3);
            size_t aoff = (size_t)(bm + r) * lda + k0 + cl * 8;
            size_t boff = (size_t)(bn + r) * ldb + k0 + cl * 8;
            int dst = (wid * 128 + it * 64) * 8;
            gload16(&A[aoff], &sAh[dst]);
            gload16(&BT[boff], &sBh[dst]);
            if constexpr (TERMS >= 2) gload16(&A[aoff + apS], &sAl[dst]);
            if constexpr (TERMS >= 3) gload16(&BT[boff + bpS], &sBl[dst]);
        }
        __syncthreads();

        bf16x8v ah[4], al[4], bh[4], bl[4];
#pragma unroll
        for (int m = 0; m < 4; m++) {
            int row = wr * 64 + m * 16 + lr;
            int off = row * 32 + ((kc ^ ((row >> 1) & 3)) << 3);
            ah[m] = *(const bf16x8v*)&sAh[off];
            if constexpr (TERMS >= 2) al[m] = *(const bf16x8v*)&sAl[off];
        }
#pragma unroll
        for (int n = 0; n < 4; n++) {
            int row = wc * 64 + n * 16 + lr;
            int off = row * 32 + ((kc ^ ((row >> 1) & 3)) << 3);
            bh[n] = *(const bf16x8v*)&sBh[off];
            if constexpr (TERMS >= 3) bl[n] = *(const bf16x8v*)&sBl[off];
        }
#pragma unroll
        for (int m = 0; m < 4; m++)
#pragma unroll
            for (int n = 0; n < 4; n++) {
                acc[m][n] = __builtin_amdgcn_mfma_f32_16x16x32_bf16(ah[m], bh[n], acc[m][n], 0, 0, 0);
                if constexpr (TERMS >= 2)
                    acc[m][n] = __builtin_amdgcn_mfma_f32_16x16x32_bf16(al[m], bh[n], acc[m][n], 0, 0, 0);
                if constexpr (TERMS >= 3)
                    acc[m][n] = __builtin_amdgcn_mfma_f32_16x16x32_bf16(ah[m], bl[n], acc[m][n], 0, 0, 0);
            }
    }

#pragma unroll
    for (int m = 0; m < 4; m++) {
#pragma unroll
        for (int n = 0; n < 4; n++) {
            int gcol = bn + wc * 64 + n * 16 + lr;
            float bv = bias ? bias[gcol] : 0.f;
#pragma unroll
            for (int j = 0; j < 4; j++) {
                int grow = bm + wr * 64 + m * 16 + kc * 4 + j;
                float v = acc[m][n][j] + bv;
                if (ACT == 1) v = 0.5f * v * (1.0f + erff(v * 0.70710678118654752f));
                if (res) v += res[(size_t)grow * ldc + gcol];
                size_t idx = (size_t)grow * ldc + gcol;
                if constexpr (__is_same(OT, float)) {
                    C[idx] = v;
                } else if constexpr (__is_same(OT, unsigned short)) {
                    C[idx] = f2bfbits(v);
                } else {
                    __hip_bfloat16 hv = f2bf(v);
                    C[idx] = hv;
                    C[idx + cpS] = f2bf(v - bf2f(hv));
                }
            }
        }
    }
}

// ---------------------------------------------------------------------------
// Split-bf16 MFMA flash attention over XL + causal local keys.
// K/V pre-split by kv_prep; staging is pure global_load_lds, DOUBLE-BUFFERED:
// tile T+1's loads are issued before tile T's compute; ONE barrier per tile
// (grid is 2 blocks/CU so the extra LDS is free).
template <int KNNL>
__global__ __launch_bounds__(256) void flash_kernel(const float* __restrict__ q,
                                                    const unsigned short* __restrict__ ksp,
                                                    const unsigned short* __restrict__ vtp,
                                                    const float* __restrict__ knn_scale,
                                                    __hip_bfloat16* __restrict__ out,
                                                    size_t opS,
                                                    float* __restrict__ stats) {
    __shared__ __align__(16) unsigned short sKh[2][4096];
    __shared__ __align__(16) unsigned short sKl[2][4096];
    __shared__ __align__(16) unsigned short sVh[2][4096];   // transposed [dim][key]
    __shared__ __align__(16) unsigned short sVl[2][4096];
    __shared__ __align__(16) float sPf[4 * 16 * 64];        // per-wave P fp32

    int qt = blockIdx.x, h = blockIdx.y, b = blockIdx.z;
    int q0 = qt * 64;
    int t = threadIdx.x;
    int w = t >> 6;
    int lane = t & 63;
    int lr = lane & 15, kc = lane >> 4;
    int wbase = w * 1024;

    float scale = KNNL ? __expf(knn_scale[h]) : 0.125f;

    bf16x8v qh[2], ql[2];
    {
        const float* qbase = q + (size_t)(b * NSEQ + q0 + w * 16 + lr) * DIM + h * DH;
#pragma unroll
        for (int ks = 0; ks < 2; ks++) {
            const float* s = qbase + ks * 32 + kc * 8;
            float4 a = *(const float4*)s;
            float4 c2 = *(const float4*)(s + 4);
            float vv[8] = {a.x, a.y, a.z, a.w, c2.x, c2.y, c2.z, c2.w};
            u16x8v hi, lo;
#pragma unroll
            for (int j = 0; j < 8; j++) {
                hi[j] = f2bfbits(vv[j]);
                lo[j] = f2bfbits(vv[j] - bfbits2f(hi[j]));
            }
            qh[ks] = *(bf16x8v*)&hi;
            ql[ks] = *(bf16x8v*)&lo;
        }
    }

    float m[4], l[4];
    f32x4v o[4];
#pragma unroll
    for (int j = 0; j < 4; j++) { m[j] = -1e30f; l[j] = 0.f; }
#pragma unroll
    for (int f = 0; f < 4; f++) o[f] = (f32x4v){0.f, 0.f, 0.f, 0.f};

    int ntiles = 5 + qt;
    size_t kbase = (size_t)b * NKEYS * DH;
    size_t vbase = (size_t)b * DH * NKEYS;

    auto stage = [&](int buf, int T) {
#pragma unroll
        for (int i2 = 0; i2 < 2; i2++) {
            int cbase = i2 * 256 + w * 64;
            int c = cbase + lane;
            int key = c >> 3, ch = (c & 7) ^ (key & 7);
            size_t ko = kbase + (size_t)(T * 64 + key) * DH + ch * 8;
            gload16(&ksp[ko], &sKh[buf][cbase * 8]);
            gload16(&ksp[ko + KSP_PS], &sKl[buf][cbase * 8]);
            int dim = c >> 3, k8 = (c & 7) ^ (dim & 7);
            size_t vo = vbase + (size_t)dim * NKEYS + T * 64 + k8 * 8;
            gload16(&vtp[vo], &sVh[buf][cbase * 8]);
            gload16(&vtp[vo + KSP_PS], &sVl[buf][cbase * 8]);
        }
    };

    stage(0, 0);
    __syncthreads();
    int cur = 0;

    for (int T = 0; T < ntiles; T++) {
        // prefetch next tile into the alternate buffer (overlaps compute)
        if (T + 1 < ntiles) stage(cur ^ 1, T + 1);

        f32x4v s4[4];
#pragma unroll
        for (int n = 0; n < 4; n++) s4[n] = (f32x4v){0.f, 0.f, 0.f, 0.f};
#pragma unroll
        for (int ks = 0; ks < 2; ks++) {
            bf16x8v qh_ = qh[ks], ql_ = ql[ks];
#pragma unroll
            for (int n = 0; n < 4; n++) {
                int row = n * 16 + lr;
                int off = row * 64 + (((ks * 4 + kc) ^ (lr & 7)) << 3);
                bf16x8v kh = *(const bf16x8v*)&sKh[cur][off];
                bf16x8v kl = *(const bf16x8v*)&sKl[cur][off];
                s4[n] = __builtin_amdgcn_mfma_f32_16x16x32_bf16(qh_, kh, s4[n], 0, 0, 0);
                s4[n] = __builtin_amdgcn_mfma_f32_16x16x32_bf16(ql_, kh, s4[n], 0, 0, 0);
                s4[n] = __builtin_amdgcn_mfma_f32_16x16x32_bf16(qh_, kl, s4[n], 0, 0, 0);
            }
        }

#pragma unroll
        for (int n = 0; n < 4; n++) {
            int key = T * 64 + n * 16 + lr;
#pragma unroll
            for (int j = 0; j < 4; j++) {
                int gq = q0 + w * 16 + kc * 4 + j;
                float sv = s4[n][j] * scale;
                s4[n][j] = (key <= XLM + gq) ? sv : -1e30f;
            }
        }

        float tm[4];
#pragma unroll
        for (int j = 0; j < 4; j++) {
            float v = fmaxf(fmaxf(s4[0][j], s4[1][j]), fmaxf(s4[2][j], s4[3][j]));
            v = fmaxf(v, __shfl_xor(v, 1, 64));
            v = fmaxf(v, __shfl_xor(v, 2, 64));
            v = fmaxf(v, __shfl_xor(v, 4, 64));
            v = fmaxf(v, __shfl_xor(v, 8, 64));
            tm[j] = v;
        }
        float alpha[4];
#pragma unroll
        for (int j = 0; j < 4; j++) {
            float mnew = fmaxf(m[j], tm[j]);
            alpha[j] = __expf(m[j] - mnew);
            m[j] = mnew;
        }
        float psum[4] = {0.f, 0.f, 0.f, 0.f};
#pragma unroll
        for (int n = 0; n < 4; n++)
#pragma unroll
            for (int j = 0; j < 4; j++) {
                float p = __expf(s4[n][j] - m[j]);
                s4[n][j] = p;
                psum[j] += p;
            }
#pragma unroll
        for (int j = 0; j < 4; j++) {
            float v = psum[j];
            v += __shfl_xor(v, 1, 64);
            v += __shfl_xor(v, 2, 64);
            v += __shfl_xor(v, 4, 64);
            v += __shfl_xor(v, 8, 64);
            l[j] = l[j] * alpha[j] + v;
        }
#pragma unroll
        for (int f = 0; f < 4; f++)
#pragma unroll
            for (int j = 0; j < 4; j++) o[f][j] *= alpha[j];

        // P to wave-private LDS (wave-synchronous, no barrier needed)
#pragma unroll
        for (int n = 0; n < 4; n++) {
            int chunkcol = 2 * n + (lr >> 3);
#pragma unroll
            for (int j = 0; j < 4; j++) {
                int row = kc * 4 + j;
                int off = wbase + row * 64 + (((chunkcol ^ (row & 7)) << 3) + (lr & 7));
                sPf[off] = s4[n][j];
            }
        }

#pragma unroll
        for (int ks = 0; ks < 2; ks++) {
            int poff = wbase + lr * 64 + (((ks * 4 + kc) ^ (lr & 7)) << 3);
            float4 a = *(const float4*)&sPf[poff];
            float4 c2 = *(const float4*)&sPf[poff + 4];
            float vv[8] = {a.x, a.y, a.z, a.w, c2.x, c2.y, c2.z, c2.w};
            u16x8v hib, lob;
#pragma unroll
            for (int j = 0; j < 8; j++) {
                hib[j] = f2bfbits(vv[j]);
                lob[j] = f2bfbits(vv[j] - bfbits2f(hib[j]));
            }
            bf16x8v ph = *(bf16x8v*)&hib;
            bf16x8v pl = *(bf16x8v*)&lob;
#pragma unroll
            for (int f = 0; f < 4; f++) {
                int row = f * 16 + lr;
                int off = row * 64 + (((ks * 4 + kc) ^ (lr & 7)) << 3);
                bf16x8v vh = *(const bf16x8v*)&sVh[cur][off];
                bf16x8v vl = *(const bf16x8v*)&sVl[cur][off];
                o[f] = __builtin_amdgcn_mfma_f32_16x16x32_bf16(ph, vh, o[f], 0, 0, 0);
                o[f] = __builtin_amdgcn_mfma_f32_16x16x32_bf16(pl, vh, o[f], 0, 0, 0);
                o[f] = __builtin_amdgcn_mfma_f32_16x16x32_bf16(ph, vl, o[f], 0, 0, 0);
            }
        }

        // single barrier per tile: drains prefetch (vmcnt) + publishes buffers
        __syncthreads();
        cur ^= 1;
    }

    float inv[4];
#pragma unroll
    for (int j = 0; j < 4; j++) inv[j] = 1.0f / l[j];
    unsigned short* outu = (unsigned short*)out;
#pragma unroll
    for (int f = 0; f < 4; f++)
#pragma unroll
        for (int j = 0; j < 4; j++) {
            int gq = q0 + w * 16 + kc * 4 + j;
            size_t oidx = (size_t)(b * NSEQ + gq) * DIM + h * DH + f * 16 + lr;
            float v = o[f][j] * inv[j];
            unsigned short hv = f2bfbits(v);
            outu[oidx] = hv;
            outu[oidx + opS] = f2bfbits(v - bfbits2f(hv));
        }
    if (KNNL && lr == 0) {
#pragma unroll
        for (int j = 0; j < 4; j++) {
            int gq = q0 + w * 16 + kc * 4 + j;
            size_t srow = (((size_t)b * NH + h) * NSEQ + gq) * 2;
            stats[srow] = m[j];
            stats[srow + 1] = l[j];
        }
    }
}

// ---------------------------------------------------------------------------
// Per-row top-32 over bf16 simdb + exact recompute + mem softmax + combine.
// 4 waves per block, ONE ROW PER WAVE (no idle waves, no barriers).
__global__ __launch_bounds__(256) void knn_select(const unsigned short* __restrict__ simdb,
                                                  const float* __restrict__ db,
                                                  const float* __restrict__ qf,
                                                  const float* __restrict__ dbkn,
                                                  const float* __restrict__ knn_scale,
                                                  const float* __restrict__ stats,
                                                  __hip_bfloat16* __restrict__ out,
                                                  size_t opS,
                                                  int bh0) {
    __shared__ unsigned short sv[4 * 4096];

    int bh = bh0 + blockIdx.y;
    int b = bh >> 4, h = bh & 15;
    int t = threadIdx.x;
    int w = t >> 6, lane = t & 63;
    int i = blockIdx.x * 4 + w;
    unsigned short* svw = &sv[w * 4096];

    // stage this wave's row: 512 16B-chunks / 64 lanes = 8 iters
    const unsigned short* srow = &simdb[((size_t)blockIdx.y * NSEQ + i) * MDB];
#pragma unroll
    for (int it = 0; it < 8; it++) {
        int g = it * 64 + lane;
        int c = g >> 3, sub = g & 7;
        u16x8v d = *(const u16x8v*)&srow[(size_t)g * 8];
        *(u16x8v*)&svw[c * 64 + ((sub ^ (c & 7)) << 3)] = d;
    }

    // per-column candidates: lane owns column l, scans 64 chunks
    float lmax = -1e30f; int lidx = 0;
#pragma unroll
    for (int c = 0; c < 64; c++) {
        float v = bfbits2f(svw[c * 64 + (lane ^ ((c & 7) << 3))]);
        if (v > lmax) { lmax = v; lidx = c * 64 + lane; }
    }

    // 32 selection iterations, wave-synchronous
    int tidx = 0;
    for (int it = 0; it < TOPK; it++) {
        float v = lmax; int idx = lidx;
#pragma unroll
        for (int off = 32; off; off >>= 1) {
            float v2 = __shfl_xor(v, off, 64);
            int i2 = __shfl_xor(idx, off, 64);
            if (v2 > v || (v2 == v && i2 < idx)) { v = v2; idx = i2; }
        }
        if (lane == it) tidx = idx;
        int col = idx & 63, cc = idx >> 6;
        if (lane == 0) svw[cc * 64 + (col ^ ((cc & 7) << 3))] = 0xFF80; // bf16 -inf
        // rescan column col: lane reads element (c=lane, col)
        float rv = bfbits2f(svw[lane * 64 + (col ^ ((lane & 7) << 3))]);
        int ridx = lane * 64 + col;
#pragma unroll
        for (int off = 32; off; off >>= 1) {
            float v2 = __shfl_xor(rv, off, 64);
            int i2 = __shfl_xor(ridx, off, 64);
            if (v2 > rv || (v2 == rv && i2 < ridx)) { rv = v2; ridx = i2; }
        }
        if (lane == col) { lmax = rv; lidx = ridx; }
    }

    // exact recompute of selected sims (lane j < 32 recomputes sim of its idx)
    float srec = -1e30f;
    if (lane < TOPK) {
        const float* qrow = &qf[(size_t)(b * NSEQ + i) * DIM + h * DH];
        const float* krow = &dbkn[((size_t)b * MDB + tidx) * DH];
        float s = 0.f;
#pragma unroll
        for (int d4 = 0; d4 < 16; d4++) {
            float4 a = *(const float4*)&qrow[d4 * 4];
            float4 k2 = *(const float4*)&krow[d4 * 4];
            s += a.x * k2.x + a.y * k2.y + a.z * k2.z + a.w * k2.w;
        }
        srec = s;
    }

    float scl = __expf(knn_scale[h]);
    size_t srow_idx = (((size_t)b * NH + h) * NSEQ + i) * 2;
    float m_loc = stats[srow_idx], l_loc = stats[srow_idx + 1];
    float mm = srec;
#pragma unroll
    for (int off = 32; off; off >>= 1) mm = fmaxf(mm, __shfl_xor(mm, off, 64));
    float M = fmaxf(m_loc, mm * scl);
    float co = __expf(m_loc - M);
    float e = (lane < TOPK) ? __expf(srec * scl - M) : 0.f;
    float esum = e;
#pragma unroll
    for (int off = 32; off; off >>= 1) esum += __shfl_xor(esum, off, 64);
    float denom = l_loc * co + esum;

    // gather: lane = output dim; iterate 32 selected keys via shfl broadcast
    float acc = 0.f;
#pragma unroll
    for (int j = 0; j < TOPK; j++) {
        int idxj = __shfl(tidx, j, 64);
        float ej = __shfl(e, j, 64);
        acc += ej * db[(((size_t)b * MDB + idxj) * 2 + 1) * DH + lane];
    }

    size_t op = (size_t)(b * NSEQ + i) * DIM + h * DH + lane;
    float o_loc = bf2f(out[op]) + bf2f(out[op + opS]);
    float nv = (o_loc * l_loc * co + acc) / denom;
    __hip_bfloat16 hv = f2bf(nv);
    out[op] = hv;
    out[op + opS] = f2bf(nv - bf2f(hv));
}

// ---------------------------------------------------------------------------
extern "C" void kernel_launch(void* const* d_in, const int* in_sizes, int n_in,
                              void* d_out, int out_size, void* d_ws, size_t ws_size,
                              hipStream_t stream) {
    const int* tokens = (const int*)d_in[0];
    const float* emb = (const float*)d_in[1];
    const float* ln1_w = (const float*)d_in[2];
    const float* ln1_b = (const float*)d_in[3];
    const float* wq = (const float*)d_in[4];
    const float* wkv = (const float*)d_in[5];
    const float* wo = (const float*)d_in[6];
    const float* wo_b = (const float*)d_in[7];
    const float* knn_scale = (const float*)d_in[8];
    const float* ln2_w = (const float*)d_in[9];
    const float* ln2_b = (const float*)d_in[10];
    const float* ff_w1 = (const float*)d_in[11];
    const float* ff_b1 = (const float*)d_in[12];
    const float* ff_w2 = (const float*)d_in[13];
    const float* ff_b2 = (const float*)d_in[14];
    const float* lnf_w = (const float*)d_in[15];
    const float* lnf_b = (const float*)d_in[16];
    const float* w_logits = (const float*)d_in[17];
    const float* b_logits = (const float*)d_in[18];
    const float* xl_mems = (const float*)d_in[19];
    const float* db_kv = (const float*)d_in[20];

    // ---- workspace layout ----
    const size_t PS_H = (size_t)BNROWS * DIM;        // plane stride for h / attn-out
    char* p = (char*)d_ws;
    float* x = (float*)p;                p += PS_H * 4;                        // 8 MB
    __hip_bfloat16* hb = (__hip_bfloat16*)p;  p += PS_H * 2 * 2;               // 8 MB (2 planes)
    float* qf = (float*)p;               p += PS_H * 4;                        // 8 MB
    float* kvf = (float*)p;              p += (size_t)BNROWS * 128 * 4;        // 1 MB
    float* dbkn = (float*)p;             p += (size_t)BB * MDB * DH * 4;       // 2 MB
    float* stats = (float*)p;            p += (size_t)BB * NH * NSEQ * 2 * 4;  // 0.25 MB
    unsigned short* ksp = (unsigned short*)p; p += KSP_PS * 2 * 2;             // 0.66 MB
    unsigned short* vtp = (unsigned short*)p; p += KSP_PS * 2 * 2;             // 0.66 MB
    __hip_bfloat16* wT = (__hip_bfloat16*)p; p += (size_t)4096 * DIM * 2 * 2;  // 16 MB (2 planes)

    // qsplit/dbkn-split live in the wT region during the KNN phase (wT idle)
    unsigned short* qsplit = (unsigned short*)wT;                  // 2 planes x PS_H
    unsigned short* dbks = (unsigned short*)wT + 2 * PS_H;         // 2 planes x BB*MDB*DH
    const size_t PS_DB = (size_t)BB * MDB * DH;

    const size_t PS_MID = (size_t)BNROWS * 4 * DIM;  // 8M elems per plane
    __hip_bfloat16* midb = (__hip_bfloat16*)d_out;   // 32 MB of the 262 MB out buf
    float* logits = (float*)d_out;
    // split-K partial buffers: d_out + 96 MB (clear of simdb 0..67MB and midb)
    float* part = (float*)((char*)d_out + ((size_t)96 << 20));

    const size_t PS_QKV = (size_t)BNROWS * NQKV;     // merged q|kv partial plane

    embed_kernel<<<BNROWS, 256, 0, stream>>>(tokens, emb, x);
    dbnorm_kernel<<<BB * MDB, 64, 0, stream>>>(db_kv, dbkn);
    // first LN (later LNs are fused into combine_ln)
    ln_kernel<<<BNROWS, 256, 0, stream>>>(x, ln1_w, ln1_b, hb, PS_H);

    for (int l = 0; l < DEPTH; l++) {
        const float* wq_l = wq + (size_t)l * DIM * DIM;
        const float* wkv_l = wkv + (size_t)l * DIM * 128;
        const float* wo_l = wo + (size_t)l * DIM * DIM;
        const float* xlm_l = xl_mems + (size_t)l * BB * XLM * 2 * DH;

        // q|kv = h @ [wq wkv]  (merged N=1152, split-K=4 -> combine_qkv)
        wconv<<<dim3(16, 16), 256, 0, stream>>>(wq_l, wT, (size_t)NQKV * DIM, DIM, DIM, DIM, 1);
        wconv<<<dim3(16, 2), 256, 0, stream>>>(wkv_l, wT + (size_t)DIM * DIM, (size_t)NQKV * DIM, DIM, 128, 128, 1);
        gemm_split<float, 0, 3, 2><<<dim3(NQKV / 128, BNROWS / 128, 4), 256, 0, stream>>>(
            hb, DIM, PS_H, wT, DIM, (size_t)NQKV * DIM, part, NQKV, PS_QKV, 256, nullptr, nullptr, 0);
        combine_qkv<4><<<(PS_QKV / 4 + 255) / 256, 256, 0, stream>>>(
            part, PS_QKV, qf, kvf, PS_QKV / 4);

        if (l == KNN_LAYER) {
            // fused q l2norm + split planes; fresh-k normalized inside kv_prep
            l2split_q<<<BNROWS * NH, 64, 0, stream>>>(qf, qsplit, PS_H);
            kv_prep<1><<<dim3(NKEYS, BB), 64, 0, stream>>>(kvf, xlm_l, ksp, vtp);
            split_conv<<<(PS_DB / 4 + 255) / 256, 256, 0, stream>>>(dbkn, dbks, PS_DB, PS_DB / 4);
            flash_kernel<1><<<dim3(NSEQ / 64, NH, BB), 256, 0, stream>>>(
                qf, ksp, vtp, knn_scale, hb, PS_H, stats);
            const int CHUNK = 8;  // 8 x 8 MB bf16 = 67 MB per gemm->select pair
            for (int bh0 = 0; bh0 < BB * NH; bh0 += CHUNK) {
                // TERMS=1: selection-grade sims (exact recompute in knn_select)
                gemm_split<unsigned short, 0, 1, 1><<<dim3(MDB / 128, NSEQ / 128, CHUNK), 256, 0, stream>>>(
                    (const __hip_bfloat16*)qsplit, DIM, PS_H,
                    (const __hip_bfloat16*)dbks, DH, PS_DB,
                    (unsigned short*)d_out, MDB, 0, DH, nullptr, nullptr, bh0);
                knn_select<<<dim3(NSEQ / 4, CHUNK), 256, 0, stream>>>(
                    (const unsigned short*)d_out, db_kv, qf, dbkn, knn_scale, stats, hb, PS_H, bh0);
            }
        } else {
            kv_prep<0><<<dim3(NKEYS, BB), 64, 0, stream>>>(kvf, xlm_l, ksp, vtp);
            flash_kernel<0><<<dim3(NSEQ / 64, NH, BB), 256, 0, stream>>>(
                qf, ksp, vtp, knn_scale, hb, PS_H, stats);
        }

        // x = attn @ wo + wo_b + x; h = LN2(x)   (split-K=4 + fused combine+LN)
        wconv<<<dim3(16, 16), 256, 0, stream>>>(wo_l, wT, (size_t)DIM * DIM, DIM, DIM, DIM, 1);
        gemm_split<float, 0, 3, 2><<<dim3(DIM / 128, BNROWS / 128, 4), 256, 0, stream>>>(
            hb, DIM, PS_H, wT, DIM, (size_t)DIM * DIM, part, DIM, PS_H, 256, nullptr, nullptr, 0);
        combine_ln<4><<<BNROWS, 256, 0, stream>>>(
            part, PS_H, wo_b + (size_t)l * DIM, x,
            ln2_w + (size_t)l * DIM, ln2_b + (size_t)l * DIM, hb, PS_H);

        // mid = gelu(h @ ff_w1 + b1)  (split-K=2 + fused combine+gelu+split)
        wconv<<<dim3(16, 64), 256, 0, stream>>>(ff_w1 + (size_t)l * DIM * 4 * DIM, wT, (size_t)4096 * DIM, DIM, 4 * DIM, 4 * DIM, 1);
        gemm_split<float, 0, 3, 2><<<dim3(4 * DIM / 128, BNROWS / 128, 2), 256, 0, stream>>>(
            hb, DIM, PS_H, wT, DIM, (size_t)4096 * DIM, part, 4 * DIM, PS_MID, 512, nullptr, nullptr, 0);
        combine_gelu_split<2><<<(PS_MID / 4 + 255) / 256, 256, 0, stream>>>(
            part, PS_MID, ff_b1 + (size_t)l * 4 * DIM, 4 * DIM,
            (unsigned short*)midb, PS_MID, PS_MID / 4);

        // x = mid @ ff_w2 + b2 + x; h = LN_next(x)  (split-K=4 + fused)
        wconv<<<dim3(64, 16), 256, 0, stream>>>(ff_w2 + (size_t)l * 4 * DIM * DIM, wT, (size_t)DIM * 4096, 4 * DIM, DIM, DIM, 1);
        gemm_split<float, 0, 3, 2><<<dim3(DIM / 128, BNROWS / 128, 4), 256, 0, stream>>>(
            midb, 4 * DIM, PS_MID, wT, 4 * DIM, (size_t)DIM * 4096, part, DIM, PS_H, 1024, nullptr, nullptr, 0);
        const float* nw = (l < DEPTH - 1) ? ln1_w + (size_t)(l + 1) * DIM : lnf_w;
        const float* nb = (l < DEPTH - 1) ? ln1_b + (size_t)(l + 1) * DIM : lnf_b;
        combine_ln<4><<<BNROWS, 256, 0, stream>>>(
            part, PS_H, ff_b2 + (size_t)l * DIM, x, nw, nb, hb, PS_H);
    }

    // logits (hb already holds LNf output; 5 column chunks, hi-plane bf16)
    for (int c0 = 0; c0 < VOCAB; c0 += LOGITS_CHUNK) {
        wconv<<<dim3(16, LOGITS_CHUNK / 64), 256, 0, stream>>>(
            w_logits + c0, wT, 0, DIM, LOGITS_CHUNK, VOCAB, 0);
        gemm_split<float, 0, 1, 0><<<dim3(LOGITS_CHUNK / 128, BNROWS / 128), 256, 0, stream>>>(
            hb, DIM, PS_H, wT, DIM, 0, logits + c0, VOCAB, 0, DIM,
            b_logits + c0, nullptr, 0);
    }
}

// Round 16
// 2226.690 us; speedup vs baseline: 1.2864x; 1.0009x over previous
//
#include <hip/hip_runtime.h>
#include <hip/hip_bf16.h>
#include <math.h>

// Problem constants (from setup_inputs)
#define BB 2
#define NSEQ 1024
#define DIM 1024
#define NH 16
#define DH 64
#define DEPTH 4
#define VOCAB 32000
#define XLM 256
#define MDB 4096
#define TOPK 32
#define KNN_LAYER 2
#define BNROWS (BB * NSEQ)   // 2048
#define LOGITS_CHUNK 6400    // 32000 = 5 * 6400
#define NKEYS 1280           // XLM + NSEQ
#define NQKV 1152            // 1024 (q) + 128 (kv) merged projection width
#define KSP_PS ((size_t)BB * NKEYS * DH)   // plane stride for K/V split planes

typedef __bf16 bf16x8v __attribute__((ext_vector_type(8)));
typedef float f32x4v __attribute__((ext_vector_type(4)));
typedef unsigned short u16x8v __attribute__((ext_vector_type(8)));

__device__ __forceinline__ float bfbits2f(unsigned short u) {
    union { float f; unsigned int i; } v; v.i = ((unsigned int)u) << 16; return v.f;
}
__device__ __forceinline__ unsigned short f2bfbits(float f) {
    union { __hip_bfloat16 b; unsigned short u; } v;
    v.b = __float2bfloat16(f);
    return v.u;
}
__device__ __forceinline__ float bf2f(__hip_bfloat16 h) { return __bfloat162float(h); }
__device__ __forceinline__ __hip_bfloat16 f2bf(float f) { return __float2bfloat16(f); }

__device__ __forceinline__ void gload16(const void* gp, void* lp) {
    __builtin_amdgcn_global_load_lds(
        (const __attribute__((address_space(1))) unsigned int*)gp,
        (__attribute__((address_space(3))) unsigned int*)lp, 16, 0, 0);
}

// ---------------------------------------------------------------------------
__global__ __launch_bounds__(256) void embed_kernel(const int* __restrict__ tok,
                                                    const float* __restrict__ emb,
                                                    float* __restrict__ x) {
    int r = blockIdx.x, t = threadIdx.x;
    int id = tok[r];
    const float* er = emb + (size_t)id * DIM;
    float* xr = x + (size_t)r * DIM;
#pragma unroll
    for (int i = 0; i < 4; i++) xr[t + 256 * i] = er[t + 256 * i];
}

// ---------------------------------------------------------------------------
// Row LayerNorm over DIM=1024, fp32 in, split-bf16 (hi/lo planes) out
__global__ __launch_bounds__(256) void ln_kernel(const float* __restrict__ x,
                                                 const float* __restrict__ w,
                                                 const float* __restrict__ b,
                                                 __hip_bfloat16* __restrict__ y,
                                                 size_t ypS) {
    __shared__ float red[256];
    int r = blockIdx.x, t = threadIdx.x;
    const float* xr = x + (size_t)r * DIM;
    float v[4];
#pragma unroll
    for (int i = 0; i < 4; i++) v[i] = xr[t + 256 * i];
    float s = v[0] + v[1] + v[2] + v[3];
    red[t] = s; __syncthreads();
    for (int st = 128; st; st >>= 1) { if (t < st) red[t] += red[t + st]; __syncthreads(); }
    float mean = red[0] * (1.0f / DIM);
    __syncthreads();
    float s2 = 0.f;
#pragma unroll
    for (int i = 0; i < 4; i++) { float d = v[i] - mean; s2 += d * d; }
    red[t] = s2; __syncthreads();
    for (int st = 128; st; st >>= 1) { if (t < st) red[t] += red[t + st]; __syncthreads(); }
    float rs = rsqrtf(red[0] * (1.0f / DIM) + 1e-5f);
    __hip_bfloat16* yr = y + (size_t)r * DIM;
#pragma unroll
    for (int i = 0; i < 4; i++) {
        int c = t + 256 * i;
        float val = (v[i] - mean) * rs * w[c] + b[c];
        __hip_bfloat16 hv = f2bf(val);
        yr[c] = hv;
        yr[c + ypS] = f2bf(val - bf2f(hv));
    }
}

// ---------------------------------------------------------------------------
// Fused split-K combine + residual + LayerNorm:
// x[r,:] += sum_z part[z] + bias;  y = LN(x[r,:]) as split-bf16 planes.
template <int NP>
__global__ __launch_bounds__(256) void combine_ln(const float* __restrict__ pbuf, size_t pS,
                                                  const float* __restrict__ bias,
                                                  float* __restrict__ x,
                                                  const float* __restrict__ w,
                                                  const float* __restrict__ b,
                                                  __hip_bfloat16* __restrict__ y,
                                                  size_t ypS) {
    __shared__ float red[256];
    int r = blockIdx.x, t = threadIdx.x;
    float v[4];
#pragma unroll
    for (int i = 0; i < 4; i++) {
        int c = t + 256 * i;
        size_t idx = (size_t)r * DIM + c;
        float s = bias[c] + x[idx];
#pragma unroll
        for (int z = 0; z < NP; z++) s += pbuf[(size_t)z * pS + idx];
        v[i] = s;
        x[idx] = s;
    }
    float s = v[0] + v[1] + v[2] + v[3];
    red[t] = s; __syncthreads();
    for (int st = 128; st; st >>= 1) { if (t < st) red[t] += red[t + st]; __syncthreads(); }
    float mean = red[0] * (1.0f / DIM);
    __syncthreads();
    float s2 = 0.f;
#pragma unroll
    for (int i = 0; i < 4; i++) { float d = v[i] - mean; s2 += d * d; }
    red[t] = s2; __syncthreads();
    for (int st = 128; st; st >>= 1) { if (t < st) red[t] += red[t + st]; __syncthreads(); }
    float rs = rsqrtf(red[0] * (1.0f / DIM) + 1e-5f);
    __hip_bfloat16* yr = y + (size_t)r * DIM;
#pragma unroll
    for (int i = 0; i < 4; i++) {
        int c = t + 256 * i;
        float val = (v[i] - mean) * rs * w[c] + b[c];
        __hip_bfloat16 hv = f2bf(val);
        yr[c] = hv;
        yr[c + ypS] = f2bf(val - bf2f(hv));
    }
}

// ---------------------------------------------------------------------------
// Fused q l2norm + split-plane write (4 rows per 256-thr block, 1 row/wave).
__global__ __launch_bounds__(256) void l2split_q(float* __restrict__ qf,
                                                 unsigned short* __restrict__ qs,
                                                 size_t pS) {
    int t = threadIdx.x;
    int w = t >> 6, lane = t & 63;
    int r = blockIdx.x * 4 + w;
    size_t idx = (size_t)r * DH + lane;
    float v = qf[idx];
    float s = v * v;
#pragma unroll
    for (int off = 32; off; off >>= 1) s += __shfl_xor(s, off, 64);
    float n = fmaxf(sqrtf(s), 1e-12f);
    v /= n;
    qf[idx] = v;
    unsigned short hv = f2bfbits(v);
    qs[idx] = hv;
    qs[idx + pS] = f2bfbits(v - bfbits2f(hv));
}

// ---------------------------------------------------------------------------
// Fused db-key l2norm + fp32 + split-bf16 plane write (4 rows/block).
__global__ __launch_bounds__(256) void dbprep(const float* __restrict__ db,
                                              float* __restrict__ dbkn,
                                              unsigned short* __restrict__ dbks,
                                              size_t pS) {
    int t = threadIdx.x;
    int w = t >> 6, lane = t & 63;
    int r = blockIdx.x * 4 + w;
    float v = db[((size_t)r * 2 + 0) * DH + lane];
    float s = v * v;
#pragma unroll
    for (int off = 32; off; off >>= 1) s += __shfl_xor(s, off, 64);
    float n = fmaxf(sqrtf(s), 1e-12f);
    v /= n;
    size_t idx = (size_t)r * DH + lane;
    dbkn[idx] = v;
    unsigned short hv = f2bfbits(v);
    dbks[idx] = hv;
    dbks[idx + pS] = f2bfbits(v - bfbits2f(hv));
}

// ---------------------------------------------------------------------------
// Split-K combine for the merged q|kv projection: part rows are 1152 wide
// (cols 0..1023 -> qf, 1024..1151 -> kvf).
template <int NP>
__global__ __launch_bounds__(256) void combine_qkv(const float* __restrict__ pbuf, size_t pS,
                                                   float* __restrict__ qf,
                                                   float* __restrict__ kvf,
                                                   size_t n4) {
    size_t idx = (size_t)blockIdx.x * 256 + threadIdx.x;
    if (idx >= n4) return;
    f32x4v s = *(const f32x4v*)&pbuf[idx * 4];
#pragma unroll
    for (int z = 1; z < NP; z++) {
        f32x4v v = *(const f32x4v*)&pbuf[(size_t)z * pS + idx * 4];
        s += v;
    }
    size_t e = idx * 4;
    size_t row = e / NQKV;
    int col = (int)(e - row * NQKV);
    if (col < DIM) *(f32x4v*)&qf[row * DIM + col] = s;
    else *(f32x4v*)&kvf[row * 128 + (col - DIM)] = s;
}

// ---------------------------------------------------------------------------
// Split-K combine + bias + exact GELU + split-bf16 plane write (for ff1).
template <int NP>
__global__ __launch_bounds__(256) void combine_gelu_split(const float* __restrict__ pbuf, size_t pS,
                                                          const float* __restrict__ bias, int N,
                                                          unsigned short* __restrict__ y, size_t ypS,
                                                          size_t n4) {
    size_t idx = (size_t)blockIdx.x * 256 + threadIdx.x;
    if (idx >= n4) return;
    f32x4v s = *(const f32x4v*)&pbuf[idx * 4];
#pragma unroll
    for (int z = 1; z < NP; z++) {
        f32x4v v = *(const f32x4v*)&pbuf[(size_t)z * pS + idx * 4];
        s += v;
    }
    int col = (int)((idx * 4) % (size_t)N);
    const f32x4v bv = *(const f32x4v*)&bias[col];
    s += bv;
    ushort4 h4, l4;
    unsigned short* hp = (unsigned short*)&h4;
    unsigned short* lp = (unsigned short*)&l4;
#pragma unroll
    for (int j = 0; j < 4; j++) {
        float v = s[j];
        v = 0.5f * v * (1.0f + erff(v * 0.70710678118654752f));
        hp[j] = f2bfbits(v);
        lp[j] = f2bfbits(v - bfbits2f(hp[j]));
    }
    *(ushort4*)&y[idx * 4] = h4;
    *(ushort4*)&y[idx * 4 + ypS] = l4;
}

// ---------------------------------------------------------------------------
// Per-layer K/V split-bf16 prep (NORM: l2-normalize fresh keys on the fly):
// K planes [b][key][dim]; V transposed planes [b][dim][key].
template <int NORM>
__global__ void kv_prep(const float* __restrict__ kvf, const float* __restrict__ xlm,
                        unsigned short* __restrict__ ksp, unsigned short* __restrict__ vtp) {
    int key = blockIdx.x, b = blockIdx.y, d = threadIdx.x; // 64 threads
    float kvv, vvv;
    if (key < XLM) {
        kvv = xlm[(((size_t)b * XLM + key) * 2 + 0) * DH + d];
        vvv = xlm[(((size_t)b * XLM + key) * 2 + 1) * DH + d];
    } else {
        const float* r = &kvf[(size_t)(b * NSEQ + key - XLM) * 128];
        kvv = r[d]; vvv = r[64 + d];
        if (NORM) {
            float s = kvv * kvv;
#pragma unroll
            for (int off = 32; off; off >>= 1) s += __shfl_xor(s, off, 64);
            kvv /= fmaxf(sqrtf(s), 1e-12f);
        }
    }
    unsigned short kh = f2bfbits(kvv), kl = f2bfbits(kvv - bfbits2f(kh));
    unsigned short vh = f2bfbits(vvv), vl = f2bfbits(vvv - bfbits2f(vh));
    size_t ko = (size_t)b * NKEYS * DH + (size_t)key * DH + d;
    ksp[ko] = kh; ksp[ko + KSP_PS] = kl;
    size_t vo = (size_t)b * DH * NKEYS + (size_t)d * NKEYS + key;
    vtp[vo] = vh; vtp[vo + KSP_PS] = vl;
}

// ---------------------------------------------------------------------------
// Weight convert + transpose: W (K x N fp32, row stride ldw) ->
// WT (N x K split-bf16, hi plane + lo plane at +wpS). wlo=0: hi only.
__global__ __launch_bounds__(256) void wconv(const float* __restrict__ W,
                                             __hip_bfloat16* __restrict__ WT,
                                             size_t wpS, int K, int N, int ldw,
                                             int wlo) {
    __shared__ float tile[64][65];
    int k0 = blockIdx.x * 64, n0 = blockIdx.y * 64;
    int t = threadIdx.x;
    int r = t >> 4, c4 = (t & 15) * 4;
#pragma unroll
    for (int rr = 0; rr < 4; rr++) {
        int row = rr * 16 + r;
        float4 v = *(const float4*)&W[(size_t)(k0 + row) * ldw + n0 + c4];
        tile[row][c4] = v.x; tile[row][c4 + 1] = v.y; tile[row][c4 + 2] = v.z; tile[row][c4 + 3] = v.w;
    }
    __syncthreads();
#pragma unroll
    for (int rr = 0; rr < 4; rr++) {
        int nrow = rr * 16 + r;
        size_t base = (size_t)(n0 + nrow) * K + k0 + c4;
#pragma unroll
        for (int j = 0; j < 4; j++) {
            float val = tile[c4 + j][nrow];
            __hip_bfloat16 hv = f2bf(val);
            WT[base + j] = hv;
            if (wlo) WT[base + j + wpS] = f2bf(val - bf2f(hv));
        }
    }
}

// ---------------------------------------------------------------------------
// Split-bf16 MFMA GEMM: C(MxN) = A(MxK) @ BT(NxK)^T with A,B as hi/lo planes.
// TERMS: 3 = hi*hi + lo*hi + hi*lo (fp32-grade); 1 = hi*hi only (bf16-grade).
// OT: float / __hip_bfloat16 (split 2-plane) / unsigned short (single bf16).
// MODE: 0 = normal; 1 = simdb batch over bh (z dim);
//       2 = split-K (z = K-slice; K param is the slice length; partial
//           written to C + z*cpS; bias/res must be null).
// XCD-aware bijective block swizzle applied to (x,y) when nwg % 8 == 0.
template <typename OT, int ACT, int TERMS, int MODE>
__global__ __launch_bounds__(256) void gemm_split(const __hip_bfloat16* __restrict__ A, int lda, size_t apS,
                                                  const __hip_bfloat16* __restrict__ BT, int ldb, size_t bpS,
                                                  OT* __restrict__ C, int ldc, size_t cpS, int K,
                                                  const float* __restrict__ bias,
                                                  const float* __restrict__ res,
                                                  int bh0) {
    __shared__ __align__(16) __hip_bfloat16 sAh[128 * 32];
    __shared__ __align__(16) __hip_bfloat16 sBh[128 * 32];
    __shared__ __align__(16) __hip_bfloat16 sAl[TERMS >= 2 ? 128 * 32 : 1];
    __shared__ __align__(16) __hip_bfloat16 sBl[TERMS >= 3 ? 128 * 32 : 1];
    if constexpr (MODE == 1) {
        int bh = bh0 + blockIdx.z;
        A += ((size_t)(bh >> 4) * NSEQ) * lda + (bh & 15) * DH;
        BT += (size_t)(bh >> 4) * MDB * ldb;
        C += (size_t)blockIdx.z * NSEQ * ldc;
    }
    if constexpr (MODE == 2) {
        A += (size_t)blockIdx.z * K;
        BT += (size_t)blockIdx.z * K;
        C += (size_t)blockIdx.z * cpS;
    }
    // XCD swizzle on the (x,y)-flattened tile index (bijective; nwg % 8 == 0)
    int nwg = gridDim.x * gridDim.y;
    int bid = blockIdx.y * gridDim.x + blockIdx.x;
    if ((nwg & 7) == 0) {
        int cpx = nwg >> 3;
        bid = (bid & 7) * cpx + (bid >> 3);
    }
    int bn = (bid % gridDim.x) * 128;
    int bm = (bid / gridDim.x) * 128;
    int t = threadIdx.x;
    int lane = t & 63, wid = t >> 6;
    int wr = wid >> 1, wc = wid & 1;
    int lr = lane & 15, kc = lane >> 4;

    f32x4v acc[4][4];
#pragma unroll
    for (int m = 0; m < 4; m++)
#pragma unroll
        for (int n = 0; n < 4; n++) acc[m][n] = (f32x4v){0.f, 0.f, 0.f, 0.f};

    for (int k0 = 0; k0 < K; k0 += 32) {
        __syncthreads();
#pragma unroll
        for (int it = 0; it < 2; it++) {
            int e = wid * 128 + it * 64 + lane;
            int r = e >> 2;
            int cl = (e & 3) ^ ((r >> 1) & 3);
            size_t aoff = (size_t)(bm + r) * lda + k0 + cl * 8;
            size_t boff = (size_t)(bn + r) * ldb + k0 + cl * 8;
            int dst = (wid * 128 + it * 64) * 8;
            gload16(&A[aoff], &sAh[dst]);
            gload16(&BT[boff], &sBh[dst]);
            if constexpr (TERMS >= 2) gload16(&A[aoff + apS], &sAl[dst]);
            if constexpr (TERMS >= 3) gload16(&BT[boff + bpS], &sBl[dst]);
        }
        __syncthreads();

        bf16x8v ah[4], al[4], bh[4], bl[4];
#pragma unroll
        for (int m = 0; m < 4; m++) {
            int row = wr * 64 + m * 16 + lr;
            int off = row * 32 + ((kc ^ ((row >> 1) & 3)) << 3);
            ah[m] = *(const bf16x8v*)&sAh[off];
            if constexpr (TERMS >= 2) al[m] = *(const bf16x8v*)&sAl[off];
        }
#pragma unroll
        for (int n = 0; n < 4; n++) {
            int row = wc * 64 + n * 16 + lr;
            int off = row * 32 + ((kc ^ ((row >> 1) & 3)) << 3);
            bh[n] = *(const bf16x8v*)&sBh[off];
            if constexpr (TERMS >= 3) bl[n] = *(const bf16x8v*)&sBl[off];
        }
#pragma unroll
        for (int m = 0; m < 4; m++)
#pragma unroll
            for (int n = 0; n < 4; n++) {
                acc[m][n] = __builtin_amdgcn_mfma_f32_16x16x32_bf16(ah[m], bh[n], acc[m][n], 0, 0, 0);
                if constexpr (TERMS >= 2)
                    acc[m][n] = __builtin_amdgcn_mfma_f32_16x16x32_bf16(al[m], bh[n], acc[m][n], 0, 0, 0);
                if constexpr (TERMS >= 3)
                    acc[m][n] = __builtin_amdgcn_mfma_f32_16x16x32_bf16(ah[m], bl[n], acc[m][n], 0, 0, 0);
            }
    }

#pragma unroll
    for (int m = 0; m < 4; m++) {
#pragma unroll
        for (int n = 0; n < 4; n++) {
            int gcol = bn + wc * 64 + n * 16 + lr;
            float bv = bias ? bias[gcol] : 0.f;
#pragma unroll
            for (int j = 0; j < 4; j++) {
                int grow = bm + wr * 64 + m * 16 + kc * 4 + j;
                float v = acc[m][n][j] + bv;
                if (ACT == 1) v = 0.5f * v * (1.0f + erff(v * 0.70710678118654752f));
                if (res) v += res[(size_t)grow * ldc + gcol];
                size_t idx = (size_t)grow * ldc + gcol;
                if constexpr (__is_same(OT, float)) {
                    C[idx] = v;
                } else if constexpr (__is_same(OT, unsigned short)) {
                    C[idx] = f2bfbits(v);
                } else {
                    __hip_bfloat16 hv = f2bf(v);
                    C[idx] = hv;
                    C[idx + cpS] = f2bf(v - bf2f(hv));
                }
            }
        }
    }
}

// ---------------------------------------------------------------------------
// Split-bf16 MFMA flash attention over XL + causal local keys.
// K/V pre-split by kv_prep; staging is pure global_load_lds, DOUBLE-BUFFERED.
template <int KNNL>
__global__ __launch_bounds__(256) void flash_kernel(const float* __restrict__ q,
                                                    const unsigned short* __restrict__ ksp,
                                                    const unsigned short* __restrict__ vtp,
                                                    const float* __restrict__ knn_scale,
                                                    __hip_bfloat16* __restrict__ out,
                                                    size_t opS,
                                                    float* __restrict__ stats) {
    __shared__ __align__(16) unsigned short sKh[2][4096];
    __shared__ __align__(16) unsigned short sKl[2][4096];
    __shared__ __align__(16) unsigned short sVh[2][4096];   // transposed [dim][key]
    __shared__ __align__(16) unsigned short sVl[2][4096];
    __shared__ __align__(16) float sPf[4 * 16 * 64];        // per-wave P fp32

    int qt = blockIdx.x, h = blockIdx.y, b = blockIdx.z;
    int q0 = qt * 64;
    int t = threadIdx.x;
    int w = t >> 6;
    int lane = t & 63;
    int lr = lane & 15, kc = lane >> 4;
    int wbase = w * 1024;

    float scale = KNNL ? __expf(knn_scale[h]) : 0.125f;

    bf16x8v qh[2], ql[2];
    {
        const float* qbase = q + (size_t)(b * NSEQ + q0 + w * 16 + lr) * DIM + h * DH;
#pragma unroll
        for (int ks = 0; ks < 2; ks++) {
            const float* s = qbase + ks * 32 + kc * 8;
            float4 a = *(const float4*)s;
            float4 c2 = *(const float4*)(s + 4);
            float vv[8] = {a.x, a.y, a.z, a.w, c2.x, c2.y, c2.z, c2.w};
            u16x8v hi, lo;
#pragma unroll
            for (int j = 0; j < 8; j++) {
                hi[j] = f2bfbits(vv[j]);
                lo[j] = f2bfbits(vv[j] - bfbits2f(hi[j]));
            }
            qh[ks] = *(bf16x8v*)&hi;
            ql[ks] = *(bf16x8v*)&lo;
        }
    }

    float m[4], l[4];
    f32x4v o[4];
#pragma unroll
    for (int j = 0; j < 4; j++) { m[j] = -1e30f; l[j] = 0.f; }
#pragma unroll
    for (int f = 0; f < 4; f++) o[f] = (f32x4v){0.f, 0.f, 0.f, 0.f};

    int ntiles = 5 + qt;
    size_t kbase = (size_t)b * NKEYS * DH;
    size_t vbase = (size_t)b * DH * NKEYS;

    auto stage = [&](int buf, int T) {
#pragma unroll
        for (int i2 = 0; i2 < 2; i2++) {
            int cbase = i2 * 256 + w * 64;
            int c = cbase + lane;
            int key = c >> 3, ch = (c & 7) ^ (key & 7);
            size_t ko = kbase + (size_t)(T * 64 + key) * DH + ch * 8;
            gload16(&ksp[ko], &sKh[buf][cbase * 8]);
            gload16(&ksp[ko + KSP_PS], &sKl[buf][cbase * 8]);
            int dim = c >> 3, k8 = (c & 7) ^ (dim & 7);
            size_t vo = vbase + (size_t)dim * NKEYS + T * 64 + k8 * 8;
            gload16(&vtp[vo], &sVh[buf][cbase * 8]);
            gload16(&vtp[vo + KSP_PS], &sVl[buf][cbase * 8]);
        }
    };

    stage(0, 0);
    __syncthreads();
    int cur = 0;

    for (int T = 0; T < ntiles; T++) {
        if (T + 1 < ntiles) stage(cur ^ 1, T + 1);

        f32x4v s4[4];
#pragma unroll
        for (int n = 0; n < 4; n++) s4[n] = (f32x4v){0.f, 0.f, 0.f, 0.f};
#pragma unroll
        for (int ks = 0; ks < 2; ks++) {
            bf16x8v qh_ = qh[ks], ql_ = ql[ks];
#pragma unroll
            for (int n = 0; n < 4; n++) {
                int row = n * 16 + lr;
                int off = row * 64 + (((ks * 4 + kc) ^ (lr & 7)) << 3);
                bf16x8v kh = *(const bf16x8v*)&sKh[cur][off];
                bf16x8v kl = *(const bf16x8v*)&sKl[cur][off];
                s4[n] = __builtin_amdgcn_mfma_f32_16x16x32_bf16(qh_, kh, s4[n], 0, 0, 0);
                s4[n] = __builtin_amdgcn_mfma_f32_16x16x32_bf16(ql_, kh, s4[n], 0, 0, 0);
                s4[n] = __builtin_amdgcn_mfma_f32_16x16x32_bf16(qh_, kl, s4[n], 0, 0, 0);
            }
        }

#pragma unroll
        for (int n = 0; n < 4; n++) {
            int key = T * 64 + n * 16 + lr;
#pragma unroll
            for (int j = 0; j < 4; j++) {
                int gq = q0 + w * 16 + kc * 4 + j;
                float sv = s4[n][j] * scale;
                s4[n][j] = (key <= XLM + gq) ? sv : -1e30f;
            }
        }

        float tm[4];
#pragma unroll
        for (int j = 0; j < 4; j++) {
            float v = fmaxf(fmaxf(s4[0][j], s4[1][j]), fmaxf(s4[2][j], s4[3][j]));
            v = fmaxf(v, __shfl_xor(v, 1, 64));
            v = fmaxf(v, __shfl_xor(v, 2, 64));
            v = fmaxf(v, __shfl_xor(v, 4, 64));
            v = fmaxf(v, __shfl_xor(v, 8, 64));
            tm[j] = v;
        }
        float alpha[4];
#pragma unroll
        for (int j = 0; j < 4; j++) {
            float mnew = fmaxf(m[j], tm[j]);
            alpha[j] = __expf(m[j] - mnew);
            m[j] = mnew;
        }
        float psum[4] = {0.f, 0.f, 0.f, 0.f};
#pragma unroll
        for (int n = 0; n < 4; n++)
#pragma unroll
            for (int j = 0; j < 4; j++) {
                float p = __expf(s4[n][j] - m[j]);
                s4[n][j] = p;
                psum[j] += p;
            }
#pragma unroll
        for (int j = 0; j < 4; j++) {
            float v = psum[j];
            v += __shfl_xor(v, 1, 64);
            v += __shfl_xor(v, 2, 64);
            v += __shfl_xor(v, 4, 64);
            v += __shfl_xor(v, 8, 64);
            l[j] = l[j] * alpha[j] + v;
        }
#pragma unroll
        for (int f = 0; f < 4; f++)
#pragma unroll
            for (int j = 0; j < 4; j++) o[f][j] *= alpha[j];

#pragma unroll
        for (int n = 0; n < 4; n++) {
            int chunkcol = 2 * n + (lr >> 3);
#pragma unroll
            for (int j = 0; j < 4; j++) {
                int row = kc * 4 + j;
                int off = wbase + row * 64 + (((chunkcol ^ (row & 7)) << 3) + (lr & 7));
                sPf[off] = s4[n][j];
            }
        }

#pragma unroll
        for (int ks = 0; ks < 2; ks++) {
            int poff = wbase + lr * 64 + (((ks * 4 + kc) ^ (lr & 7)) << 3);
            float4 a = *(const float4*)&sPf[poff];
            float4 c2 = *(const float4*)&sPf[poff + 4];
            float vv[8] = {a.x, a.y, a.z, a.w, c2.x, c2.y, c2.z, c2.w};
            u16x8v hib, lob;
#pragma unroll
            for (int j = 0; j < 8; j++) {
                hib[j] = f2bfbits(vv[j]);
                lob[j] = f2bfbits(vv[j] - bfbits2f(hib[j]));
            }
            bf16x8v ph = *(bf16x8v*)&hib;
            bf16x8v pl = *(bf16x8v*)&lob;
#pragma unroll
            for (int f = 0; f < 4; f++) {
                int row = f * 16 + lr;
                int off = row * 64 + (((ks * 4 + kc) ^ (lr & 7)) << 3);
                bf16x8v vh = *(const bf16x8v*)&sVh[cur][off];
                bf16x8v vl = *(const bf16x8v*)&sVl[cur][off];
                o[f] = __builtin_amdgcn_mfma_f32_16x16x32_bf16(ph, vh, o[f], 0, 0, 0);
                o[f] = __builtin_amdgcn_mfma_f32_16x16x32_bf16(pl, vh, o[f], 0, 0, 0);
                o[f] = __builtin_amdgcn_mfma_f32_16x16x32_bf16(ph, vl, o[f], 0, 0, 0);
            }
        }

        __syncthreads();
        cur ^= 1;
    }

    float inv[4];
#pragma unroll
    for (int j = 0; j < 4; j++) inv[j] = 1.0f / l[j];
    unsigned short* outu = (unsigned short*)out;
#pragma unroll
    for (int f = 0; f < 4; f++)
#pragma unroll
        for (int j = 0; j < 4; j++) {
            int gq = q0 + w * 16 + kc * 4 + j;
            size_t oidx = (size_t)(b * NSEQ + gq) * DIM + h * DH + f * 16 + lr;
            float v = o[f][j] * inv[j];
            unsigned short hv = f2bfbits(v);
            outu[oidx] = hv;
            outu[oidx + opS] = f2bfbits(v - bfbits2f(hv));
        }
    if (KNNL && lr == 0) {
#pragma unroll
        for (int j = 0; j < 4; j++) {
            int gq = q0 + w * 16 + kc * 4 + j;
            size_t srow = (((size_t)b * NH + h) * NSEQ + gq) * 2;
            stats[srow] = m[j];
            stats[srow + 1] = l[j];
        }
    }
}

// ---------------------------------------------------------------------------
// Per-row top-32 over bf16 simdb + exact recompute + mem softmax + combine.
// 4 waves per block, ONE ROW PER WAVE (no idle waves, no barriers).
__global__ __launch_bounds__(256) void knn_select(const unsigned short* __restrict__ simdb,
                                                  const float* __restrict__ db,
                                                  const float* __restrict__ qf,
                                                  const float* __restrict__ dbkn,
                                                  const float* __restrict__ knn_scale,
                                                  const float* __restrict__ stats,
                                                  __hip_bfloat16* __restrict__ out,
                                                  size_t opS,
                                                  int bh0) {
    __shared__ unsigned short sv[4 * 4096];

    int bh = bh0 + blockIdx.y;
    int b = bh >> 4, h = bh & 15;
    int t = threadIdx.x;
    int w = t >> 6, lane = t & 63;
    int i = blockIdx.x * 4 + w;
    unsigned short* svw = &sv[w * 4096];

    // stage this wave's row: 512 16B-chunks / 64 lanes = 8 iters
    const unsigned short* srow = &simdb[((size_t)blockIdx.y * NSEQ + i) * MDB];
#pragma unroll
    for (int it = 0; it < 8; it++) {
        int g = it * 64 + lane;
        int c = g >> 3, sub = g & 7;
        u16x8v d = *(const u16x8v*)&srow[(size_t)g * 8];
        *(u16x8v*)&svw[c * 64 + ((sub ^ (c & 7)) << 3)] = d;
    }

    // per-column candidates: lane owns column l, scans 64 chunks
    float lmax = -1e30f; int lidx = 0;
#pragma unroll
    for (int c = 0; c < 64; c++) {
        float v = bfbits2f(svw[c * 64 + (lane ^ ((c & 7) << 3))]);
        if (v > lmax) { lmax = v; lidx = c * 64 + lane; }
    }

    // 32 selection iterations, wave-synchronous
    int tidx = 0;
    for (int it = 0; it < TOPK; it++) {
        float v = lmax; int idx = lidx;
#pragma unroll
        for (int off = 32; off; off >>= 1) {
            float v2 = __shfl_xor(v, off, 64);
            int i2 = __shfl_xor(idx, off, 64);
            if (v2 > v || (v2 == v && i2 < idx)) { v = v2; idx = i2; }
        }
        if (lane == it) tidx = idx;
        int col = idx & 63, cc = idx >> 6;
        if (lane == 0) svw[cc * 64 + (col ^ ((cc & 7) << 3))] = 0xFF80; // bf16 -inf
        // rescan column col: lane reads element (c=lane, col)
        float rv = bfbits2f(svw[lane * 64 + (col ^ ((lane & 7) << 3))]);
        int ridx = lane * 64 + col;
#pragma unroll
        for (int off = 32; off; off >>= 1) {
            float v2 = __shfl_xor(rv, off, 64);
            int i2 = __shfl_xor(ridx, off, 64);
            if (v2 > rv || (v2 == rv && i2 < ridx)) { rv = v2; ridx = i2; }
        }
        if (lane == col) { lmax = rv; lidx = ridx; }
    }

    // exact recompute of selected sims (lane j < 32 recomputes sim of its idx)
    float srec = -1e30f;
    if (lane < TOPK) {
        const float* qrow = &qf[(size_t)(b * NSEQ + i) * DIM + h * DH];
        const float* krow = &dbkn[((size_t)b * MDB + tidx) * DH];
        float s = 0.f;
#pragma unroll
        for (int d4 = 0; d4 < 16; d4++) {
            float4 a = *(const float4*)&qrow[d4 * 4];
            float4 k2 = *(const float4*)&krow[d4 * 4];
            s += a.x * k2.x + a.y * k2.y + a.z * k2.z + a.w * k2.w;
        }
        srec = s;
    }

    float scl = __expf(knn_scale[h]);
    size_t srow_idx = (((size_t)b * NH + h) * NSEQ + i) * 2;
    float m_loc = stats[srow_idx], l_loc = stats[srow_idx + 1];
    float mm = srec;
#pragma unroll
    for (int off = 32; off; off >>= 1) mm = fmaxf(mm, __shfl_xor(mm, off, 64));
    float M = fmaxf(m_loc, mm * scl);
    float co = __expf(m_loc - M);
    float e = (lane < TOPK) ? __expf(srec * scl - M) : 0.f;
    float esum = e;
#pragma unroll
    for (int off = 32; off; off >>= 1) esum += __shfl_xor(esum, off, 64);
    float denom = l_loc * co + esum;

    // gather: lane = output dim; iterate 32 selected keys via shfl broadcast
    float acc = 0.f;
#pragma unroll
    for (int j = 0; j < TOPK; j++) {
        int idxj = __shfl(tidx, j, 64);
        float ej = __shfl(e, j, 64);
        acc += ej * db[(((size_t)b * MDB + idxj) * 2 + 1) * DH + lane];
    }

    size_t op = (size_t)(b * NSEQ + i) * DIM + h * DH + lane;
    float o_loc = bf2f(out[op]) + bf2f(out[op + opS]);
    float nv = (o_loc * l_loc * co + acc) / denom;
    __hip_bfloat16 hv = f2bf(nv);
    out[op] = hv;
    out[op + opS] = f2bf(nv - bf2f(hv));
}

// ---------------------------------------------------------------------------
extern "C" void kernel_launch(void* const* d_in, const int* in_sizes, int n_in,
                              void* d_out, int out_size, void* d_ws, size_t ws_size,
                              hipStream_t stream) {
    const int* tokens = (const int*)d_in[0];
    const float* emb = (const float*)d_in[1];
    const float* ln1_w = (const float*)d_in[2];
    const float* ln1_b = (const float*)d_in[3];
    const float* wq = (const float*)d_in[4];
    const float* wkv = (const float*)d_in[5];
    const float* wo = (const float*)d_in[6];
    const float* wo_b = (const float*)d_in[7];
    const float* knn_scale = (const float*)d_in[8];
    const float* ln2_w = (const float*)d_in[9];
    const float* ln2_b = (const float*)d_in[10];
    const float* ff_w1 = (const float*)d_in[11];
    const float* ff_b1 = (const float*)d_in[12];
    const float* ff_w2 = (const float*)d_in[13];
    const float* ff_b2 = (const float*)d_in[14];
    const float* lnf_w = (const float*)d_in[15];
    const float* lnf_b = (const float*)d_in[16];
    const float* w_logits = (const float*)d_in[17];
    const float* b_logits = (const float*)d_in[18];
    const float* xl_mems = (const float*)d_in[19];
    const float* db_kv = (const float*)d_in[20];

    // ---- workspace layout ----
    const size_t PS_H = (size_t)BNROWS * DIM;        // plane stride for h / attn-out
    char* p = (char*)d_ws;
    float* x = (float*)p;                p += PS_H * 4;                        // 8 MB
    __hip_bfloat16* hb = (__hip_bfloat16*)p;  p += PS_H * 2 * 2;               // 8 MB (2 planes)
    float* qf = (float*)p;               p += PS_H * 4;                        // 8 MB
    float* kvf = (float*)p;              p += (size_t)BNROWS * 128 * 4;        // 1 MB
    float* dbkn = (float*)p;             p += (size_t)BB * MDB * DH * 4;       // 2 MB
    float* stats = (float*)p;            p += (size_t)BB * NH * NSEQ * 2 * 4;  // 0.25 MB
    unsigned short* ksp = (unsigned short*)p; p += KSP_PS * 2 * 2;             // 0.66 MB
    unsigned short* vtp = (unsigned short*)p; p += KSP_PS * 2 * 2;             // 0.66 MB
    __hip_bfloat16* wT = (__hip_bfloat16*)p; p += (size_t)4096 * DIM * 2 * 2;  // 16 MB (2 planes)

    // qsplit/dbkn-split live in the wT region during the KNN phase (wT idle)
    unsigned short* qsplit = (unsigned short*)wT;                  // 2 planes x PS_H
    unsigned short* dbks = (unsigned short*)wT + 2 * PS_H;         // 2 planes x BB*MDB*DH
    const size_t PS_DB = (size_t)BB * MDB * DH;

    const size_t PS_MID = (size_t)BNROWS * 4 * DIM;  // 8M elems per plane
    __hip_bfloat16* midb = (__hip_bfloat16*)d_out;   // 32 MB of the 262 MB out buf
    float* logits = (float*)d_out;
    // split-K partial buffers: d_out + 96 MB (clear of simdb 0..67MB and midb)
    float* part = (float*)((char*)d_out + ((size_t)96 << 20));

    const size_t PS_QKV = (size_t)BNROWS * NQKV;     // merged q|kv partial plane

    embed_kernel<<<BNROWS, 256, 0, stream>>>(tokens, emb, x);
    // first LN (later LNs are fused into combine_ln)
    ln_kernel<<<BNROWS, 256, 0, stream>>>(x, ln1_w, ln1_b, hb, PS_H);

    for (int l = 0; l < DEPTH; l++) {
        const float* wq_l = wq + (size_t)l * DIM * DIM;
        const float* wkv_l = wkv + (size_t)l * DIM * 128;
        const float* wo_l = wo + (size_t)l * DIM * DIM;
        const float* xlm_l = xl_mems + (size_t)l * BB * XLM * 2 * DH;

        // q|kv = h @ [wq wkv]  (merged N=1152, split-K=4 -> combine_qkv)
        wconv<<<dim3(16, 16), 256, 0, stream>>>(wq_l, wT, (size_t)NQKV * DIM, DIM, DIM, DIM, 1);
        wconv<<<dim3(16, 2), 256, 0, stream>>>(wkv_l, wT + (size_t)DIM * DIM, (size_t)NQKV * DIM, DIM, 128, 128, 1);
        gemm_split<float, 0, 3, 2><<<dim3(NQKV / 128, BNROWS / 128, 4), 256, 0, stream>>>(
            hb, DIM, PS_H, wT, DIM, (size_t)NQKV * DIM, part, NQKV, PS_QKV, 256, nullptr, nullptr, 0);
        combine_qkv<4><<<(PS_QKV / 4 + 255) / 256, 256, 0, stream>>>(
            part, PS_QKV, qf, kvf, PS_QKV / 4);

        if (l == KNN_LAYER) {
            // fused q l2norm + split planes; fresh-k normalized inside kv_prep;
            // db keys normalized + split in one pass (dbks lives in idle wT)
            l2split_q<<<BNROWS * NH / 4, 256, 0, stream>>>(qf, qsplit, PS_H);
            kv_prep<1><<<dim3(NKEYS, BB), 64, 0, stream>>>(kvf, xlm_l, ksp, vtp);
            dbprep<<<BB * MDB / 4, 256, 0, stream>>>(db_kv, dbkn, dbks, PS_DB);
            flash_kernel<1><<<dim3(NSEQ / 64, NH, BB), 256, 0, stream>>>(
                qf, ksp, vtp, knn_scale, hb, PS_H, stats);
            const int CHUNK = 8;  // 8 x 8 MB bf16 = 67 MB per gemm->select pair
            for (int bh0 = 0; bh0 < BB * NH; bh0 += CHUNK) {
                // TERMS=1: selection-grade sims (exact recompute in knn_select)
                gemm_split<unsigned short, 0, 1, 1><<<dim3(MDB / 128, NSEQ / 128, CHUNK), 256, 0, stream>>>(
                    (const __hip_bfloat16*)qsplit, DIM, PS_H,
                    (const __hip_bfloat16*)dbks, DH, PS_DB,
                    (unsigned short*)d_out, MDB, 0, DH, nullptr, nullptr, bh0);
                knn_select<<<dim3(NSEQ / 4, CHUNK), 256, 0, stream>>>(
                    (const unsigned short*)d_out, db_kv, qf, dbkn, knn_scale, stats, hb, PS_H, bh0);
            }
        } else {
            kv_prep<0><<<dim3(NKEYS, BB), 64, 0, stream>>>(kvf, xlm_l, ksp, vtp);
            flash_kernel<0><<<dim3(NSEQ / 64, NH, BB), 256, 0, stream>>>(
                qf, ksp, vtp, knn_scale, hb, PS_H, stats);
        }

        // x = attn @ wo + wo_b + x; h = LN2(x)   (split-K=4 + fused combine+LN)
        wconv<<<dim3(16, 16), 256, 0, stream>>>(wo_l, wT, (size_t)DIM * DIM, DIM, DIM, DIM, 1);
        gemm_split<float, 0, 3, 2><<<dim3(DIM / 128, BNROWS / 128, 4), 256, 0, stream>>>(
            hb, DIM, PS_H, wT, DIM, (size_t)DIM * DIM, part, DIM, PS_H, 256, nullptr, nullptr, 0);
        combine_ln<4><<<BNROWS, 256, 0, stream>>>(
            part, PS_H, wo_b + (size_t)l * DIM, x,
            ln2_w + (size_t)l * DIM, ln2_b + (size_t)l * DIM, hb, PS_H);

        // mid = gelu(h @ ff_w1 + b1)  (split-K=2 + fused combine+gelu+split)
        wconv<<<dim3(16, 64), 256, 0, stream>>>(ff_w1 + (size_t)l * DIM * 4 * DIM, wT, (size_t)4096 * DIM, DIM, 4 * DIM, 4 * DIM, 1);
        gemm_split<float, 0, 3, 2><<<dim3(4 * DIM / 128, BNROWS / 128, 2), 256, 0, stream>>>(
            hb, DIM, PS_H, wT, DIM, (size_t)4096 * DIM, part, 4 * DIM, PS_MID, 512, nullptr, nullptr, 0);
        combine_gelu_split<2><<<(PS_MID / 4 + 255) / 256, 256, 0, stream>>>(
            part, PS_MID, ff_b1 + (size_t)l * 4 * DIM, 4 * DIM,
            (unsigned short*)midb, PS_MID, PS_MID / 4);

        // x = mid @ ff_w2 + b2 + x; h = LN_next(x)  (split-K=4 + fused)
        wconv<<<dim3(64, 16), 256, 0, stream>>>(ff_w2 + (size_t)l * 4 * DIM * DIM, wT, (size_t)DIM * 4096, 4 * DIM, DIM, DIM, 1);
        gemm_split<float, 0, 3, 2><<<dim3(DIM / 128, BNROWS / 128, 4), 256, 0, stream>>>(
            midb, 4 * DIM, PS_MID, wT, 4 * DIM, (size_t)DIM * 4096, part, DIM, PS_H, 1024, nullptr, nullptr, 0);
        const float* nw = (l < DEPTH - 1) ? ln1_w + (size_t)(l + 1) * DIM : lnf_w;
        const float* nb = (l < DEPTH - 1) ? ln1_b + (size_t)(l + 1) * DIM : lnf_b;
        combine_ln<4><<<BNROWS, 256, 0, stream>>>(
            part, PS_H, ff_b2 + (size_t)l * DIM, x, nw, nb, hb, PS_H);
    }

    // logits (hb already holds LNf output; 5 column chunks, hi-plane bf16)
    for (int c0 = 0; c0 < VOCAB; c0 += LOGITS_CHUNK) {
        wconv<<<dim3(16, LOGITS_CHUNK / 64), 256, 0, stream>>>(
            w_logits + c0, wT, 0, DIM, LOGITS_CHUNK, VOCAB, 0);
        gemm_split<float, 0, 1, 0><<<dim3(LOGITS_CHUNK / 128, BNROWS / 128), 256, 0, stream>>>(
            hb, DIM, PS_H, wT, DIM, 0, logits + c0, VOCAB, 0, DIM,
            b_logits + c0, nullptr, 0);
    }
}